// Round 6
// baseline (831.750 us; speedup 1.0000x reference)
//
#include <hip/hip_runtime.h>
#include <hip/hip_bf16.h>

// Problem constants (Mp_encoder): N nodes, D dims, P metapaths.
constexpr int N = 4096;
constexpr int D = 256;
constexpr int P = 3;
constexpr int MAXDEG = 17;       // K+1
constexpr float TAU = 0.8f;
constexpr float MARGIN = 0.1f;
constexpr float EPS_PD = 1e-6f;

constexpr int LDP = 40;          // LDS k-stride for 64-tiles (2-way max conflicts)
constexpr int LDK = 72;          // LDS k-stride for sim BK=64 staging
constexpr int NW = N / 32;       // bitmap words per row (128)

// bf16 conversion-area offsets (elements), all 256-aligned
constexpr int OFF_H    = 0;             // 1048576
constexpr int OFF_WG   = 1048576;       // 196608
constexpr int OFF_ATTW = 1245184;       // 65536
constexpr int OFF_W1   = 1310720;       // 65536
constexpr int OFF_W2   = 1376256;       // 65536
constexpr int OFF_BG   = 1441792;       // 768
constexpr int OFF_ATTB = 1442560;       // 256
constexpr int OFF_AV   = 1442816;       // 256
constexpr int OFF_PA   = 1443072;       // 3 (reserve 256)
constexpr int OFF_B1   = 1443328;       // 256
constexpr int OFF_B2   = 1443584;       // 256
constexpr int CONV_TOTAL = 1443840;

typedef __attribute__((ext_vector_type(8))) short bfrag8;
typedef __attribute__((ext_vector_type(4))) float facc4;

__device__ inline facc4 mfma16(bfrag8 a, bfrag8 b, facc4 c) {
    return __builtin_amdgcn_mfma_f32_16x16x32_bf16(a, b, c, 0, 0, 0);
}
__device__ inline float b2f(__hip_bfloat16 v) { return __bfloat162float(v); }
__device__ inline float bfbits2f(unsigned short u) {
    return __uint_as_float(((unsigned int)u) << 16);
}
__device__ inline unsigned short f2bfbits(float v) {
    __hip_bfloat16 t = __float2bfloat16(v);
    return *(unsigned short*)&t;
}
__device__ inline int get_bf(const int* __restrict__ counter) { return counter[0] > 100; }

__device__ inline float load_in(const void* p, size_t i, int bf) {
    return bf ? __bfloat162float(((const __hip_bfloat16*)p)[i])
              : ((const float*)p)[i];
}

// ---------------------------------------------------------------------------
// 0. dtype detection from mps bit patterns (bf16 ⇒ many nonzero low-halves)
// ---------------------------------------------------------------------------
__global__ void detect_dtype(const unsigned int* __restrict__ w, int nwords,
                             int* __restrict__ counter) {
    int stride = gridDim.x * blockDim.x;
    int c = 0;
    for (int i = blockIdx.x * blockDim.x + threadIdx.x; i < nwords; i += stride) {
        unsigned int x = w[i];
        if ((x & 0xFFFF0000u) == 0u && x != 0u) c++;
    }
    for (int s = 32; s > 0; s >>= 1) c += __shfl_down(c, s);
    if ((threadIdx.x & 63) == 0 && c > 0) atomicAdd(counter, c);
}

// ---------------------------------------------------------------------------
// 1. Convert all dense inputs to a contiguous bf16 staging area.
// ---------------------------------------------------------------------------
__global__ void convert_all(const void* h, const void* wg, const void* attw,
                            const void* w1, const void* w2, const void* bg,
                            const void* attb, const void* av, const void* pa,
                            const void* b1, const void* b2,
                            const int* __restrict__ counter,
                            __hip_bfloat16* __restrict__ dst) {
    int bf = get_bf(counter);
    const void* srcs[11] = {h, wg, attw, w1, w2, bg, attb, av, pa, b1, b2};
    const int offs[11] = {OFF_H, OFF_WG, OFF_ATTW, OFF_W1, OFF_W2, OFF_BG,
                          OFF_ATTB, OFF_AV, OFF_PA, OFF_B1, OFF_B2};
    const int lens[11] = {1048576, 196608, 65536, 65536, 65536, 768, 256, 256, 3, 256, 256};
    int stride = gridDim.x * blockDim.x;
    int t0 = blockIdx.x * blockDim.x + threadIdx.x;
    #pragma unroll
    for (int s = 0; s < 11; s++) {
        for (int i = t0; i < lens[s]; i += stride)
            dst[offs[s] + i] = __float2bfloat16(load_in(srcs[s], i, bf));
    }
}

// ---------------------------------------------------------------------------
// 2. Sparse extraction (per (p,n) row of mps), vectorized 16B loads.
//    Also writes adjacency bitmaps for pairs 0,1 (rows < 2N).
// ---------------------------------------------------------------------------
__global__ void extract_sparse(const void* __restrict__ mps, const int* __restrict__ counter,
                               int* __restrict__ nbr_idx, float* __restrict__ nbr_val,
                               int* __restrict__ neg_idx, int* __restrict__ deg,
                               unsigned int* __restrict__ bmp) {
    int bf = get_bf(counter);
    int row = blockIdx.x;              // 0 .. P*N-1
    int t = threadIdx.x;               // 256 threads, 16 elems each
    __shared__ int cnt;
    __shared__ int sidx[32];
    __shared__ float sval[32];
    if (t == 0) cnt = 0;
    __syncthreads();
    int e0 = t * 16;
    if (bf) {
        const uint4* base = (const uint4*)((const __hip_bfloat16*)mps + (size_t)row * N + e0);
        #pragma unroll
        for (int v = 0; v < 2; v++) {
            uint4 w = base[v];
            unsigned int ws[4] = {w.x, w.y, w.z, w.w};
            #pragma unroll
            for (int j = 0; j < 4; j++) {
                unsigned short lo = (unsigned short)(ws[j] & 0xFFFFu);
                unsigned short hi = (unsigned short)(ws[j] >> 16);
                if (lo) { int k = atomicAdd(&cnt, 1); if (k < 32) { sidx[k] = e0 + v * 8 + j * 2;     sval[k] = bfbits2f(lo); } }
                if (hi) { int k = atomicAdd(&cnt, 1); if (k < 32) { sidx[k] = e0 + v * 8 + j * 2 + 1; sval[k] = bfbits2f(hi); } }
            }
        }
    } else {
        const float4* base = (const float4*)((const float*)mps + (size_t)row * N + e0);
        #pragma unroll
        for (int v = 0; v < 4; v++) {
            float4 w = base[v];
            float ws[4] = {w.x, w.y, w.z, w.w};
            #pragma unroll
            for (int j = 0; j < 4; j++)
                if (ws[j] > 0.f) { int k = atomicAdd(&cnt, 1); if (k < 32) { sidx[k] = e0 + v * 4 + j; sval[k] = ws[j]; } }
        }
    }
    __syncthreads();
    if (t == 0) {
        int dg = cnt; if (dg > MAXDEG) dg = MAXDEG;
        for (int i = 1; i < dg; i++) {           // insertion sort by index
            int ki = sidx[i]; float kv = sval[i]; int j = i - 1;
            while (j >= 0 && sidx[j] > ki) { sidx[j+1] = sidx[j]; sval[j+1] = sval[j]; j--; }
            sidx[j+1] = ki; sval[j+1] = kv;
        }
        deg[row] = dg;
        int* oi = nbr_idx + (size_t)row * MAXDEG;
        float* ov = nbr_val + (size_t)row * MAXDEG;
        int* ng = neg_idx + (size_t)row * MAXDEG;
        for (int i = 0; i < MAXDEG; i++) { oi[i] = (i < dg) ? sidx[i] : 0; ov[i] = (i < dg) ? sval[i] : 0.f; }
        if (row < 2 * N) {
            for (int i = 0; i < dg; i++)
                atomicOr(&bmp[(size_t)row * NW + (sidx[i] >> 5)], 1u << (sidx[i] & 31));
        }
        int c = 0, j = 0, found = 0;
        while (found < MAXDEG) {
            if (j < dg && sidx[j] == c) { j++; c++; continue; }
            ng[found++] = c++;
        }
    }
}

// ---------------------------------------------------------------------------
// 3. MFMA GEMM: C[z][r][c] = sum_k A[z][r][k]*B[z][c][k] (+bias)
//    64x64 tile, BK=32, 4 waves of 32x32. Used for the X-stage.
// ---------------------------------------------------------------------------
template <int ACT>
__global__ void gemm_mfma(const __hip_bfloat16* __restrict__ Abase, size_t strideA,
                          const __hip_bfloat16* __restrict__ Bbase, size_t strideB,
                          const __hip_bfloat16* __restrict__ bias, size_t strideBias,
                          __hip_bfloat16* __restrict__ Cbase, size_t strideC) {
    int z = blockIdx.z;
    const __hip_bfloat16* A = Abase + (size_t)z * strideA;
    const __hip_bfloat16* B = Bbase + (size_t)z * strideB;
    __shared__ __align__(16) __hip_bfloat16 As[64 * LDP];
    __shared__ __align__(16) __hip_bfloat16 Bs[64 * LDP];
    int bm = blockIdx.x * 64, bn = blockIdx.y * 64;
    int tid = threadIdx.x, wave = tid >> 6, lane = tid & 63;
    int quad = lane >> 4, l15 = lane & 15;
    int wr = (wave & 1) * 32, wc = (wave >> 1) * 32;
    facc4 acc[2][2] = {};
    int sr = tid >> 2, kq = (tid & 3) * 8;
    for (int k0 = 0; k0 < D; k0 += 32) {
        *(bfrag8*)&As[sr * LDP + kq] = *(const bfrag8*)&A[(size_t)(bm + sr) * D + k0 + kq];
        *(bfrag8*)&Bs[sr * LDP + kq] = *(const bfrag8*)&B[(size_t)(bn + sr) * D + k0 + kq];
        __syncthreads();
        bfrag8 af[2], bfr[2];
        #pragma unroll
        for (int mi = 0; mi < 2; mi++)
            af[mi] = *(const bfrag8*)&As[(wr + mi * 16 + l15) * LDP + quad * 8];
        #pragma unroll
        for (int ni = 0; ni < 2; ni++)
            bfr[ni] = *(const bfrag8*)&Bs[(wc + ni * 16 + l15) * LDP + quad * 8];
        #pragma unroll
        for (int mi = 0; mi < 2; mi++)
            #pragma unroll
            for (int ni = 0; ni < 2; ni++)
                acc[mi][ni] = mfma16(af[mi], bfr[ni], acc[mi][ni]);
        __syncthreads();
    }
    #pragma unroll
    for (int mi = 0; mi < 2; mi++) {
        #pragma unroll
        for (int ni = 0; ni < 2; ni++) {
            int col = bn + wc + ni * 16 + l15;
            #pragma unroll
            for (int r = 0; r < 4; r++) {
                int row = bm + wr + mi * 16 + quad * 4 + r;
                float v = acc[mi][ni][r];
                if (bias) v += b2f(bias[col]);
                if (ACT == 1) v = v > 0.f ? v : expm1f(v);
                Cbase[(size_t)z * strideC + (size_t)row * D + col] = __float2bfloat16(v);
            }
        }
    }
}

// ---------------------------------------------------------------------------
// 3b. Fused dual-B GEMM over emb: shares A staging.
//     path 1: tanh(emb@attW^T + attb) → column-sum into spacc (no C write)
//     path 2: elu(emb@W1^T + b1) → xbuf
// ---------------------------------------------------------------------------
__global__ void gemm_dual(const __hip_bfloat16* __restrict__ embBase,
                          const __hip_bfloat16* __restrict__ conv,
                          __hip_bfloat16* __restrict__ xbuf,
                          float* __restrict__ spacc) {
    int z = blockIdx.z;
    const __hip_bfloat16* A = embBase + (size_t)z * N * D;
    const __hip_bfloat16* Ba = conv + OFF_ATTW;
    const __hip_bfloat16* Bw = conv + OFF_W1;
    __shared__ __align__(16) __hip_bfloat16 As[64 * LDP];
    __shared__ __align__(16) __hip_bfloat16 Bsa[64 * LDP];
    __shared__ __align__(16) __hip_bfloat16 Bsw[64 * LDP];
    int bm = blockIdx.x * 64, bn = blockIdx.y * 64;
    int tid = threadIdx.x, wave = tid >> 6, lane = tid & 63;
    int quad = lane >> 4, l15 = lane & 15;
    int wr = (wave & 1) * 32, wc = (wave >> 1) * 32;
    facc4 accA[2][2] = {};
    facc4 accW[2][2] = {};
    int sr = tid >> 2, kq = (tid & 3) * 8;
    for (int k0 = 0; k0 < D; k0 += 32) {
        *(bfrag8*)&As[sr * LDP + kq]  = *(const bfrag8*)&A[(size_t)(bm + sr) * D + k0 + kq];
        *(bfrag8*)&Bsa[sr * LDP + kq] = *(const bfrag8*)&Ba[(size_t)(bn + sr) * D + k0 + kq];
        *(bfrag8*)&Bsw[sr * LDP + kq] = *(const bfrag8*)&Bw[(size_t)(bn + sr) * D + k0 + kq];
        __syncthreads();
        bfrag8 af[2], ba[2], bw[2];
        #pragma unroll
        for (int mi = 0; mi < 2; mi++)
            af[mi] = *(const bfrag8*)&As[(wr + mi * 16 + l15) * LDP + quad * 8];
        #pragma unroll
        for (int ni = 0; ni < 2; ni++) {
            ba[ni] = *(const bfrag8*)&Bsa[(wc + ni * 16 + l15) * LDP + quad * 8];
            bw[ni] = *(const bfrag8*)&Bsw[(wc + ni * 16 + l15) * LDP + quad * 8];
        }
        #pragma unroll
        for (int mi = 0; mi < 2; mi++)
            #pragma unroll
            for (int ni = 0; ni < 2; ni++) {
                accA[mi][ni] = mfma16(af[mi], ba[ni], accA[mi][ni]);
                accW[mi][ni] = mfma16(af[mi], bw[ni], accW[mi][ni]);
            }
        __syncthreads();
    }
    float cs[2] = {0.f, 0.f};
    #pragma unroll
    for (int mi = 0; mi < 2; mi++) {
        #pragma unroll
        for (int ni = 0; ni < 2; ni++) {
            int col = bn + wc + ni * 16 + l15;
            float battb = b2f(conv[OFF_ATTB + col]);
            float bb1   = b2f(conv[OFF_B1 + col]);
            #pragma unroll
            for (int r = 0; r < 4; r++) {
                int row = bm + wr + mi * 16 + quad * 4 + r;
                cs[ni] += tanhf(accA[mi][ni][r] + battb);
                float v = accW[mi][ni][r] + bb1;
                v = v > 0.f ? v : expm1f(v);
                xbuf[(size_t)z * N * D + (size_t)row * D + col] = __float2bfloat16(v);
            }
        }
    }
    #pragma unroll
    for (int ni = 0; ni < 2; ni++) {
        float v = cs[ni];
        v += __shfl_xor(v, 16); v += __shfl_xor(v, 32);
        if (quad == 0) {
            int col = bn + wc + ni * 16 + l15;
            atomicAdd(&spacc[(size_t)z * D + col], v);
        }
    }
}

// ---------------------------------------------------------------------------
// 3c. proj2 GEMM with fused row-normalize: block = 16 rows × all 256 cols.
//     q[z][r][:] = normalize( xbuf[z][r][:] @ W2^T + b2 )
// ---------------------------------------------------------------------------
__global__ void gemm_w2_norm(const __hip_bfloat16* __restrict__ xbase,
                             const __hip_bfloat16* __restrict__ conv,
                             __hip_bfloat16* __restrict__ qbase) {
    int z = blockIdx.z;
    const __hip_bfloat16* A = xbase + (size_t)z * N * D;
    const __hip_bfloat16* B = conv + OFF_W2;
    __shared__ __align__(16) __hip_bfloat16 As[16 * LDP];
    __shared__ __align__(16) __hip_bfloat16 Bs[256 * LDP];
    __shared__ float sred[4][16];
    int bm = blockIdx.x * 16;
    int tid = threadIdx.x, wave = tid >> 6, lane = tid & 63;
    int quad = lane >> 4, l15 = lane & 15;
    int wc = wave * 64;
    facc4 acc[4] = {};
    for (int k0 = 0; k0 < D; k0 += 32) {
        if (tid < 64) {
            int r = tid >> 2, kq = (tid & 3) * 8;
            *(bfrag8*)&As[r * LDP + kq] = *(const bfrag8*)&A[(size_t)(bm + r) * D + k0 + kq];
        }
        #pragma unroll
        for (int i = 0; i < 4; i++) {
            int f = tid + 256 * i;          // 1024 fragments of B
            int r = f >> 2, kq = (f & 3) * 8;
            *(bfrag8*)&Bs[r * LDP + kq] = *(const bfrag8*)&B[(size_t)r * D + k0 + kq];
        }
        __syncthreads();
        bfrag8 af = *(const bfrag8*)&As[l15 * LDP + quad * 8];
        #pragma unroll
        for (int ni = 0; ni < 4; ni++) {
            bfrag8 bf = *(const bfrag8*)&Bs[(wc + ni * 16 + l15) * LDP + quad * 8];
            acc[ni] = mfma16(af, bf, acc[ni]);
        }
        __syncthreads();
    }
    float vv[4][4];   // [ni][r], bias applied
    #pragma unroll
    for (int ni = 0; ni < 4; ni++) {
        float bb = b2f(conv[OFF_B2 + wc + ni * 16 + l15]);
        #pragma unroll
        for (int r = 0; r < 4; r++) vv[ni][r] = acc[ni][r] + bb;
    }
    #pragma unroll
    for (int r = 0; r < 4; r++) {
        float ss = vv[0][r] * vv[0][r] + vv[1][r] * vv[1][r] +
                   vv[2][r] * vv[2][r] + vv[3][r] * vv[3][r];
        ss += __shfl_xor(ss, 1); ss += __shfl_xor(ss, 2);
        ss += __shfl_xor(ss, 4); ss += __shfl_xor(ss, 8);
        if (l15 == 0) sred[wave][quad * 4 + r] = ss;
    }
    __syncthreads();
    #pragma unroll
    for (int r = 0; r < 4; r++) {
        int rl = quad * 4 + r;
        float ssum = sred[0][rl] + sred[1][rl] + sred[2][rl] + sred[3][rl];
        float inv = rsqrtf(ssum + 1e-30f);
        int row = bm + rl;
        #pragma unroll
        for (int ni = 0; ni < 4; ni++)
            qbase[(size_t)z * N * D + (size_t)row * D + wc + ni * 16 + l15] =
                __float2bfloat16(vv[ni][r] * inv);
    }
}

// ---------------------------------------------------------------------------
// 4. spmm + prelu: wave per node, ushort4 loads/stores.
// ---------------------------------------------------------------------------
__global__ void spmm_prelu(const __hip_bfloat16* __restrict__ Xbase,
                           const int* __restrict__ nbr_idx, const float* __restrict__ nbr_val,
                           const int* __restrict__ deg, const __hip_bfloat16* __restrict__ conv,
                           __hip_bfloat16* __restrict__ embBase) {
    int z = blockIdx.z;
    int wave = threadIdx.x >> 6, lane = threadIdx.x & 63;
    int n = blockIdx.x * 4 + wave;
    const __hip_bfloat16* X = Xbase + (size_t)z * N * D;
    const int* idx = nbr_idx + ((size_t)z * N + n) * MAXDEG;
    const float* val = nbr_val + ((size_t)z * N + n) * MAXDEG;
    int dg = deg[z * N + n];
    float acc[4] = {0.f, 0.f, 0.f, 0.f};
    for (int k = 0; k < dg; k++) {
        int j = idx[k];
        float vk = val[k];
        ushort4 x = *(const ushort4*)&X[(size_t)j * D + lane * 4];
        acc[0] += vk * bfbits2f(x.x); acc[1] += vk * bfbits2f(x.y);
        acc[2] += vk * bfbits2f(x.z); acc[3] += vk * bfbits2f(x.w);
    }
    ushort4 bb = *(const ushort4*)&conv[OFF_BG + z * D + lane * 4];
    float b[4] = {bfbits2f(bb.x), bfbits2f(bb.y), bfbits2f(bb.z), bfbits2f(bb.w)};
    float a = b2f(conv[OFF_PA + z]);
    ushort4 o;
    float v0 = acc[0] + b[0]; o.x = f2bfbits(v0 > 0.f ? v0 : a * v0);
    float v1 = acc[1] + b[1]; o.y = f2bfbits(v1 > 0.f ? v1 : a * v1);
    float v2 = acc[2] + b[2]; o.z = f2bfbits(v2 > 0.f ? v2 : a * v2);
    float v3 = acc[3] + b[3]; o.w = f2bfbits(v3 > 0.f ? v3 : a * v3);
    *(ushort4*)&embBase[(size_t)z * N * D + (size_t)n * D + lane * 4] = o;
}

// ---------------------------------------------------------------------------
// 6. sim MFMA + fused posdot: per pair z, S = exp(Qz @ Q2^T / TAU);
//    rowsum/colsum atomics; bitmap-gated sparse pdrow/pdcol atomics.
// ---------------------------------------------------------------------------
__global__ void sim_mfma(const __hip_bfloat16* __restrict__ q,
                         const unsigned int* __restrict__ bmp,
                         const int* __restrict__ nbr_idx, const float* __restrict__ nbr_val,
                         const int* __restrict__ deg,
                         float* __restrict__ rowsum, float* __restrict__ colsum,
                         float* __restrict__ pdrow, float* __restrict__ pdcol) {
    int pair = blockIdx.z;
    const __hip_bfloat16* Qa = q + (size_t)pair * N * D;
    const __hip_bfloat16* Qb = q + (size_t)2 * N * D;
    __shared__ __align__(16) __hip_bfloat16 As[128 * LDK];
    __shared__ __align__(16) __hip_bfloat16 Bs[128 * LDK];
    __shared__ unsigned int Mrow[128][4];   // rows bm+i, col-words bn/32..+3
    __shared__ unsigned int Mcol[128][4];   // rows bn+i, col-words bm/32..+3
    int bm = blockIdx.x * 128, bn = blockIdx.y * 128;
    int tid = threadIdx.x, wave = tid >> 6, lane = tid & 63;
    int quad = lane >> 4, l15 = lane & 15;
    int wr = (wave & 1) * 64, wc = (wave >> 1) * 64;
    // bitmap tile loads (visible after first __syncthreads)
    for (int i = tid; i < 512; i += 256) {
        int rr = i >> 2, w = i & 3;
        Mrow[rr][w] = bmp[((size_t)pair * N + bm + rr) * NW + (bn >> 5) + w];
        Mcol[rr][w] = bmp[((size_t)pair * N + bn + rr) * NW + (bm >> 5) + w];
    }
    facc4 acc[4][4] = {};
    int sr0 = tid >> 3, kq = (tid & 7) * 8;      // 32 rows per chunk, 64 k-cols
    for (int k0 = 0; k0 < D; k0 += 64) {
        #pragma unroll
        for (int i = 0; i < 4; i++) {
            int r = sr0 + 32 * i;
            *(bfrag8*)&As[r * LDK + kq] = *(const bfrag8*)&Qa[(size_t)(bm + r) * D + k0 + kq];
            *(bfrag8*)&Bs[r * LDK + kq] = *(const bfrag8*)&Qb[(size_t)(bn + r) * D + k0 + kq];
        }
        __syncthreads();
        #pragma unroll
        for (int kk = 0; kk < 64; kk += 32) {
            bfrag8 af[4], bfr[4];
            #pragma unroll
            for (int mi = 0; mi < 4; mi++)
                af[mi] = *(const bfrag8*)&As[(wr + mi * 16 + l15) * LDK + kk + quad * 8];
            #pragma unroll
            for (int ni = 0; ni < 4; ni++)
                bfr[ni] = *(const bfrag8*)&Bs[(wc + ni * 16 + l15) * LDK + kk + quad * 8];
            #pragma unroll
            for (int mi = 0; mi < 4; mi++)
                #pragma unroll
                for (int ni = 0; ni < 4; ni++)
                    acc[mi][ni] = mfma16(af[mi], bfr[ni], acc[mi][ni]);
        }
        __syncthreads();
    }
    constexpr float invtau = 1.0f / TAU;
    float rs[4][4];   // [mi][r]
    float cs[4] = {0.f, 0.f, 0.f, 0.f};
    #pragma unroll
    for (int mi = 0; mi < 4; mi++)
        #pragma unroll
        for (int r = 0; r < 4; r++) rs[mi][r] = 0.f;
    #pragma unroll
    for (int mi = 0; mi < 4; mi++)
        #pragma unroll
        for (int ni = 0; ni < 4; ni++)
            #pragma unroll
            for (int r = 0; r < 4; r++) {
                float e = __expf(acc[mi][ni][r] * invtau);
                rs[mi][r] += e;
                cs[ni] += e;
                acc[mi][ni][r] = e;   // keep e for the sparse pass
            }
    #pragma unroll
    for (int mi = 0; mi < 4; mi++)
        #pragma unroll
        for (int r = 0; r < 4; r++) {
            float v = rs[mi][r];
            v += __shfl_xor(v, 1); v += __shfl_xor(v, 2);
            v += __shfl_xor(v, 4); v += __shfl_xor(v, 8);
            rs[mi][r] = v;
        }
    if (l15 == 0) {
        #pragma unroll
        for (int mi = 0; mi < 4; mi++)
            #pragma unroll
            for (int r = 0; r < 4; r++)
                atomicAdd(&rowsum[(size_t)pair * N + bm + wr + mi * 16 + quad * 4 + r], rs[mi][r]);
    }
    #pragma unroll
    for (int ni = 0; ni < 4; ni++) {
        float v = cs[ni];
        v += __shfl_xor(v, 16); v += __shfl_xor(v, 32);
        if (quad == 0)
            atomicAdd(&colsum[(size_t)pair * N + bn + wc + ni * 16 + l15], v);
    }
    // sparse pdrow: S[n, j]*pos[n, j] for j in nbr(n)
    #pragma unroll
    for (int mi = 0; mi < 4; mi++) {
        #pragma unroll
        for (int r = 0; r < 4; r++) {
            int rl = wr + mi * 16 + quad * 4 + r;
            if ((Mrow[rl][0] | Mrow[rl][1] | Mrow[rl][2] | Mrow[rl][3]) == 0u) continue;
            int ng = bm + rl;
            #pragma unroll
            for (int ni = 0; ni < 4; ni++) {
                int cl = wc + ni * 16 + l15;
                if ((Mrow[rl][cl >> 5] >> (cl & 31)) & 1u) {
                    int jg = bn + cl;
                    int dgn = deg[pair * N + ng];
                    const int* ix = nbr_idx + ((size_t)pair * N + ng) * MAXDEG;
                    float vv = 0.f;
                    for (int k = 0; k < dgn; k++)
                        if (ix[k] == jg) { vv = nbr_val[((size_t)pair * N + ng) * MAXDEG + k]; break; }
                    atomicAdd(&pdrow[pair * N + ng], vv * acc[mi][ni][r]);
                }
            }
        }
    }
    // sparse pdcol: S[j, n]*pos[n, j] → element (row,col) hits pdcol[col] iff row∈nbr(col)
    #pragma unroll
    for (int ni = 0; ni < 4; ni++) {
        int cl = wc + ni * 16 + l15;
        if ((Mcol[cl][0] | Mcol[cl][1] | Mcol[cl][2] | Mcol[cl][3]) == 0u) continue;
        int ng = bn + cl;   // the pdcol node
        #pragma unroll
        for (int mi = 0; mi < 4; mi++) {
            #pragma unroll
            for (int r = 0; r < 4; r++) {
                int rl = wr + mi * 16 + quad * 4 + r;
                if ((Mcol[cl][rl >> 5] >> (rl & 31)) & 1u) {
                    int jg = bm + rl;
                    int dgn = deg[pair * N + ng];
                    const int* ix = nbr_idx + ((size_t)pair * N + ng) * MAXDEG;
                    float vv = 0.f;
                    for (int k = 0; k < dgn; k++)
                        if (ix[k] == jg) { vv = nbr_val[((size_t)pair * N + ng) * MAXDEG + k]; break; }
                    atomicAdd(&pdcol[pair * N + ng], vv * acc[mi][ni][r]);
                }
            }
        }
    }
}

// ---------------------------------------------------------------------------
// 8. node loss: one wave per node, partials to buffer (no atomics).
// ---------------------------------------------------------------------------
__global__ void node_loss_k(const __hip_bfloat16* __restrict__ embBase,
                            const int* __restrict__ nbr_idx, const int* __restrict__ neg_idx,
                            const int* __restrict__ deg, float* __restrict__ nlpart) {
    int z = blockIdx.z;
    int wave = threadIdx.x >> 6, lane = threadIdx.x & 63;
    int n = blockIdx.x * 4 + wave;
    const __hip_bfloat16* emb = embBase + (size_t)z * N * D;
    int dg = deg[z * N + n];
    const int* ip = nbr_idx + ((size_t)z * N + n) * MAXDEG;
    const int* ig = neg_idx + ((size_t)z * N + n) * MAXDEG;
    ushort4 ar = *(const ushort4*)&emb[(size_t)n * D + lane * 4];
    float a[4] = {bfbits2f(ar.x), bfbits2f(ar.y), bfbits2f(ar.z), bfbits2f(ar.w)};
    float s = 0.f;
    for (int k = 0; k < dg; k++) {
        int jp = ip[k], jn = ig[k];
        ushort4 pr = *(const ushort4*)&emb[(size_t)jp * D + lane * 4];
        ushort4 nr = *(const ushort4*)&emb[(size_t)jn * D + lane * 4];
        float pv[4] = {bfbits2f(pr.x), bfbits2f(pr.y), bfbits2f(pr.z), bfbits2f(pr.w)};
        float nv[4] = {bfbits2f(nr.x), bfbits2f(nr.y), bfbits2f(nr.z), bfbits2f(nr.w)};
        float dp = 0.f, dn = 0.f;
        #pragma unroll
        for (int i = 0; i < 4; i++) {
            float x = a[i] - pv[i] + EPS_PD; dp += x * x;
            float y = a[i] - nv[i] + EPS_PD; dn += y * y;
        }
        #pragma unroll
        for (int st = 1; st <= 32; st <<= 1) { dp += __shfl_xor(dp, st); dn += __shfl_xor(dn, st); }
        float v = dp - dn + MARGIN;
        s += v > 0.f ? v : 0.f;
    }
    if (lane == 0) nlpart[z * N + n] = s / (float)dg;
}

// ---------------------------------------------------------------------------
// 9. final loss + beta: single block, no atomics.
// ---------------------------------------------------------------------------
__global__ void reduce_loss_beta(const float* __restrict__ nlpart,
                                 const float* __restrict__ rowsum, const float* __restrict__ colsum,
                                 const float* __restrict__ pdrow, const float* __restrict__ pdcol,
                                 const float* __restrict__ spacc,
                                 const __hip_bfloat16* __restrict__ conv,
                                 float* __restrict__ beta, float* __restrict__ loss) {
    int t = threadIdx.x;
    __shared__ float red[256];
    __shared__ float w[P];
    for (int p = 0; p < P; p++) {
        float v = (spacc[p * D + t] / (float)N) * b2f(conv[OFF_AV + t]);
        red[t] = v;
        __syncthreads();
        for (int s = 128; s > 0; s >>= 1) { if (t < s) red[t] += red[t + s]; __syncthreads(); }
        if (t == 0) w[p] = red[0];
        __syncthreads();
    }
    float s = 0.f;
    for (int i = t; i < P * N; i += 256) s += nlpart[i];
    for (int i = t; i < 2 * N; i += 256) {
        float l12 = -logf(pdrow[i] / (rowsum[i] + 1e-8f));
        float l21 = -logf(pdcol[i] / (colsum[i] + 1e-8f));
        s += (0.5f * l12 + 0.5f * l21) / (float)N;
    }
    red[t] = s;
    __syncthreads();
    for (int st = 128; st > 0; st >>= 1) { if (t < st) red[t] += red[t + st]; __syncthreads(); }
    if (t == 0) {
        loss[0] = red[0];
        float m = fmaxf(w[0], fmaxf(w[1], w[2]));
        float e0 = __expf(w[0] - m), e1 = __expf(w[1] - m), e2 = __expf(w[2] - m);
        float ssum = e0 + e1 + e2;
        beta[0] = e0 / ssum; beta[1] = e1 / ssum; beta[2] = e2 / ssum;
    }
}

// ---------------------------------------------------------------------------
// 10. z_mp output + loss scalar (output dtype follows detected input dtype)
// ---------------------------------------------------------------------------
__global__ void zmp_out(const __hip_bfloat16* __restrict__ embBase, const float* __restrict__ beta,
                        const float* __restrict__ loss, const int* __restrict__ counter,
                        void* __restrict__ out) {
    int bf = get_bf(counter);
    int i = blockIdx.x * 256 + threadIdx.x;
    float v = beta[0] * b2f(embBase[i]) + beta[1] * b2f(embBase[(size_t)N * D + i]) +
              beta[2] * b2f(embBase[(size_t)2 * N * D + i]);
    if (bf) {
        __hip_bfloat16* o = (__hip_bfloat16*)out;
        o[i] = __float2bfloat16(v);
        if (i == 0) o[(size_t)N * D] = __float2bfloat16(*loss);
    } else {
        float* o = (float*)out;
        o[i] = v;
        if (i == 0) o[(size_t)N * D] = *loss;
    }
}

extern "C" void kernel_launch(void* const* d_in, const int* in_sizes, int n_in,
                              void* d_out, int out_size, void* d_ws, size_t ws_size,
                              hipStream_t stream) {
    const void* h        = d_in[0];
    const void* mps      = d_in[1];
    const void* W_gcn    = d_in[2];
    const void* b_gcn    = d_in[3];
    const void* prelu_a  = d_in[4];
    const void* att_fc_W = d_in[5];
    const void* att_fc_b = d_in[6];
    const void* att_vec  = d_in[7];
    const void* proj_W1  = d_in[8];
    const void* proj_b1  = d_in[9];
    const void* proj_W2  = d_in[10];
    const void* proj_b2  = d_in[11];

    char* ws = (char*)d_ws;
    size_t off = 0;
    auto alloc = [&](size_t bytes) -> char* {
        char* p = ws + off;
        off = (off + bytes + 255) & ~(size_t)255;
        return p;
    };
    __hip_bfloat16* conv = (__hip_bfloat16*)alloc((size_t)CONV_TOTAL * 2);
    __hip_bfloat16* xbuf = (__hip_bfloat16*)alloc((size_t)P * N * D * 2);
    __hip_bfloat16* emb  = (__hip_bfloat16*)alloc((size_t)P * N * D * 2);
    __hip_bfloat16* q    = (__hip_bfloat16*)alloc((size_t)P * N * D * 2);
    int*   nbr_idx = (int*)alloc((size_t)P * N * MAXDEG * 4);
    float* nbr_val = (float*)alloc((size_t)P * N * MAXDEG * 4);
    int*   neg_idx = (int*)alloc((size_t)P * N * MAXDEG * 4);
    int*   deg     = (int*)alloc((size_t)P * N * 4);
    float* nlpart  = (float*)alloc((size_t)P * N * 4);
    char* zero_begin = ws + off;
    unsigned int* bmp = (unsigned int*)alloc((size_t)2 * N * NW * 4);  // 4 MB
    float* pdrow  = (float*)alloc((size_t)2 * N * 4);
    float* pdcol  = (float*)alloc((size_t)2 * N * 4);
    float* rowsum = (float*)alloc((size_t)2 * N * 4);
    float* colsum = (float*)alloc((size_t)2 * N * 4);
    float* spacc  = (float*)alloc((size_t)P * D * 4);
    float* beta   = (float*)alloc(16);
    float* loss   = (float*)alloc(16);
    int*   counter = (int*)alloc(16);
    size_t zero_bytes = (size_t)((ws + off) - zero_begin);
    hipMemsetAsync(zero_begin, 0, zero_bytes, stream);

    // 0. dtype detection
    detect_dtype<<<1024, 256, 0, stream>>>((const unsigned int*)mps, 2 * 1024 * 1024, counter);

    // 1. convert dense inputs to bf16 staging
    convert_all<<<512, 256, 0, stream>>>(h, W_gcn, att_fc_W, proj_W1, proj_W2, b_gcn,
                                         att_fc_b, att_vec, prelu_a, proj_b1, proj_b2,
                                         counter, conv);

    // 2. sparse extraction (+ pair bitmaps)
    extract_sparse<<<P * N, 256, 0, stream>>>(mps, counter, nbr_idx, nbr_val, neg_idx, deg, bmp);

    dim3 ggrid(N / 64, D / 64, P);
    size_t nd = (size_t)N * D;
    // 3. GCN: X[z] = h @ Wg[z]^T
    gemm_mfma<0><<<ggrid, 256, 0, stream>>>(
        conv + OFF_H, 0, conv + OFF_WG, (size_t)D * D, nullptr, 0, xbuf, nd);
    // 4. emb[z] = prelu(spmm + bias)
    spmm_prelu<<<dim3(N / 4, 1, P), 256, 0, stream>>>(xbuf, nbr_idx, nbr_val, deg, conv, emb);
    // 5+6a. fused: spacc = colsum(tanh(emb@attW^T+attb)); xbuf = elu(emb@W1^T+b1)
    gemm_dual<<<ggrid, 256, 0, stream>>>(emb, conv, xbuf, spacc);
    // 6b+7. q[z] = rownorm(xbuf[z] @ W2^T + b2), fused
    gemm_w2_norm<<<dim3(N / 16, 1, P), 256, 0, stream>>>(xbuf, conv, q);
    // 8+9. sim (both pairs): rowsum/colsum + fused sparse pdrow/pdcol
    sim_mfma<<<dim3(N / 128, N / 128, 2), 256, 0, stream>>>(q, bmp, nbr_idx, nbr_val, deg,
                                                            rowsum, colsum, pdrow, pdcol);
    // 10. node losses (wave per node, partials)
    node_loss_k<<<dim3(N / 4, 1, P), 256, 0, stream>>>(emb, nbr_idx, neg_idx, deg, nlpart);
    // 11. final loss + beta (no atomics)
    reduce_loss_beta<<<1, 256, 0, stream>>>(nlpart, rowsum, colsum, pdrow, pdcol,
                                            spacc, conv, beta, loss);
    // 12. output
    zmp_out<<<(N * D) / 256, 256, 0, stream>>>(emb, beta, loss, counter, d_out);
}

// Round 7
// 507.776 us; speedup vs baseline: 1.6380x; 1.6380x over previous
//
#include <hip/hip_runtime.h>
#include <hip/hip_bf16.h>

// Problem constants (Mp_encoder): N nodes, D dims, P metapaths.
constexpr int N = 4096;
constexpr int D = 256;
constexpr int P = 3;
constexpr int MAXDEG = 17;       // K+1
constexpr float TAU = 0.8f;
constexpr float MARGIN = 0.1f;
constexpr float EPS_PD = 1e-6f;

constexpr int LDP = 40;          // LDS k-stride for 64-tiles (2-way max conflicts)
constexpr int LDK = 72;          // LDS k-stride for sim BK=64 staging

// bf16 conversion-area offsets (elements), all 256-aligned
constexpr int OFF_H    = 0;             // 1048576
constexpr int OFF_WG   = 1048576;       // 196608
constexpr int OFF_ATTW = 1245184;       // 65536
constexpr int OFF_W1   = 1310720;       // 65536
constexpr int OFF_W2   = 1376256;       // 65536
constexpr int OFF_BG   = 1441792;       // 768
constexpr int OFF_ATTB = 1442560;       // 256
constexpr int OFF_AV   = 1442816;       // 256
constexpr int OFF_PA   = 1443072;       // 3 (reserve 256)
constexpr int OFF_B1   = 1443328;       // 256
constexpr int OFF_B2   = 1443584;       // 256
constexpr int CONV_TOTAL = 1443840;

typedef __attribute__((ext_vector_type(8))) short bfrag8;
typedef __attribute__((ext_vector_type(4))) float facc4;

__device__ inline facc4 mfma16(bfrag8 a, bfrag8 b, facc4 c) {
    return __builtin_amdgcn_mfma_f32_16x16x32_bf16(a, b, c, 0, 0, 0);
}
__device__ inline float b2f(__hip_bfloat16 v) { return __bfloat162float(v); }
__device__ inline float bfbits2f(unsigned short u) {
    return __uint_as_float(((unsigned int)u) << 16);
}
__device__ inline unsigned short f2bfbits(float v) {
    __hip_bfloat16 t = __float2bfloat16(v);
    return *(unsigned short*)&t;
}
__device__ inline int get_bf(const int* __restrict__ counter) { return counter[0] > 100; }

__device__ inline float load_in(const void* p, size_t i, int bf) {
    return bf ? __bfloat162float(((const __hip_bfloat16*)p)[i])
              : ((const float*)p)[i];
}

// ---------------------------------------------------------------------------
// 0. dtype detection from mps bit patterns (bf16 ⇒ many nonzero low-halves)
// ---------------------------------------------------------------------------
__global__ void detect_dtype(const unsigned int* __restrict__ w, int nwords,
                             int* __restrict__ counter) {
    int stride = gridDim.x * blockDim.x;
    int c = 0;
    for (int i = blockIdx.x * blockDim.x + threadIdx.x; i < nwords; i += stride) {
        unsigned int x = w[i];
        if ((x & 0xFFFF0000u) == 0u && x != 0u) c++;
    }
    for (int s = 32; s > 0; s >>= 1) c += __shfl_down(c, s);
    if ((threadIdx.x & 63) == 0 && c > 0) atomicAdd(counter, c);
}

// ---------------------------------------------------------------------------
// 1. Convert all dense inputs to a contiguous bf16 staging area.
// ---------------------------------------------------------------------------
__global__ void convert_all(const void* h, const void* wg, const void* attw,
                            const void* w1, const void* w2, const void* bg,
                            const void* attb, const void* av, const void* pa,
                            const void* b1, const void* b2,
                            const int* __restrict__ counter,
                            __hip_bfloat16* __restrict__ dst) {
    int bf = get_bf(counter);
    const void* srcs[11] = {h, wg, attw, w1, w2, bg, attb, av, pa, b1, b2};
    const int offs[11] = {OFF_H, OFF_WG, OFF_ATTW, OFF_W1, OFF_W2, OFF_BG,
                          OFF_ATTB, OFF_AV, OFF_PA, OFF_B1, OFF_B2};
    const int lens[11] = {1048576, 196608, 65536, 65536, 65536, 768, 256, 256, 3, 256, 256};
    int stride = gridDim.x * blockDim.x;
    int t0 = blockIdx.x * blockDim.x + threadIdx.x;
    #pragma unroll
    for (int s = 0; s < 11; s++) {
        for (int i = t0; i < lens[s]; i += stride)
            dst[offs[s] + i] = __float2bfloat16(load_in(srcs[s], i, bf));
    }
}

// ---------------------------------------------------------------------------
// 2. Sparse extraction (per (p,n) row of mps), vectorized 16B loads.
// ---------------------------------------------------------------------------
__global__ void extract_sparse(const void* __restrict__ mps, const int* __restrict__ counter,
                               int* __restrict__ nbr_idx, float* __restrict__ nbr_val,
                               int* __restrict__ neg_idx, int* __restrict__ deg) {
    int bf = get_bf(counter);
    int row = blockIdx.x;              // 0 .. P*N-1
    int t = threadIdx.x;               // 256 threads, 16 elems each
    __shared__ int cnt;
    __shared__ int sidx[32];
    __shared__ float sval[32];
    if (t == 0) cnt = 0;
    __syncthreads();
    int e0 = t * 16;
    if (bf) {
        const uint4* base = (const uint4*)((const __hip_bfloat16*)mps + (size_t)row * N + e0);
        #pragma unroll
        for (int v = 0; v < 2; v++) {
            uint4 w = base[v];
            unsigned int ws[4] = {w.x, w.y, w.z, w.w};
            #pragma unroll
            for (int j = 0; j < 4; j++) {
                unsigned short lo = (unsigned short)(ws[j] & 0xFFFFu);
                unsigned short hi = (unsigned short)(ws[j] >> 16);
                if (lo) { int k = atomicAdd(&cnt, 1); if (k < 32) { sidx[k] = e0 + v * 8 + j * 2;     sval[k] = bfbits2f(lo); } }
                if (hi) { int k = atomicAdd(&cnt, 1); if (k < 32) { sidx[k] = e0 + v * 8 + j * 2 + 1; sval[k] = bfbits2f(hi); } }
            }
        }
    } else {
        const float4* base = (const float4*)((const float*)mps + (size_t)row * N + e0);
        #pragma unroll
        for (int v = 0; v < 4; v++) {
            float4 w = base[v];
            float ws[4] = {w.x, w.y, w.z, w.w};
            #pragma unroll
            for (int j = 0; j < 4; j++)
                if (ws[j] > 0.f) { int k = atomicAdd(&cnt, 1); if (k < 32) { sidx[k] = e0 + v * 4 + j; sval[k] = ws[j]; } }
        }
    }
    __syncthreads();
    if (t == 0) {
        int dg = cnt; if (dg > MAXDEG) dg = MAXDEG;
        for (int i = 1; i < dg; i++) {           // insertion sort by index
            int ki = sidx[i]; float kv = sval[i]; int j = i - 1;
            while (j >= 0 && sidx[j] > ki) { sidx[j+1] = sidx[j]; sval[j+1] = sval[j]; j--; }
            sidx[j+1] = ki; sval[j+1] = kv;
        }
        deg[row] = dg;
        int* oi = nbr_idx + (size_t)row * MAXDEG;
        float* ov = nbr_val + (size_t)row * MAXDEG;
        int* ng = neg_idx + (size_t)row * MAXDEG;
        for (int i = 0; i < MAXDEG; i++) { oi[i] = (i < dg) ? sidx[i] : 0; ov[i] = (i < dg) ? sval[i] : 0.f; }
        int c = 0, j = 0, found = 0;
        while (found < MAXDEG) {
            if (j < dg && sidx[j] == c) { j++; c++; continue; }
            ng[found++] = c++;
        }
    }
}

// ---------------------------------------------------------------------------
// 3. MFMA GEMM: C[z][r][c] = sum_k A[z][r][k]*B[z][c][k] (+bias)
//    64x64 tile, BK=32, 4 waves of 32x32. Used for the X-stage.
// ---------------------------------------------------------------------------
template <int ACT>
__global__ void gemm_mfma(const __hip_bfloat16* __restrict__ Abase, size_t strideA,
                          const __hip_bfloat16* __restrict__ Bbase, size_t strideB,
                          const __hip_bfloat16* __restrict__ bias, size_t strideBias,
                          __hip_bfloat16* __restrict__ Cbase, size_t strideC) {
    int z = blockIdx.z;
    const __hip_bfloat16* A = Abase + (size_t)z * strideA;
    const __hip_bfloat16* B = Bbase + (size_t)z * strideB;
    __shared__ __align__(16) __hip_bfloat16 As[64 * LDP];
    __shared__ __align__(16) __hip_bfloat16 Bs[64 * LDP];
    int bm = blockIdx.x * 64, bn = blockIdx.y * 64;
    int tid = threadIdx.x, wave = tid >> 6, lane = tid & 63;
    int quad = lane >> 4, l15 = lane & 15;
    int wr = (wave & 1) * 32, wc = (wave >> 1) * 32;
    facc4 acc[2][2] = {};
    int sr = tid >> 2, kq = (tid & 3) * 8;
    for (int k0 = 0; k0 < D; k0 += 32) {
        *(bfrag8*)&As[sr * LDP + kq] = *(const bfrag8*)&A[(size_t)(bm + sr) * D + k0 + kq];
        *(bfrag8*)&Bs[sr * LDP + kq] = *(const bfrag8*)&B[(size_t)(bn + sr) * D + k0 + kq];
        __syncthreads();
        bfrag8 af[2], bfr[2];
        #pragma unroll
        for (int mi = 0; mi < 2; mi++)
            af[mi] = *(const bfrag8*)&As[(wr + mi * 16 + l15) * LDP + quad * 8];
        #pragma unroll
        for (int ni = 0; ni < 2; ni++)
            bfr[ni] = *(const bfrag8*)&Bs[(wc + ni * 16 + l15) * LDP + quad * 8];
        #pragma unroll
        for (int mi = 0; mi < 2; mi++)
            #pragma unroll
            for (int ni = 0; ni < 2; ni++)
                acc[mi][ni] = mfma16(af[mi], bfr[ni], acc[mi][ni]);
        __syncthreads();
    }
    #pragma unroll
    for (int mi = 0; mi < 2; mi++) {
        #pragma unroll
        for (int ni = 0; ni < 2; ni++) {
            int col = bn + wc + ni * 16 + l15;
            #pragma unroll
            for (int r = 0; r < 4; r++) {
                int row = bm + wr + mi * 16 + quad * 4 + r;
                float v = acc[mi][ni][r];
                if (bias) v += b2f(bias[col]);
                if (ACT == 1) v = v > 0.f ? v : expm1f(v);
                Cbase[(size_t)z * strideC + (size_t)row * D + col] = __float2bfloat16(v);
            }
        }
    }
}

// ---------------------------------------------------------------------------
// 3b. Fused dual-B GEMM over emb: shares A staging.
//     path 1: tanh(emb@attW^T + attb) → column-sum into spacc (no C write)
//     path 2: elu(emb@W1^T + b1) → xbuf
// ---------------------------------------------------------------------------
__global__ void gemm_dual(const __hip_bfloat16* __restrict__ embBase,
                          const __hip_bfloat16* __restrict__ conv,
                          __hip_bfloat16* __restrict__ xbuf,
                          float* __restrict__ spacc) {
    int z = blockIdx.z;
    const __hip_bfloat16* A = embBase + (size_t)z * N * D;
    const __hip_bfloat16* Ba = conv + OFF_ATTW;
    const __hip_bfloat16* Bw = conv + OFF_W1;
    __shared__ __align__(16) __hip_bfloat16 As[64 * LDP];
    __shared__ __align__(16) __hip_bfloat16 Bsa[64 * LDP];
    __shared__ __align__(16) __hip_bfloat16 Bsw[64 * LDP];
    int bm = blockIdx.x * 64, bn = blockIdx.y * 64;
    int tid = threadIdx.x, wave = tid >> 6, lane = tid & 63;
    int quad = lane >> 4, l15 = lane & 15;
    int wr = (wave & 1) * 32, wc = (wave >> 1) * 32;
    facc4 accA[2][2] = {};
    facc4 accW[2][2] = {};
    int sr = tid >> 2, kq = (tid & 3) * 8;
    for (int k0 = 0; k0 < D; k0 += 32) {
        *(bfrag8*)&As[sr * LDP + kq]  = *(const bfrag8*)&A[(size_t)(bm + sr) * D + k0 + kq];
        *(bfrag8*)&Bsa[sr * LDP + kq] = *(const bfrag8*)&Ba[(size_t)(bn + sr) * D + k0 + kq];
        *(bfrag8*)&Bsw[sr * LDP + kq] = *(const bfrag8*)&Bw[(size_t)(bn + sr) * D + k0 + kq];
        __syncthreads();
        bfrag8 af[2], ba[2], bw[2];
        #pragma unroll
        for (int mi = 0; mi < 2; mi++)
            af[mi] = *(const bfrag8*)&As[(wr + mi * 16 + l15) * LDP + quad * 8];
        #pragma unroll
        for (int ni = 0; ni < 2; ni++) {
            ba[ni] = *(const bfrag8*)&Bsa[(wc + ni * 16 + l15) * LDP + quad * 8];
            bw[ni] = *(const bfrag8*)&Bsw[(wc + ni * 16 + l15) * LDP + quad * 8];
        }
        #pragma unroll
        for (int mi = 0; mi < 2; mi++)
            #pragma unroll
            for (int ni = 0; ni < 2; ni++) {
                accA[mi][ni] = mfma16(af[mi], ba[ni], accA[mi][ni]);
                accW[mi][ni] = mfma16(af[mi], bw[ni], accW[mi][ni]);
            }
        __syncthreads();
    }
    float cs[2] = {0.f, 0.f};
    #pragma unroll
    for (int mi = 0; mi < 2; mi++) {
        #pragma unroll
        for (int ni = 0; ni < 2; ni++) {
            int col = bn + wc + ni * 16 + l15;
            float battb = b2f(conv[OFF_ATTB + col]);
            float bb1   = b2f(conv[OFF_B1 + col]);
            #pragma unroll
            for (int r = 0; r < 4; r++) {
                int row = bm + wr + mi * 16 + quad * 4 + r;
                cs[ni] += tanhf(accA[mi][ni][r] + battb);
                float v = accW[mi][ni][r] + bb1;
                v = v > 0.f ? v : expm1f(v);
                xbuf[(size_t)z * N * D + (size_t)row * D + col] = __float2bfloat16(v);
            }
        }
    }
    #pragma unroll
    for (int ni = 0; ni < 2; ni++) {
        float v = cs[ni];
        v += __shfl_xor(v, 16); v += __shfl_xor(v, 32);
        if (quad == 0) {
            int col = bn + wc + ni * 16 + l15;
            atomicAdd(&spacc[(size_t)z * D + col], v);
        }
    }
}

// ---------------------------------------------------------------------------
// 3c. proj2 GEMM with fused row-normalize: block = 16 rows × all 256 cols.
//     q[z][r][:] = normalize( xbuf[z][r][:] @ W2^T + b2 )
// ---------------------------------------------------------------------------
__global__ void gemm_w2_norm(const __hip_bfloat16* __restrict__ xbase,
                             const __hip_bfloat16* __restrict__ conv,
                             __hip_bfloat16* __restrict__ qbase) {
    int z = blockIdx.z;
    const __hip_bfloat16* A = xbase + (size_t)z * N * D;
    const __hip_bfloat16* B = conv + OFF_W2;
    __shared__ __align__(16) __hip_bfloat16 As[16 * LDP];
    __shared__ __align__(16) __hip_bfloat16 Bs[256 * LDP];
    __shared__ float sred[4][16];
    int bm = blockIdx.x * 16;
    int tid = threadIdx.x, wave = tid >> 6, lane = tid & 63;
    int quad = lane >> 4, l15 = lane & 15;
    int wc = wave * 64;
    facc4 acc[4] = {};
    for (int k0 = 0; k0 < D; k0 += 32) {
        if (tid < 64) {
            int r = tid >> 2, kq = (tid & 3) * 8;
            *(bfrag8*)&As[r * LDP + kq] = *(const bfrag8*)&A[(size_t)(bm + r) * D + k0 + kq];
        }
        #pragma unroll
        for (int i = 0; i < 4; i++) {
            int f = tid + 256 * i;          // 1024 fragments of B
            int r = f >> 2, kq = (f & 3) * 8;
            *(bfrag8*)&Bs[r * LDP + kq] = *(const bfrag8*)&B[(size_t)r * D + k0 + kq];
        }
        __syncthreads();
        bfrag8 af = *(const bfrag8*)&As[l15 * LDP + quad * 8];
        #pragma unroll
        for (int ni = 0; ni < 4; ni++) {
            bfrag8 bf = *(const bfrag8*)&Bs[(wc + ni * 16 + l15) * LDP + quad * 8];
            acc[ni] = mfma16(af, bf, acc[ni]);
        }
        __syncthreads();
    }
    float vv[4][4];   // [ni][r], bias applied
    #pragma unroll
    for (int ni = 0; ni < 4; ni++) {
        float bb = b2f(conv[OFF_B2 + wc + ni * 16 + l15]);
        #pragma unroll
        for (int r = 0; r < 4; r++) vv[ni][r] = acc[ni][r] + bb;
    }
    #pragma unroll
    for (int r = 0; r < 4; r++) {
        float ss = vv[0][r] * vv[0][r] + vv[1][r] * vv[1][r] +
                   vv[2][r] * vv[2][r] + vv[3][r] * vv[3][r];
        ss += __shfl_xor(ss, 1); ss += __shfl_xor(ss, 2);
        ss += __shfl_xor(ss, 4); ss += __shfl_xor(ss, 8);
        if (l15 == 0) sred[wave][quad * 4 + r] = ss;
    }
    __syncthreads();
    #pragma unroll
    for (int r = 0; r < 4; r++) {
        int rl = quad * 4 + r;
        float ssum = sred[0][rl] + sred[1][rl] + sred[2][rl] + sred[3][rl];
        float inv = rsqrtf(ssum + 1e-30f);
        int row = bm + rl;
        #pragma unroll
        for (int ni = 0; ni < 4; ni++)
            qbase[(size_t)z * N * D + (size_t)row * D + wc + ni * 16 + l15] =
                __float2bfloat16(vv[ni][r] * inv);
    }
}

// ---------------------------------------------------------------------------
// 4. spmm + prelu: wave per node, ushort4 loads/stores.
// ---------------------------------------------------------------------------
__global__ void spmm_prelu(const __hip_bfloat16* __restrict__ Xbase,
                           const int* __restrict__ nbr_idx, const float* __restrict__ nbr_val,
                           const int* __restrict__ deg, const __hip_bfloat16* __restrict__ conv,
                           __hip_bfloat16* __restrict__ embBase) {
    int z = blockIdx.z;
    int wave = threadIdx.x >> 6, lane = threadIdx.x & 63;
    int n = blockIdx.x * 4 + wave;
    const __hip_bfloat16* X = Xbase + (size_t)z * N * D;
    const int* idx = nbr_idx + ((size_t)z * N + n) * MAXDEG;
    const float* val = nbr_val + ((size_t)z * N + n) * MAXDEG;
    int dg = deg[z * N + n];
    float acc[4] = {0.f, 0.f, 0.f, 0.f};
    for (int k = 0; k < dg; k++) {
        int j = idx[k];
        float vk = val[k];
        ushort4 x = *(const ushort4*)&X[(size_t)j * D + lane * 4];
        acc[0] += vk * bfbits2f(x.x); acc[1] += vk * bfbits2f(x.y);
        acc[2] += vk * bfbits2f(x.z); acc[3] += vk * bfbits2f(x.w);
    }
    ushort4 bb = *(const ushort4*)&conv[OFF_BG + z * D + lane * 4];
    float b[4] = {bfbits2f(bb.x), bfbits2f(bb.y), bfbits2f(bb.z), bfbits2f(bb.w)};
    float a = b2f(conv[OFF_PA + z]);
    ushort4 o;
    float v0 = acc[0] + b[0]; o.x = f2bfbits(v0 > 0.f ? v0 : a * v0);
    float v1 = acc[1] + b[1]; o.y = f2bfbits(v1 > 0.f ? v1 : a * v1);
    float v2 = acc[2] + b[2]; o.z = f2bfbits(v2 > 0.f ? v2 : a * v2);
    float v3 = acc[3] + b[3]; o.w = f2bfbits(v3 > 0.f ? v3 : a * v3);
    *(ushort4*)&embBase[(size_t)z * N * D + (size_t)n * D + lane * 4] = o;
}

// ---------------------------------------------------------------------------
// 6. sim MFMA: per pair z, S = exp(Qz @ Q2^T / TAU) → rowsum/colsum atomics.
//    128x128 tile, 4 waves of 64x64 (16 accs), BK=64.
// ---------------------------------------------------------------------------
__global__ void sim_mfma(const __hip_bfloat16* __restrict__ q,
                         float* __restrict__ rowsum, float* __restrict__ colsum) {
    int pair = blockIdx.z;
    const __hip_bfloat16* Qa = q + (size_t)pair * N * D;
    const __hip_bfloat16* Qb = q + (size_t)2 * N * D;
    __shared__ __align__(16) __hip_bfloat16 As[128 * LDK];
    __shared__ __align__(16) __hip_bfloat16 Bs[128 * LDK];
    int bm = blockIdx.x * 128, bn = blockIdx.y * 128;
    int tid = threadIdx.x, wave = tid >> 6, lane = tid & 63;
    int quad = lane >> 4, l15 = lane & 15;
    int wr = (wave & 1) * 64, wc = (wave >> 1) * 64;
    facc4 acc[4][4] = {};
    int sr0 = tid >> 3, kq = (tid & 7) * 8;      // 32 rows per chunk, 64 k-cols
    for (int k0 = 0; k0 < D; k0 += 64) {
        #pragma unroll
        for (int i = 0; i < 4; i++) {
            int r = sr0 + 32 * i;
            *(bfrag8*)&As[r * LDK + kq] = *(const bfrag8*)&Qa[(size_t)(bm + r) * D + k0 + kq];
            *(bfrag8*)&Bs[r * LDK + kq] = *(const bfrag8*)&Qb[(size_t)(bn + r) * D + k0 + kq];
        }
        __syncthreads();
        #pragma unroll
        for (int kk = 0; kk < 64; kk += 32) {
            bfrag8 af[4], bfr[4];
            #pragma unroll
            for (int mi = 0; mi < 4; mi++)
                af[mi] = *(const bfrag8*)&As[(wr + mi * 16 + l15) * LDK + kk + quad * 8];
            #pragma unroll
            for (int ni = 0; ni < 4; ni++)
                bfr[ni] = *(const bfrag8*)&Bs[(wc + ni * 16 + l15) * LDK + kk + quad * 8];
            #pragma unroll
            for (int mi = 0; mi < 4; mi++)
                #pragma unroll
                for (int ni = 0; ni < 4; ni++)
                    acc[mi][ni] = mfma16(af[mi], bfr[ni], acc[mi][ni]);
        }
        __syncthreads();
    }
    constexpr float invtau = 1.0f / TAU;
    float rs[4][4];   // [mi][r]
    float cs[4] = {0.f, 0.f, 0.f, 0.f};
    #pragma unroll
    for (int mi = 0; mi < 4; mi++)
        #pragma unroll
        for (int r = 0; r < 4; r++) rs[mi][r] = 0.f;
    #pragma unroll
    for (int mi = 0; mi < 4; mi++)
        #pragma unroll
        for (int ni = 0; ni < 4; ni++)
            #pragma unroll
            for (int r = 0; r < 4; r++) {
                float e = __expf(acc[mi][ni][r] * invtau);
                rs[mi][r] += e;
                cs[ni] += e;
            }
    #pragma unroll
    for (int mi = 0; mi < 4; mi++)
        #pragma unroll
        for (int r = 0; r < 4; r++) {
            float v = rs[mi][r];
            v += __shfl_xor(v, 1); v += __shfl_xor(v, 2);
            v += __shfl_xor(v, 4); v += __shfl_xor(v, 8);
            rs[mi][r] = v;
        }
    if (l15 == 0) {
        #pragma unroll
        for (int mi = 0; mi < 4; mi++)
            #pragma unroll
            for (int r = 0; r < 4; r++)
                atomicAdd(&rowsum[(size_t)pair * N + bm + wr + mi * 16 + quad * 4 + r], rs[mi][r]);
    }
    #pragma unroll
    for (int ni = 0; ni < 4; ni++) {
        float v = cs[ni];
        v += __shfl_xor(v, 16); v += __shfl_xor(v, 32);
        if (quad == 0)
            atomicAdd(&colsum[(size_t)pair * N + bn + wc + ni * 16 + l15], v);
    }
}

// ---------------------------------------------------------------------------
// 7. pos-weighted sums, one wave per node, vector loads.
// ---------------------------------------------------------------------------
__global__ void posdot(const __hip_bfloat16* __restrict__ q,
                       const int* __restrict__ nbr_idx, const float* __restrict__ nbr_val,
                       const int* __restrict__ deg,
                       float* __restrict__ pdrow, float* __restrict__ pdcol) {
    int pair = blockIdx.z;
    int wave = threadIdx.x >> 6, lane = threadIdx.x & 63;
    int n = blockIdx.x * 4 + wave;
    const __hip_bfloat16* Qa = q + (size_t)pair * N * D;
    const __hip_bfloat16* Qb = q + (size_t)2 * N * D;
    int dg = deg[pair * N + n];
    const int* idx = nbr_idx + ((size_t)pair * N + n) * MAXDEG;
    const float* val = nbr_val + ((size_t)pair * N + n) * MAXDEG;
    const float invtau = 1.0f / TAU;
    ushort4 ar = *(const ushort4*)&Qa[(size_t)n * D + lane * 4];
    ushort4 br = *(const ushort4*)&Qb[(size_t)n * D + lane * 4];
    float a[4] = {bfbits2f(ar.x), bfbits2f(ar.y), bfbits2f(ar.z), bfbits2f(ar.w)};
    float b[4] = {bfbits2f(br.x), bfbits2f(br.y), bfbits2f(br.z), bfbits2f(br.w)};
    float sr = 0.f, sc = 0.f;
    for (int k = 0; k < dg; k++) {
        int j = idx[k];
        ushort4 pj = *(const ushort4*)&Qb[(size_t)j * D + lane * 4];
        ushort4 aj = *(const ushort4*)&Qa[(size_t)j * D + lane * 4];
        float dr = a[0] * bfbits2f(pj.x) + a[1] * bfbits2f(pj.y) +
                   a[2] * bfbits2f(pj.z) + a[3] * bfbits2f(pj.w);
        float dc = b[0] * bfbits2f(aj.x) + b[1] * bfbits2f(aj.y) +
                   b[2] * bfbits2f(aj.z) + b[3] * bfbits2f(aj.w);
        #pragma unroll
        for (int s = 1; s <= 32; s <<= 1) { dr += __shfl_xor(dr, s); dc += __shfl_xor(dc, s); }
        sr += __expf(dr * invtau) * val[k];
        sc += __expf(dc * invtau) * val[k];
    }
    if (lane == 0) { pdrow[pair * N + n] = sr; pdcol[pair * N + n] = sc; }
}

// ---------------------------------------------------------------------------
// 8. node loss: one wave per node, partials to buffer (no atomics).
// ---------------------------------------------------------------------------
__global__ void node_loss_k(const __hip_bfloat16* __restrict__ embBase,
                            const int* __restrict__ nbr_idx, const int* __restrict__ neg_idx,
                            const int* __restrict__ deg, float* __restrict__ nlpart) {
    int z = blockIdx.z;
    int wave = threadIdx.x >> 6, lane = threadIdx.x & 63;
    int n = blockIdx.x * 4 + wave;
    const __hip_bfloat16* emb = embBase + (size_t)z * N * D;
    int dg = deg[z * N + n];
    const int* ip = nbr_idx + ((size_t)z * N + n) * MAXDEG;
    const int* ig = neg_idx + ((size_t)z * N + n) * MAXDEG;
    ushort4 ar = *(const ushort4*)&emb[(size_t)n * D + lane * 4];
    float a[4] = {bfbits2f(ar.x), bfbits2f(ar.y), bfbits2f(ar.z), bfbits2f(ar.w)};
    float s = 0.f;
    for (int k = 0; k < dg; k++) {
        int jp = ip[k], jn = ig[k];
        ushort4 pr = *(const ushort4*)&emb[(size_t)jp * D + lane * 4];
        ushort4 nr = *(const ushort4*)&emb[(size_t)jn * D + lane * 4];
        float pv[4] = {bfbits2f(pr.x), bfbits2f(pr.y), bfbits2f(pr.z), bfbits2f(pr.w)};
        float nv[4] = {bfbits2f(nr.x), bfbits2f(nr.y), bfbits2f(nr.z), bfbits2f(nr.w)};
        float dp = 0.f, dn = 0.f;
        #pragma unroll
        for (int i = 0; i < 4; i++) {
            float x = a[i] - pv[i] + EPS_PD; dp += x * x;
            float y = a[i] - nv[i] + EPS_PD; dn += y * y;
        }
        #pragma unroll
        for (int st = 1; st <= 32; st <<= 1) { dp += __shfl_xor(dp, st); dn += __shfl_xor(dn, st); }
        float v = dp - dn + MARGIN;
        s += v > 0.f ? v : 0.f;
    }
    if (lane == 0) nlpart[z * N + n] = s / (float)dg;
}

// ---------------------------------------------------------------------------
// 9. final loss + beta: single block, no atomics.
// ---------------------------------------------------------------------------
__global__ void reduce_loss_beta(const float* __restrict__ nlpart,
                                 const float* __restrict__ rowsum, const float* __restrict__ colsum,
                                 const float* __restrict__ pdrow, const float* __restrict__ pdcol,
                                 const float* __restrict__ spacc,
                                 const __hip_bfloat16* __restrict__ conv,
                                 float* __restrict__ beta, float* __restrict__ loss) {
    int t = threadIdx.x;
    __shared__ float red[256];
    __shared__ float w[P];
    for (int p = 0; p < P; p++) {
        float v = (spacc[p * D + t] / (float)N) * b2f(conv[OFF_AV + t]);
        red[t] = v;
        __syncthreads();
        for (int s = 128; s > 0; s >>= 1) { if (t < s) red[t] += red[t + s]; __syncthreads(); }
        if (t == 0) w[p] = red[0];
        __syncthreads();
    }
    float s = 0.f;
    for (int i = t; i < P * N; i += 256) s += nlpart[i];
    for (int i = t; i < 2 * N; i += 256) {
        float l12 = -logf(pdrow[i] / (rowsum[i] + 1e-8f));
        float l21 = -logf(pdcol[i] / (colsum[i] + 1e-8f));
        s += (0.5f * l12 + 0.5f * l21) / (float)N;
    }
    red[t] = s;
    __syncthreads();
    for (int st = 128; st > 0; st >>= 1) { if (t < st) red[t] += red[t + st]; __syncthreads(); }
    if (t == 0) {
        loss[0] = red[0];
        float m = fmaxf(w[0], fmaxf(w[1], w[2]));
        float e0 = __expf(w[0] - m), e1 = __expf(w[1] - m), e2 = __expf(w[2] - m);
        float ssum = e0 + e1 + e2;
        beta[0] = e0 / ssum; beta[1] = e1 / ssum; beta[2] = e2 / ssum;
    }
}

// ---------------------------------------------------------------------------
// 10. z_mp output + loss scalar (output dtype follows detected input dtype)
// ---------------------------------------------------------------------------
__global__ void zmp_out(const __hip_bfloat16* __restrict__ embBase, const float* __restrict__ beta,
                        const float* __restrict__ loss, const int* __restrict__ counter,
                        void* __restrict__ out) {
    int bf = get_bf(counter);
    int i = blockIdx.x * 256 + threadIdx.x;
    float v = beta[0] * b2f(embBase[i]) + beta[1] * b2f(embBase[(size_t)N * D + i]) +
              beta[2] * b2f(embBase[(size_t)2 * N * D + i]);
    if (bf) {
        __hip_bfloat16* o = (__hip_bfloat16*)out;
        o[i] = __float2bfloat16(v);
        if (i == 0) o[(size_t)N * D] = __float2bfloat16(*loss);
    } else {
        float* o = (float*)out;
        o[i] = v;
        if (i == 0) o[(size_t)N * D] = *loss;
    }
}

extern "C" void kernel_launch(void* const* d_in, const int* in_sizes, int n_in,
                              void* d_out, int out_size, void* d_ws, size_t ws_size,
                              hipStream_t stream) {
    const void* h        = d_in[0];
    const void* mps      = d_in[1];
    const void* W_gcn    = d_in[2];
    const void* b_gcn    = d_in[3];
    const void* prelu_a  = d_in[4];
    const void* att_fc_W = d_in[5];
    const void* att_fc_b = d_in[6];
    const void* att_vec  = d_in[7];
    const void* proj_W1  = d_in[8];
    const void* proj_b1  = d_in[9];
    const void* proj_W2  = d_in[10];
    const void* proj_b2  = d_in[11];

    char* ws = (char*)d_ws;
    size_t off = 0;
    auto alloc = [&](size_t bytes) -> char* {
        char* p = ws + off;
        off = (off + bytes + 255) & ~(size_t)255;
        return p;
    };
    __hip_bfloat16* conv = (__hip_bfloat16*)alloc((size_t)CONV_TOTAL * 2);
    __hip_bfloat16* xbuf = (__hip_bfloat16*)alloc((size_t)P * N * D * 2);
    __hip_bfloat16* emb  = (__hip_bfloat16*)alloc((size_t)P * N * D * 2);
    __hip_bfloat16* q    = (__hip_bfloat16*)alloc((size_t)P * N * D * 2);
    int*   nbr_idx = (int*)alloc((size_t)P * N * MAXDEG * 4);
    float* nbr_val = (float*)alloc((size_t)P * N * MAXDEG * 4);
    int*   neg_idx = (int*)alloc((size_t)P * N * MAXDEG * 4);
    int*   deg     = (int*)alloc((size_t)P * N * 4);
    float* nlpart  = (float*)alloc((size_t)P * N * 4);
    float* pdrow   = (float*)alloc((size_t)2 * N * 4);
    float* pdcol   = (float*)alloc((size_t)2 * N * 4);
    char* zero_begin = ws + off;
    float* rowsum = (float*)alloc((size_t)2 * N * 4);
    float* colsum = (float*)alloc((size_t)2 * N * 4);
    float* spacc  = (float*)alloc((size_t)P * D * 4);
    float* beta   = (float*)alloc(16);
    float* loss   = (float*)alloc(16);
    int*   counter = (int*)alloc(16);
    size_t zero_bytes = (size_t)((ws + off) - zero_begin);
    hipMemsetAsync(zero_begin, 0, zero_bytes, stream);

    // 0. dtype detection
    detect_dtype<<<1024, 256, 0, stream>>>((const unsigned int*)mps, 2 * 1024 * 1024, counter);

    // 1. convert dense inputs to bf16 staging
    convert_all<<<512, 256, 0, stream>>>(h, W_gcn, att_fc_W, proj_W1, proj_W2, b_gcn,
                                         att_fc_b, att_vec, prelu_a, proj_b1, proj_b2,
                                         counter, conv);

    // 2. sparse extraction
    extract_sparse<<<P * N, 256, 0, stream>>>(mps, counter, nbr_idx, nbr_val, neg_idx, deg);

    dim3 ggrid(N / 64, D / 64, P);
    size_t nd = (size_t)N * D;
    // 3. GCN: X[z] = h @ Wg[z]^T
    gemm_mfma<0><<<ggrid, 256, 0, stream>>>(
        conv + OFF_H, 0, conv + OFF_WG, (size_t)D * D, nullptr, 0, xbuf, nd);
    // 4. emb[z] = prelu(spmm + bias)
    spmm_prelu<<<dim3(N / 4, 1, P), 256, 0, stream>>>(xbuf, nbr_idx, nbr_val, deg, conv, emb);
    // 5+6a. fused: spacc = colsum(tanh(emb@attW^T+attb)); xbuf = elu(emb@W1^T+b1)
    gemm_dual<<<ggrid, 256, 0, stream>>>(emb, conv, xbuf, spacc);
    // 6b+7. q[z] = rownorm(xbuf[z] @ W2^T + b2), fused
    gemm_w2_norm<<<dim3(N / 16, 1, P), 256, 0, stream>>>(xbuf, conv, q);
    // 8. sim (both pairs batched): rowsum/colsum
    sim_mfma<<<dim3(N / 128, N / 128, 2), 256, 0, stream>>>(q, rowsum, colsum);
    // 9. pos-weighted sums (wave per node)
    posdot<<<dim3(N / 4, 1, 2), 256, 0, stream>>>(q, nbr_idx, nbr_val, deg, pdrow, pdcol);
    // 10. node losses (wave per node, partials)
    node_loss_k<<<dim3(N / 4, 1, P), 256, 0, stream>>>(emb, nbr_idx, neg_idx, deg, nlpart);
    // 11. final loss + beta (no atomics)
    reduce_loss_beta<<<1, 256, 0, stream>>>(nlpart, rowsum, colsum, pdrow, pdcol,
                                            spacc, conv, beta, loss);
    // 12. output
    zmp_out<<<(N * D) / 256, 256, 0, stream>>>(emb, beta, loss, counter, d_out);
}

// Round 8
// 499.256 us; speedup vs baseline: 1.6660x; 1.0171x over previous
//
#include <hip/hip_runtime.h>
#include <hip/hip_bf16.h>

// Problem constants (Mp_encoder): N nodes, D dims, P metapaths.
constexpr int N = 4096;
constexpr int D = 256;
constexpr int P = 3;
constexpr int MAXDEG = 17;       // K+1
constexpr float TAU = 0.8f;
constexpr float MARGIN = 0.1f;
constexpr float EPS_PD = 1e-6f;

constexpr int LDP = 40;          // LDS k-stride for 64-tiles (2-way max conflicts)

// bf16 conversion-area offsets (elements), all 256-aligned
constexpr int OFF_H    = 0;             // 1048576
constexpr int OFF_WG   = 1048576;       // 196608
constexpr int OFF_ATTW = 1245184;       // 65536
constexpr int OFF_W1   = 1310720;       // 65536
constexpr int OFF_W2   = 1376256;       // 65536
constexpr int OFF_BG   = 1441792;       // 768
constexpr int OFF_ATTB = 1442560;       // 256
constexpr int OFF_AV   = 1442816;       // 256
constexpr int OFF_PA   = 1443072;       // 3 (reserve 256)
constexpr int OFF_B1   = 1443328;       // 256
constexpr int OFF_B2   = 1443584;       // 256
constexpr int CONV_TOTAL = 1443840;

typedef __attribute__((ext_vector_type(8))) short bfrag8;
typedef __attribute__((ext_vector_type(4))) float facc4;

__device__ inline facc4 mfma16(bfrag8 a, bfrag8 b, facc4 c) {
    return __builtin_amdgcn_mfma_f32_16x16x32_bf16(a, b, c, 0, 0, 0);
}
__device__ inline float b2f(__hip_bfloat16 v) { return __bfloat162float(v); }
__device__ inline float bfbits2f(unsigned short u) {
    return __uint_as_float(((unsigned int)u) << 16);
}
__device__ inline unsigned short f2bfbits(float v) {
    __hip_bfloat16 t = __float2bfloat16(v);
    return *(unsigned short*)&t;
}
__device__ inline int get_bf(const int* __restrict__ counter) { return counter[0] > 100; }

__device__ inline float load_in(const void* p, size_t i, int bf) {
    return bf ? __bfloat162float(((const __hip_bfloat16*)p)[i])
              : ((const float*)p)[i];
}

// async global->LDS, 16 bytes per lane; dest = wave-uniform base + lane*16
__device__ __forceinline__ void gl_lds16(const __hip_bfloat16* g, __hip_bfloat16* l) {
    __builtin_amdgcn_global_load_lds(
        (const __attribute__((address_space(1))) unsigned int*)g,
        (__attribute__((address_space(3))) unsigned int*)l, 16, 0, 0);
}

// ---------------------------------------------------------------------------
// 0. dtype detection from mps bit patterns (bf16 ⇒ many nonzero low-halves)
// ---------------------------------------------------------------------------
__global__ void detect_dtype(const unsigned int* __restrict__ w, int nwords,
                             int* __restrict__ counter) {
    int stride = gridDim.x * blockDim.x;
    int c = 0;
    for (int i = blockIdx.x * blockDim.x + threadIdx.x; i < nwords; i += stride) {
        unsigned int x = w[i];
        if ((x & 0xFFFF0000u) == 0u && x != 0u) c++;
    }
    for (int s = 32; s > 0; s >>= 1) c += __shfl_down(c, s);
    if ((threadIdx.x & 63) == 0 && c > 0) atomicAdd(counter, c);
}

// ---------------------------------------------------------------------------
// 1. Convert all dense inputs to a contiguous bf16 staging area.
// ---------------------------------------------------------------------------
__global__ void convert_all(const void* h, const void* wg, const void* attw,
                            const void* w1, const void* w2, const void* bg,
                            const void* attb, const void* av, const void* pa,
                            const void* b1, const void* b2,
                            const int* __restrict__ counter,
                            __hip_bfloat16* __restrict__ dst) {
    int bf = get_bf(counter);
    const void* srcs[11] = {h, wg, attw, w1, w2, bg, attb, av, pa, b1, b2};
    const int offs[11] = {OFF_H, OFF_WG, OFF_ATTW, OFF_W1, OFF_W2, OFF_BG,
                          OFF_ATTB, OFF_AV, OFF_PA, OFF_B1, OFF_B2};
    const int lens[11] = {1048576, 196608, 65536, 65536, 65536, 768, 256, 256, 3, 256, 256};
    int stride = gridDim.x * blockDim.x;
    int t0 = blockIdx.x * blockDim.x + threadIdx.x;
    #pragma unroll
    for (int s = 0; s < 11; s++) {
        for (int i = t0; i < lens[s]; i += stride)
            dst[offs[s] + i] = __float2bfloat16(load_in(srcs[s], i, bf));
    }
}

// ---------------------------------------------------------------------------
// 2. Sparse extraction (per (p,n) row of mps), vectorized 16B loads.
// ---------------------------------------------------------------------------
__global__ void extract_sparse(const void* __restrict__ mps, const int* __restrict__ counter,
                               int* __restrict__ nbr_idx, float* __restrict__ nbr_val,
                               int* __restrict__ neg_idx, int* __restrict__ deg) {
    int bf = get_bf(counter);
    int row = blockIdx.x;              // 0 .. P*N-1
    int t = threadIdx.x;               // 256 threads, 16 elems each
    __shared__ int cnt;
    __shared__ int sidx[32];
    __shared__ float sval[32];
    if (t == 0) cnt = 0;
    __syncthreads();
    int e0 = t * 16;
    if (bf) {
        const uint4* base = (const uint4*)((const __hip_bfloat16*)mps + (size_t)row * N + e0);
        #pragma unroll
        for (int v = 0; v < 2; v++) {
            uint4 w = base[v];
            unsigned int ws[4] = {w.x, w.y, w.z, w.w};
            #pragma unroll
            for (int j = 0; j < 4; j++) {
                unsigned short lo = (unsigned short)(ws[j] & 0xFFFFu);
                unsigned short hi = (unsigned short)(ws[j] >> 16);
                if (lo) { int k = atomicAdd(&cnt, 1); if (k < 32) { sidx[k] = e0 + v * 8 + j * 2;     sval[k] = bfbits2f(lo); } }
                if (hi) { int k = atomicAdd(&cnt, 1); if (k < 32) { sidx[k] = e0 + v * 8 + j * 2 + 1; sval[k] = bfbits2f(hi); } }
            }
        }
    } else {
        const float4* base = (const float4*)((const float*)mps + (size_t)row * N + e0);
        #pragma unroll
        for (int v = 0; v < 4; v++) {
            float4 w = base[v];
            float ws[4] = {w.x, w.y, w.z, w.w};
            #pragma unroll
            for (int j = 0; j < 4; j++)
                if (ws[j] > 0.f) { int k = atomicAdd(&cnt, 1); if (k < 32) { sidx[k] = e0 + v * 4 + j; sval[k] = ws[j]; } }
        }
    }
    __syncthreads();
    if (t == 0) {
        int dg = cnt; if (dg > MAXDEG) dg = MAXDEG;
        for (int i = 1; i < dg; i++) {           // insertion sort by index
            int ki = sidx[i]; float kv = sval[i]; int j = i - 1;
            while (j >= 0 && sidx[j] > ki) { sidx[j+1] = sidx[j]; sval[j+1] = sval[j]; j--; }
            sidx[j+1] = ki; sval[j+1] = kv;
        }
        deg[row] = dg;
        int* oi = nbr_idx + (size_t)row * MAXDEG;
        float* ov = nbr_val + (size_t)row * MAXDEG;
        int* ng = neg_idx + (size_t)row * MAXDEG;
        for (int i = 0; i < MAXDEG; i++) { oi[i] = (i < dg) ? sidx[i] : 0; ov[i] = (i < dg) ? sval[i] : 0.f; }
        int c = 0, j = 0, found = 0;
        while (found < MAXDEG) {
            if (j < dg && sidx[j] == c) { j++; c++; continue; }
            ng[found++] = c++;
        }
    }
}

// ---------------------------------------------------------------------------
// 3. MFMA GEMM: C[z][r][c] = sum_k A[z][r][k]*B[z][c][k] (+bias)
//    64x64 tile, BK=32, 4 waves of 32x32. Used for the X-stage.
// ---------------------------------------------------------------------------
template <int ACT>
__global__ void gemm_mfma(const __hip_bfloat16* __restrict__ Abase, size_t strideA,
                          const __hip_bfloat16* __restrict__ Bbase, size_t strideB,
                          const __hip_bfloat16* __restrict__ bias, size_t strideBias,
                          __hip_bfloat16* __restrict__ Cbase, size_t strideC) {
    int z = blockIdx.z;
    const __hip_bfloat16* A = Abase + (size_t)z * strideA;
    const __hip_bfloat16* B = Bbase + (size_t)z * strideB;
    __shared__ __align__(16) __hip_bfloat16 As[64 * LDP];
    __shared__ __align__(16) __hip_bfloat16 Bs[64 * LDP];
    int bm = blockIdx.x * 64, bn = blockIdx.y * 64;
    int tid = threadIdx.x, wave = tid >> 6, lane = tid & 63;
    int quad = lane >> 4, l15 = lane & 15;
    int wr = (wave & 1) * 32, wc = (wave >> 1) * 32;
    facc4 acc[2][2] = {};
    int sr = tid >> 2, kq = (tid & 3) * 8;
    for (int k0 = 0; k0 < D; k0 += 32) {
        *(bfrag8*)&As[sr * LDP + kq] = *(const bfrag8*)&A[(size_t)(bm + sr) * D + k0 + kq];
        *(bfrag8*)&Bs[sr * LDP + kq] = *(const bfrag8*)&B[(size_t)(bn + sr) * D + k0 + kq];
        __syncthreads();
        bfrag8 af[2], bfr[2];
        #pragma unroll
        for (int mi = 0; mi < 2; mi++)
            af[mi] = *(const bfrag8*)&As[(wr + mi * 16 + l15) * LDP + quad * 8];
        #pragma unroll
        for (int ni = 0; ni < 2; ni++)
            bfr[ni] = *(const bfrag8*)&Bs[(wc + ni * 16 + l15) * LDP + quad * 8];
        #pragma unroll
        for (int mi = 0; mi < 2; mi++)
            #pragma unroll
            for (int ni = 0; ni < 2; ni++)
                acc[mi][ni] = mfma16(af[mi], bfr[ni], acc[mi][ni]);
        __syncthreads();
    }
    #pragma unroll
    for (int mi = 0; mi < 2; mi++) {
        #pragma unroll
        for (int ni = 0; ni < 2; ni++) {
            int col = bn + wc + ni * 16 + l15;
            #pragma unroll
            for (int r = 0; r < 4; r++) {
                int row = bm + wr + mi * 16 + quad * 4 + r;
                float v = acc[mi][ni][r];
                if (bias) v += b2f(bias[col]);
                if (ACT == 1) v = v > 0.f ? v : expm1f(v);
                Cbase[(size_t)z * strideC + (size_t)row * D + col] = __float2bfloat16(v);
            }
        }
    }
}

// ---------------------------------------------------------------------------
// 3b. Fused dual-B GEMM over emb: shares A staging.
//     path 1: tanh(emb@attW^T + attb) → column-sum into spacc (no C write)
//     path 2: elu(emb@W1^T + b1) → xbuf
// ---------------------------------------------------------------------------
__global__ void gemm_dual(const __hip_bfloat16* __restrict__ embBase,
                          const __hip_bfloat16* __restrict__ conv,
                          __hip_bfloat16* __restrict__ xbuf,
                          float* __restrict__ spacc) {
    int z = blockIdx.z;
    const __hip_bfloat16* A = embBase + (size_t)z * N * D;
    const __hip_bfloat16* Ba = conv + OFF_ATTW;
    const __hip_bfloat16* Bw = conv + OFF_W1;
    __shared__ __align__(16) __hip_bfloat16 As[64 * LDP];
    __shared__ __align__(16) __hip_bfloat16 Bsa[64 * LDP];
    __shared__ __align__(16) __hip_bfloat16 Bsw[64 * LDP];
    int bm = blockIdx.x * 64, bn = blockIdx.y * 64;
    int tid = threadIdx.x, wave = tid >> 6, lane = tid & 63;
    int quad = lane >> 4, l15 = lane & 15;
    int wr = (wave & 1) * 32, wc = (wave >> 1) * 32;
    facc4 accA[2][2] = {};
    facc4 accW[2][2] = {};
    int sr = tid >> 2, kq = (tid & 3) * 8;
    for (int k0 = 0; k0 < D; k0 += 32) {
        *(bfrag8*)&As[sr * LDP + kq]  = *(const bfrag8*)&A[(size_t)(bm + sr) * D + k0 + kq];
        *(bfrag8*)&Bsa[sr * LDP + kq] = *(const bfrag8*)&Ba[(size_t)(bn + sr) * D + k0 + kq];
        *(bfrag8*)&Bsw[sr * LDP + kq] = *(const bfrag8*)&Bw[(size_t)(bn + sr) * D + k0 + kq];
        __syncthreads();
        bfrag8 af[2], ba[2], bw[2];
        #pragma unroll
        for (int mi = 0; mi < 2; mi++)
            af[mi] = *(const bfrag8*)&As[(wr + mi * 16 + l15) * LDP + quad * 8];
        #pragma unroll
        for (int ni = 0; ni < 2; ni++) {
            ba[ni] = *(const bfrag8*)&Bsa[(wc + ni * 16 + l15) * LDP + quad * 8];
            bw[ni] = *(const bfrag8*)&Bsw[(wc + ni * 16 + l15) * LDP + quad * 8];
        }
        #pragma unroll
        for (int mi = 0; mi < 2; mi++)
            #pragma unroll
            for (int ni = 0; ni < 2; ni++) {
                accA[mi][ni] = mfma16(af[mi], ba[ni], accA[mi][ni]);
                accW[mi][ni] = mfma16(af[mi], bw[ni], accW[mi][ni]);
            }
        __syncthreads();
    }
    float cs[2] = {0.f, 0.f};
    #pragma unroll
    for (int mi = 0; mi < 2; mi++) {
        #pragma unroll
        for (int ni = 0; ni < 2; ni++) {
            int col = bn + wc + ni * 16 + l15;
            float battb = b2f(conv[OFF_ATTB + col]);
            float bb1   = b2f(conv[OFF_B1 + col]);
            #pragma unroll
            for (int r = 0; r < 4; r++) {
                int row = bm + wr + mi * 16 + quad * 4 + r;
                cs[ni] += tanhf(accA[mi][ni][r] + battb);
                float v = accW[mi][ni][r] + bb1;
                v = v > 0.f ? v : expm1f(v);
                xbuf[(size_t)z * N * D + (size_t)row * D + col] = __float2bfloat16(v);
            }
        }
    }
    #pragma unroll
    for (int ni = 0; ni < 2; ni++) {
        float v = cs[ni];
        v += __shfl_xor(v, 16); v += __shfl_xor(v, 32);
        if (quad == 0) {
            int col = bn + wc + ni * 16 + l15;
            atomicAdd(&spacc[(size_t)z * D + col], v);
        }
    }
}

// ---------------------------------------------------------------------------
// 3c. proj2 GEMM with fused row-normalize: block = 16 rows × all 256 cols.
//     q[z][r][:] = normalize( xbuf[z][r][:] @ W2^T + b2 )
// ---------------------------------------------------------------------------
__global__ void gemm_w2_norm(const __hip_bfloat16* __restrict__ xbase,
                             const __hip_bfloat16* __restrict__ conv,
                             __hip_bfloat16* __restrict__ qbase) {
    int z = blockIdx.z;
    const __hip_bfloat16* A = xbase + (size_t)z * N * D;
    const __hip_bfloat16* B = conv + OFF_W2;
    __shared__ __align__(16) __hip_bfloat16 As[16 * LDP];
    __shared__ __align__(16) __hip_bfloat16 Bs[256 * LDP];
    __shared__ float sred[4][16];
    int bm = blockIdx.x * 16;
    int tid = threadIdx.x, wave = tid >> 6, lane = tid & 63;
    int quad = lane >> 4, l15 = lane & 15;
    int wc = wave * 64;
    facc4 acc[4] = {};
    for (int k0 = 0; k0 < D; k0 += 32) {
        if (tid < 64) {
            int r = tid >> 2, kq = (tid & 3) * 8;
            *(bfrag8*)&As[r * LDP + kq] = *(const bfrag8*)&A[(size_t)(bm + r) * D + k0 + kq];
        }
        #pragma unroll
        for (int i = 0; i < 4; i++) {
            int f = tid + 256 * i;          // 1024 fragments of B
            int r = f >> 2, kq = (f & 3) * 8;
            *(bfrag8*)&Bs[r * LDP + kq] = *(const bfrag8*)&B[(size_t)r * D + k0 + kq];
        }
        __syncthreads();
        bfrag8 af = *(const bfrag8*)&As[l15 * LDP + quad * 8];
        #pragma unroll
        for (int ni = 0; ni < 4; ni++) {
            bfrag8 bf = *(const bfrag8*)&Bs[(wc + ni * 16 + l15) * LDP + quad * 8];
            acc[ni] = mfma16(af, bf, acc[ni]);
        }
        __syncthreads();
    }
    float vv[4][4];   // [ni][r], bias applied
    #pragma unroll
    for (int ni = 0; ni < 4; ni++) {
        float bb = b2f(conv[OFF_B2 + wc + ni * 16 + l15]);
        #pragma unroll
        for (int r = 0; r < 4; r++) vv[ni][r] = acc[ni][r] + bb;
    }
    #pragma unroll
    for (int r = 0; r < 4; r++) {
        float ss = vv[0][r] * vv[0][r] + vv[1][r] * vv[1][r] +
                   vv[2][r] * vv[2][r] + vv[3][r] * vv[3][r];
        ss += __shfl_xor(ss, 1); ss += __shfl_xor(ss, 2);
        ss += __shfl_xor(ss, 4); ss += __shfl_xor(ss, 8);
        if (l15 == 0) sred[wave][quad * 4 + r] = ss;
    }
    __syncthreads();
    #pragma unroll
    for (int r = 0; r < 4; r++) {
        int rl = quad * 4 + r;
        float ssum = sred[0][rl] + sred[1][rl] + sred[2][rl] + sred[3][rl];
        float inv = rsqrtf(ssum + 1e-30f);
        int row = bm + rl;
        #pragma unroll
        for (int ni = 0; ni < 4; ni++)
            qbase[(size_t)z * N * D + (size_t)row * D + wc + ni * 16 + l15] =
                __float2bfloat16(vv[ni][r] * inv);
    }
}

// ---------------------------------------------------------------------------
// 4. spmm + prelu: wave per node, ushort4 loads/stores.
// ---------------------------------------------------------------------------
__global__ void spmm_prelu(const __hip_bfloat16* __restrict__ Xbase,
                           const int* __restrict__ nbr_idx, const float* __restrict__ nbr_val,
                           const int* __restrict__ deg, const __hip_bfloat16* __restrict__ conv,
                           __hip_bfloat16* __restrict__ embBase) {
    int z = blockIdx.z;
    int wave = threadIdx.x >> 6, lane = threadIdx.x & 63;
    int n = blockIdx.x * 4 + wave;
    const __hip_bfloat16* X = Xbase + (size_t)z * N * D;
    const int* idx = nbr_idx + ((size_t)z * N + n) * MAXDEG;
    const float* val = nbr_val + ((size_t)z * N + n) * MAXDEG;
    int dg = deg[z * N + n];
    float acc[4] = {0.f, 0.f, 0.f, 0.f};
    for (int k = 0; k < dg; k++) {
        int j = idx[k];
        float vk = val[k];
        ushort4 x = *(const ushort4*)&X[(size_t)j * D + lane * 4];
        acc[0] += vk * bfbits2f(x.x); acc[1] += vk * bfbits2f(x.y);
        acc[2] += vk * bfbits2f(x.z); acc[3] += vk * bfbits2f(x.w);
    }
    ushort4 bb = *(const ushort4*)&conv[OFF_BG + z * D + lane * 4];
    float b[4] = {bfbits2f(bb.x), bfbits2f(bb.y), bfbits2f(bb.z), bfbits2f(bb.w)};
    float a = b2f(conv[OFF_PA + z]);
    ushort4 o;
    float v0 = acc[0] + b[0]; o.x = f2bfbits(v0 > 0.f ? v0 : a * v0);
    float v1 = acc[1] + b[1]; o.y = f2bfbits(v1 > 0.f ? v1 : a * v1);
    float v2 = acc[2] + b[2]; o.z = f2bfbits(v2 > 0.f ? v2 : a * v2);
    float v3 = acc[3] + b[3]; o.w = f2bfbits(v3 > 0.f ? v3 : a * v3);
    *(ushort4*)&embBase[(size_t)z * N * D + (size_t)n * D + lane * 4] = o;
}

// ---------------------------------------------------------------------------
// 6. sim MFMA: per pair z, S = exp(Qz @ Q2^T / TAU) → rowsum/colsum atomics.
//    128x128 tile, 4 waves of 64x64 (16 accs), BK=64.
//    Staging via global_load_lds(16B) into unpadded LDS; bank conflicts
//    avoided by XOR chunk swizzle on the GLOBAL source address.
// ---------------------------------------------------------------------------
__global__ void sim_mfma(const __hip_bfloat16* __restrict__ q,
                         float* __restrict__ rowsum, float* __restrict__ colsum) {
    int pair = blockIdx.z;
    const __hip_bfloat16* Qa = q + (size_t)pair * N * D;
    const __hip_bfloat16* Qb = q + (size_t)2 * N * D;
    __shared__ __align__(16) __hip_bfloat16 As[128 * 64];
    __shared__ __align__(16) __hip_bfloat16 Bs[128 * 64];
    int bm = blockIdx.x * 128, bn = blockIdx.y * 128;
    int tid = threadIdx.x, wave = tid >> 6, lane = tid & 63;
    int quad = lane >> 4, l15 = lane & 15;
    int wr = (wave & 1) * 64, wc = (wave >> 1) * 64;
    facc4 acc[4][4] = {};
    int sr0 = tid >> 3;                 // 0..31 (8 rows/wave per chunk)
    int cc  = tid & 7;                  // lds chunk slot = lane&7
    for (int k0 = 0; k0 < D; k0 += 64) {
        #pragma unroll
        for (int i = 0; i < 4; i++) {
            int r = sr0 + 32 * i;
            int cg = (cc ^ (r & 7)) * 8;          // swizzled global chunk
            gl_lds16(&Qa[(size_t)(bm + r) * D + k0 + cg], &As[r * 64 + cc * 8]);
            gl_lds16(&Qb[(size_t)(bn + r) * D + k0 + cg], &Bs[r * 64 + cc * 8]);
        }
        __syncthreads();
        #pragma unroll
        for (int kk = 0; kk < 64; kk += 32) {
            int kb = kk >> 3;                      // 0 or 4
            bfrag8 af[4], bfr[4];
            #pragma unroll
            for (int mi = 0; mi < 4; mi++) {
                int R = wr + mi * 16 + l15;
                int pc = ((kb + quad) ^ (l15 & 7)) * 8;   // physical chunk
                af[mi] = *(const bfrag8*)&As[R * 64 + pc];
            }
            #pragma unroll
            for (int ni = 0; ni < 4; ni++) {
                int R = wc + ni * 16 + l15;
                int pc = ((kb + quad) ^ (l15 & 7)) * 8;
                bfr[ni] = *(const bfrag8*)&Bs[R * 64 + pc];
            }
            #pragma unroll
            for (int mi = 0; mi < 4; mi++)
                #pragma unroll
                for (int ni = 0; ni < 4; ni++)
                    acc[mi][ni] = mfma16(af[mi], bfr[ni], acc[mi][ni]);
        }
        __syncthreads();
    }
    constexpr float invtau = 1.0f / TAU;
    float rs[4][4];   // [mi][r]
    float cs[4] = {0.f, 0.f, 0.f, 0.f};
    #pragma unroll
    for (int mi = 0; mi < 4; mi++)
        #pragma unroll
        for (int r = 0; r < 4; r++) rs[mi][r] = 0.f;
    #pragma unroll
    for (int mi = 0; mi < 4; mi++)
        #pragma unroll
        for (int ni = 0; ni < 4; ni++)
            #pragma unroll
            for (int r = 0; r < 4; r++) {
                float e = __expf(acc[mi][ni][r] * invtau);
                rs[mi][r] += e;
                cs[ni] += e;
            }
    #pragma unroll
    for (int mi = 0; mi < 4; mi++)
        #pragma unroll
        for (int r = 0; r < 4; r++) {
            float v = rs[mi][r];
            v += __shfl_xor(v, 1); v += __shfl_xor(v, 2);
            v += __shfl_xor(v, 4); v += __shfl_xor(v, 8);
            rs[mi][r] = v;
        }
    if (l15 == 0) {
        #pragma unroll
        for (int mi = 0; mi < 4; mi++)
            #pragma unroll
            for (int r = 0; r < 4; r++)
                atomicAdd(&rowsum[(size_t)pair * N + bm + wr + mi * 16 + quad * 4 + r], rs[mi][r]);
    }
    #pragma unroll
    for (int ni = 0; ni < 4; ni++) {
        float v = cs[ni];
        v += __shfl_xor(v, 16); v += __shfl_xor(v, 32);
        if (quad == 0)
            atomicAdd(&colsum[(size_t)pair * N + bn + wc + ni * 16 + l15], v);
    }
}

// ---------------------------------------------------------------------------
// 7. merged edge losses: z<P → node-loss on emb[z]; z>=P → posdot on pair z-P.
//    One wave per node, vector loads, no scalar atomics.
// ---------------------------------------------------------------------------
__global__ void edge_losses(const __hip_bfloat16* __restrict__ embBase,
                            const __hip_bfloat16* __restrict__ q,
                            const int* __restrict__ nbr_idx, const float* __restrict__ nbr_val,
                            const int* __restrict__ neg_idx, const int* __restrict__ deg,
                            float* __restrict__ nlpart,
                            float* __restrict__ pdrow, float* __restrict__ pdcol) {
    int z = blockIdx.z;
    int wave = threadIdx.x >> 6, lane = threadIdx.x & 63;
    int n = blockIdx.x * 4 + wave;
    if (z < P) {
        const __hip_bfloat16* emb = embBase + (size_t)z * N * D;
        int dg = deg[z * N + n];
        const int* ip = nbr_idx + ((size_t)z * N + n) * MAXDEG;
        const int* ig = neg_idx + ((size_t)z * N + n) * MAXDEG;
        ushort4 ar = *(const ushort4*)&emb[(size_t)n * D + lane * 4];
        float a[4] = {bfbits2f(ar.x), bfbits2f(ar.y), bfbits2f(ar.z), bfbits2f(ar.w)};
        float s = 0.f;
        for (int k = 0; k < dg; k++) {
            int jp = ip[k], jn = ig[k];
            ushort4 pr = *(const ushort4*)&emb[(size_t)jp * D + lane * 4];
            ushort4 nr = *(const ushort4*)&emb[(size_t)jn * D + lane * 4];
            float dp = 0.f, dn = 0.f;
            float x0 = a[0] - bfbits2f(pr.x) + EPS_PD, y0 = a[0] - bfbits2f(nr.x) + EPS_PD;
            float x1 = a[1] - bfbits2f(pr.y) + EPS_PD, y1 = a[1] - bfbits2f(nr.y) + EPS_PD;
            float x2 = a[2] - bfbits2f(pr.z) + EPS_PD, y2 = a[2] - bfbits2f(nr.z) + EPS_PD;
            float x3 = a[3] - bfbits2f(pr.w) + EPS_PD, y3 = a[3] - bfbits2f(nr.w) + EPS_PD;
            dp = x0 * x0 + x1 * x1 + x2 * x2 + x3 * x3;
            dn = y0 * y0 + y1 * y1 + y2 * y2 + y3 * y3;
            #pragma unroll
            for (int st = 1; st <= 32; st <<= 1) { dp += __shfl_xor(dp, st); dn += __shfl_xor(dn, st); }
            float v = dp - dn + MARGIN;
            s += v > 0.f ? v : 0.f;
        }
        if (lane == 0) nlpart[z * N + n] = s / (float)dg;
    } else {
        int pair = z - P;
        const __hip_bfloat16* Qa = q + (size_t)pair * N * D;
        const __hip_bfloat16* Qb = q + (size_t)2 * N * D;
        int dg = deg[pair * N + n];
        const int* idx = nbr_idx + ((size_t)pair * N + n) * MAXDEG;
        const float* val = nbr_val + ((size_t)pair * N + n) * MAXDEG;
        const float invtau = 1.0f / TAU;
        ushort4 ar = *(const ushort4*)&Qa[(size_t)n * D + lane * 4];
        ushort4 br = *(const ushort4*)&Qb[(size_t)n * D + lane * 4];
        float a[4] = {bfbits2f(ar.x), bfbits2f(ar.y), bfbits2f(ar.z), bfbits2f(ar.w)};
        float b[4] = {bfbits2f(br.x), bfbits2f(br.y), bfbits2f(br.z), bfbits2f(br.w)};
        float sr = 0.f, sc = 0.f;
        for (int k = 0; k < dg; k++) {
            int j = idx[k];
            ushort4 pj = *(const ushort4*)&Qb[(size_t)j * D + lane * 4];
            ushort4 aj = *(const ushort4*)&Qa[(size_t)j * D + lane * 4];
            float dr = a[0] * bfbits2f(pj.x) + a[1] * bfbits2f(pj.y) +
                       a[2] * bfbits2f(pj.z) + a[3] * bfbits2f(pj.w);
            float dc = b[0] * bfbits2f(aj.x) + b[1] * bfbits2f(aj.y) +
                       b[2] * bfbits2f(aj.z) + b[3] * bfbits2f(aj.w);
            #pragma unroll
            for (int s = 1; s <= 32; s <<= 1) { dr += __shfl_xor(dr, s); dc += __shfl_xor(dc, s); }
            sr += __expf(dr * invtau) * val[k];
            sc += __expf(dc * invtau) * val[k];
        }
        if (lane == 0) { pdrow[pair * N + n] = sr; pdcol[pair * N + n] = sc; }
    }
}

// ---------------------------------------------------------------------------
// 9. final loss + beta: single block, no atomics.
// ---------------------------------------------------------------------------
__global__ void reduce_loss_beta(const float* __restrict__ nlpart,
                                 const float* __restrict__ rowsum, const float* __restrict__ colsum,
                                 const float* __restrict__ pdrow, const float* __restrict__ pdcol,
                                 const float* __restrict__ spacc,
                                 const __hip_bfloat16* __restrict__ conv,
                                 float* __restrict__ beta, float* __restrict__ loss) {
    int t = threadIdx.x;
    __shared__ float red[256];
    __shared__ float w[P];
    for (int p = 0; p < P; p++) {
        float v = (spacc[p * D + t] / (float)N) * b2f(conv[OFF_AV + t]);
        red[t] = v;
        __syncthreads();
        for (int s = 128; s > 0; s >>= 1) { if (t < s) red[t] += red[t + s]; __syncthreads(); }
        if (t == 0) w[p] = red[0];
        __syncthreads();
    }
    float s = 0.f;
    for (int i = t; i < P * N; i += 256) s += nlpart[i];
    for (int i = t; i < 2 * N; i += 256) {
        float l12 = -logf(pdrow[i] / (rowsum[i] + 1e-8f));
        float l21 = -logf(pdcol[i] / (colsum[i] + 1e-8f));
        s += (0.5f * l12 + 0.5f * l21) / (float)N;
    }
    red[t] = s;
    __syncthreads();
    for (int st = 128; st > 0; st >>= 1) { if (t < st) red[t] += red[t + st]; __syncthreads(); }
    if (t == 0) {
        loss[0] = red[0];
        float m = fmaxf(w[0], fmaxf(w[1], w[2]));
        float e0 = __expf(w[0] - m), e1 = __expf(w[1] - m), e2 = __expf(w[2] - m);
        float ssum = e0 + e1 + e2;
        beta[0] = e0 / ssum; beta[1] = e1 / ssum; beta[2] = e2 / ssum;
    }
}

// ---------------------------------------------------------------------------
// 10. z_mp output + loss scalar (output dtype follows detected input dtype)
// ---------------------------------------------------------------------------
__global__ void zmp_out(const __hip_bfloat16* __restrict__ embBase, const float* __restrict__ beta,
                        const float* __restrict__ loss, const int* __restrict__ counter,
                        void* __restrict__ out) {
    int bf = get_bf(counter);
    int i = blockIdx.x * 256 + threadIdx.x;
    float v = beta[0] * b2f(embBase[i]) + beta[1] * b2f(embBase[(size_t)N * D + i]) +
              beta[2] * b2f(embBase[(size_t)2 * N * D + i]);
    if (bf) {
        __hip_bfloat16* o = (__hip_bfloat16*)out;
        o[i] = __float2bfloat16(v);
        if (i == 0) o[(size_t)N * D] = __float2bfloat16(*loss);
    } else {
        float* o = (float*)out;
        o[i] = v;
        if (i == 0) o[(size_t)N * D] = *loss;
    }
}

extern "C" void kernel_launch(void* const* d_in, const int* in_sizes, int n_in,
                              void* d_out, int out_size, void* d_ws, size_t ws_size,
                              hipStream_t stream) {
    const void* h        = d_in[0];
    const void* mps      = d_in[1];
    const void* W_gcn    = d_in[2];
    const void* b_gcn    = d_in[3];
    const void* prelu_a  = d_in[4];
    const void* att_fc_W = d_in[5];
    const void* att_fc_b = d_in[6];
    const void* att_vec  = d_in[7];
    const void* proj_W1  = d_in[8];
    const void* proj_b1  = d_in[9];
    const void* proj_W2  = d_in[10];
    const void* proj_b2  = d_in[11];

    char* ws = (char*)d_ws;
    size_t off = 0;
    auto alloc = [&](size_t bytes) -> char* {
        char* p = ws + off;
        off = (off + bytes + 255) & ~(size_t)255;
        return p;
    };
    __hip_bfloat16* conv = (__hip_bfloat16*)alloc((size_t)CONV_TOTAL * 2);
    __hip_bfloat16* xbuf = (__hip_bfloat16*)alloc((size_t)P * N * D * 2);
    __hip_bfloat16* emb  = (__hip_bfloat16*)alloc((size_t)P * N * D * 2);
    __hip_bfloat16* q    = (__hip_bfloat16*)alloc((size_t)P * N * D * 2);
    int*   nbr_idx = (int*)alloc((size_t)P * N * MAXDEG * 4);
    float* nbr_val = (float*)alloc((size_t)P * N * MAXDEG * 4);
    int*   neg_idx = (int*)alloc((size_t)P * N * MAXDEG * 4);
    int*   deg     = (int*)alloc((size_t)P * N * 4);
    float* nlpart  = (float*)alloc((size_t)P * N * 4);
    float* pdrow   = (float*)alloc((size_t)2 * N * 4);
    float* pdcol   = (float*)alloc((size_t)2 * N * 4);
    char* zero_begin = ws + off;
    float* rowsum = (float*)alloc((size_t)2 * N * 4);
    float* colsum = (float*)alloc((size_t)2 * N * 4);
    float* spacc  = (float*)alloc((size_t)P * D * 4);
    float* beta   = (float*)alloc(16);
    float* loss   = (float*)alloc(16);
    int*   counter = (int*)alloc(16);
    size_t zero_bytes = (size_t)((ws + off) - zero_begin);
    hipMemsetAsync(zero_begin, 0, zero_bytes, stream);

    // 0. dtype detection
    detect_dtype<<<1024, 256, 0, stream>>>((const unsigned int*)mps, 2 * 1024 * 1024, counter);

    // 1. convert dense inputs to bf16 staging
    convert_all<<<512, 256, 0, stream>>>(h, W_gcn, att_fc_W, proj_W1, proj_W2, b_gcn,
                                         att_fc_b, att_vec, prelu_a, proj_b1, proj_b2,
                                         counter, conv);

    // 2. sparse extraction
    extract_sparse<<<P * N, 256, 0, stream>>>(mps, counter, nbr_idx, nbr_val, neg_idx, deg);

    dim3 ggrid(N / 64, D / 64, P);
    size_t nd = (size_t)N * D;
    // 3. GCN: X[z] = h @ Wg[z]^T
    gemm_mfma<0><<<ggrid, 256, 0, stream>>>(
        conv + OFF_H, 0, conv + OFF_WG, (size_t)D * D, nullptr, 0, xbuf, nd);
    // 4. emb[z] = prelu(spmm + bias)
    spmm_prelu<<<dim3(N / 4, 1, P), 256, 0, stream>>>(xbuf, nbr_idx, nbr_val, deg, conv, emb);
    // 5+6a. fused: spacc = colsum(tanh(emb@attW^T+attb)); xbuf = elu(emb@W1^T+b1)
    gemm_dual<<<ggrid, 256, 0, stream>>>(emb, conv, xbuf, spacc);
    // 6b+7. q[z] = rownorm(xbuf[z] @ W2^T + b2), fused
    gemm_w2_norm<<<dim3(N / 16, 1, P), 256, 0, stream>>>(xbuf, conv, q);
    // 8. sim (both pairs batched): rowsum/colsum (async-staged MFMA)
    sim_mfma<<<dim3(N / 128, N / 128, 2), 256, 0, stream>>>(q, rowsum, colsum);
    // 9. merged node-loss + posdot (grid.z = P+2)
    edge_losses<<<dim3(N / 4, 1, P + 2), 256, 0, stream>>>(emb, q, nbr_idx, nbr_val,
                                                           neg_idx, deg, nlpart, pdrow, pdcol);
    // 10. final loss + beta (no atomics)
    reduce_loss_beta<<<1, 256, 0, stream>>>(nlpart, rowsum, colsum, pdrow, pdcol,
                                            spacc, conv, beta, loss);
    // 11. output
    zmp_out<<<(N * D) / 256, 256, 0, stream>>>(emb, beta, loss, counter, d_out);
}

// Round 9
// 476.209 us; speedup vs baseline: 1.7466x; 1.0484x over previous
//
#include <hip/hip_runtime.h>
#include <hip/hip_bf16.h>

// Problem constants (Mp_encoder): N nodes, D dims, P metapaths.
constexpr int N = 4096;
constexpr int D = 256;
constexpr int P = 3;
constexpr int MAXDEG = 17;       // K+1
constexpr float TAU = 0.8f;
constexpr float MARGIN = 0.1f;
constexpr float EPS_PD = 1e-6f;

constexpr int LDP = 40;          // LDS k-stride for 64-tiles (2-way max conflicts)

// bf16 conversion-area offsets (elements), all 256-aligned
constexpr int OFF_H    = 0;             // 1048576
constexpr int OFF_WG   = 1048576;       // 196608
constexpr int OFF_ATTW = 1245184;       // 65536
constexpr int OFF_W1   = 1310720;       // 65536
constexpr int OFF_W2   = 1376256;       // 65536
constexpr int OFF_BG   = 1441792;       // 768
constexpr int OFF_ATTB = 1442560;       // 256
constexpr int OFF_AV   = 1442816;       // 256
constexpr int OFF_PA   = 1443072;       // 3 (reserve 256)
constexpr int OFF_B1   = 1443328;       // 256
constexpr int OFF_B2   = 1443584;       // 256
constexpr int CONV_TOTAL = 1443840;

typedef __attribute__((ext_vector_type(8))) short bfrag8;
typedef __attribute__((ext_vector_type(4))) float facc4;

__device__ inline facc4 mfma16(bfrag8 a, bfrag8 b, facc4 c) {
    return __builtin_amdgcn_mfma_f32_16x16x32_bf16(a, b, c, 0, 0, 0);
}
__device__ inline float b2f(__hip_bfloat16 v) { return __bfloat162float(v); }
__device__ inline float bfbits2f(unsigned short u) {
    return __uint_as_float(((unsigned int)u) << 16);
}
__device__ inline unsigned short f2bfbits(float v) {
    __hip_bfloat16 t = __float2bfloat16(v);
    return *(unsigned short*)&t;
}
__device__ inline int get_bf(const int* __restrict__ counter) { return counter[0] > 100; }

__device__ inline float load_in(const void* p, size_t i, int bf) {
    return bf ? __bfloat162float(((const __hip_bfloat16*)p)[i])
              : ((const float*)p)[i];
}

// async global->LDS, 16 bytes per lane; dest = wave-uniform base + lane*16
__device__ __forceinline__ void gl_lds16(const __hip_bfloat16* g, __hip_bfloat16* l) {
    __builtin_amdgcn_global_load_lds(
        (const __attribute__((address_space(1))) unsigned int*)g,
        (__attribute__((address_space(3))) unsigned int*)l, 16, 0, 0);
}

// ---------------------------------------------------------------------------
// 0. dtype detection from mps bit patterns (bf16 ⇒ many nonzero low-halves)
// ---------------------------------------------------------------------------
__global__ void detect_dtype(const unsigned int* __restrict__ w, int nwords,
                             int* __restrict__ counter) {
    int stride = gridDim.x * blockDim.x;
    int c = 0;
    for (int i = blockIdx.x * blockDim.x + threadIdx.x; i < nwords; i += stride) {
        unsigned int x = w[i];
        if ((x & 0xFFFF0000u) == 0u && x != 0u) c++;
    }
    for (int s = 32; s > 0; s >>= 1) c += __shfl_down(c, s);
    if ((threadIdx.x & 63) == 0 && c > 0) atomicAdd(counter, c);
}

// ---------------------------------------------------------------------------
// 1. Convert all dense inputs to a contiguous bf16 staging area.
// ---------------------------------------------------------------------------
__global__ void convert_all(const void* h, const void* wg, const void* attw,
                            const void* w1, const void* w2, const void* bg,
                            const void* attb, const void* av, const void* pa,
                            const void* b1, const void* b2,
                            const int* __restrict__ counter,
                            __hip_bfloat16* __restrict__ dst) {
    int bf = get_bf(counter);
    const void* srcs[11] = {h, wg, attw, w1, w2, bg, attb, av, pa, b1, b2};
    const int offs[11] = {OFF_H, OFF_WG, OFF_ATTW, OFF_W1, OFF_W2, OFF_BG,
                          OFF_ATTB, OFF_AV, OFF_PA, OFF_B1, OFF_B2};
    const int lens[11] = {1048576, 196608, 65536, 65536, 65536, 768, 256, 256, 3, 256, 256};
    int stride = gridDim.x * blockDim.x;
    int t0 = blockIdx.x * blockDim.x + threadIdx.x;
    #pragma unroll
    for (int s = 0; s < 11; s++) {
        for (int i = t0; i < lens[s]; i += stride)
            dst[offs[s] + i] = __float2bfloat16(load_in(srcs[s], i, bf));
    }
}

// ---------------------------------------------------------------------------
// 2. Sparse extraction (per (p,n) row of mps), vectorized 16B loads.
//    Epilogue is wave-parallel (rank sort + ballot-ranked neg list).
// ---------------------------------------------------------------------------
__global__ void extract_sparse(const void* __restrict__ mps, const int* __restrict__ counter,
                               int* __restrict__ nbr_idx, float* __restrict__ nbr_val,
                               int* __restrict__ neg_idx, int* __restrict__ deg) {
    int bf = get_bf(counter);
    int row = blockIdx.x;              // 0 .. P*N-1
    int t = threadIdx.x;               // 256 threads, 16 elems each
    __shared__ int cnt;
    __shared__ int sidx[32];
    __shared__ float sval[32];
    if (t == 0) cnt = 0;
    __syncthreads();
    int e0 = t * 16;
    if (bf) {
        const uint4* base = (const uint4*)((const __hip_bfloat16*)mps + (size_t)row * N + e0);
        #pragma unroll
        for (int v = 0; v < 2; v++) {
            uint4 w = base[v];
            unsigned int ws[4] = {w.x, w.y, w.z, w.w};
            #pragma unroll
            for (int j = 0; j < 4; j++) {
                unsigned short lo = (unsigned short)(ws[j] & 0xFFFFu);
                unsigned short hi = (unsigned short)(ws[j] >> 16);
                if (lo) { int k = atomicAdd(&cnt, 1); if (k < 32) { sidx[k] = e0 + v * 8 + j * 2;     sval[k] = bfbits2f(lo); } }
                if (hi) { int k = atomicAdd(&cnt, 1); if (k < 32) { sidx[k] = e0 + v * 8 + j * 2 + 1; sval[k] = bfbits2f(hi); } }
            }
        }
    } else {
        const float4* base = (const float4*)((const float*)mps + (size_t)row * N + e0);
        #pragma unroll
        for (int v = 0; v < 4; v++) {
            float4 w = base[v];
            float ws[4] = {w.x, w.y, w.z, w.w};
            #pragma unroll
            for (int j = 0; j < 4; j++)
                if (ws[j] > 0.f) { int k = atomicAdd(&cnt, 1); if (k < 32) { sidx[k] = e0 + v * 4 + j; sval[k] = ws[j]; } }
        }
    }
    __syncthreads();
    if (t < 64) {
        int dg = cnt; if (dg > MAXDEG) dg = MAXDEG;
        // wave-parallel rank sort (indices unique)
        int myidx = 0; float myval = 0.f; int rank = 0;
        if (t < dg) {
            myidx = sidx[t]; myval = sval[t];
            for (int j = 0; j < dg; j++) rank += (sidx[j] < myidx) ? 1 : 0;
        }
        // in-place sorted write (wave-lockstep: all reads above precede these writes)
        if (t < dg) { sidx[rank] = myidx; sval[rank] = myval; }
        if (t < MAXDEG) {
            nbr_idx[(size_t)row * MAXDEG + t] = (t < dg) ? sidx[t] : 0;
            nbr_val[(size_t)row * MAXDEG + t] = (t < dg) ? sval[t] : 0.f;
        }
        if (t == 0) deg[row] = dg;
        // neg list: first MAXDEG non-neighbors among candidates 0..dg+16 (<=33)
        int c = t;
        bool cand = (c < dg + MAXDEG);
        bool isnbr = false;
        if (cand) for (int j = 0; j < dg; j++) isnbr |= (sidx[j] == c);
        bool nonnbr = cand && !isnbr;
        unsigned long long m = __ballot(nonnbr);
        int nrank = __popcll(m & ((c < 64) ? ((1ull << c) - 1ull) : ~0ull));
        if (nonnbr && nrank < MAXDEG) neg_idx[(size_t)row * MAXDEG + nrank] = c;
    }
}

// ---------------------------------------------------------------------------
// 3. Triple-B GEMM for the X-stage: shares A (= h) staging across the three
//    metapath weights. X[z] = h @ Wg[z]^T, 64x64 tiles, BK=32.
// ---------------------------------------------------------------------------
__global__ void gemm_triple(const __hip_bfloat16* __restrict__ conv,
                            __hip_bfloat16* __restrict__ xbuf) {
    const __hip_bfloat16* A = conv + OFF_H;
    __shared__ __align__(16) __hip_bfloat16 As[64 * LDP];
    __shared__ __align__(16) __hip_bfloat16 Bs[3][64 * LDP];
    int bm = blockIdx.x * 64, bn = blockIdx.y * 64;
    int tid = threadIdx.x, wave = tid >> 6, lane = tid & 63;
    int quad = lane >> 4, l15 = lane & 15;
    int wr = (wave & 1) * 32, wc = (wave >> 1) * 32;
    facc4 acc[3][2][2] = {};
    int sr = tid >> 2, kq = (tid & 3) * 8;
    for (int k0 = 0; k0 < D; k0 += 32) {
        *(bfrag8*)&As[sr * LDP + kq] = *(const bfrag8*)&A[(size_t)(bm + sr) * D + k0 + kq];
        #pragma unroll
        for (int z = 0; z < 3; z++)
            *(bfrag8*)&Bs[z][sr * LDP + kq] =
                *(const bfrag8*)&conv[OFF_WG + (size_t)z * D * D + (size_t)(bn + sr) * D + k0 + kq];
        __syncthreads();
        bfrag8 af[2];
        #pragma unroll
        for (int mi = 0; mi < 2; mi++)
            af[mi] = *(const bfrag8*)&As[(wr + mi * 16 + l15) * LDP + quad * 8];
        #pragma unroll
        for (int z = 0; z < 3; z++) {
            bfrag8 bfr[2];
            #pragma unroll
            for (int ni = 0; ni < 2; ni++)
                bfr[ni] = *(const bfrag8*)&Bs[z][(wc + ni * 16 + l15) * LDP + quad * 8];
            #pragma unroll
            for (int mi = 0; mi < 2; mi++)
                #pragma unroll
                for (int ni = 0; ni < 2; ni++)
                    acc[z][mi][ni] = mfma16(af[mi], bfr[ni], acc[z][mi][ni]);
        }
        __syncthreads();
    }
    #pragma unroll
    for (int z = 0; z < 3; z++)
        #pragma unroll
        for (int mi = 0; mi < 2; mi++)
            #pragma unroll
            for (int ni = 0; ni < 2; ni++) {
                int col = bn + wc + ni * 16 + l15;
                #pragma unroll
                for (int r = 0; r < 4; r++) {
                    int row = bm + wr + mi * 16 + quad * 4 + r;
                    xbuf[(size_t)z * N * D + (size_t)row * D + col] =
                        __float2bfloat16(acc[z][mi][ni][r]);
                }
            }
}

// ---------------------------------------------------------------------------
// 3b. Fused dual-B GEMM over emb: shares A staging.
//     path 1: tanh(emb@attW^T + attb) → column-sum into spacc (no C write)
//     path 2: elu(emb@W1^T + b1) → xbuf
// ---------------------------------------------------------------------------
__global__ void gemm_dual(const __hip_bfloat16* __restrict__ embBase,
                          const __hip_bfloat16* __restrict__ conv,
                          __hip_bfloat16* __restrict__ xbuf,
                          float* __restrict__ spacc) {
    int z = blockIdx.z;
    const __hip_bfloat16* A = embBase + (size_t)z * N * D;
    const __hip_bfloat16* Ba = conv + OFF_ATTW;
    const __hip_bfloat16* Bw = conv + OFF_W1;
    __shared__ __align__(16) __hip_bfloat16 As[64 * LDP];
    __shared__ __align__(16) __hip_bfloat16 Bsa[64 * LDP];
    __shared__ __align__(16) __hip_bfloat16 Bsw[64 * LDP];
    int bm = blockIdx.x * 64, bn = blockIdx.y * 64;
    int tid = threadIdx.x, wave = tid >> 6, lane = tid & 63;
    int quad = lane >> 4, l15 = lane & 15;
    int wr = (wave & 1) * 32, wc = (wave >> 1) * 32;
    facc4 accA[2][2] = {};
    facc4 accW[2][2] = {};
    int sr = tid >> 2, kq = (tid & 3) * 8;
    for (int k0 = 0; k0 < D; k0 += 32) {
        *(bfrag8*)&As[sr * LDP + kq]  = *(const bfrag8*)&A[(size_t)(bm + sr) * D + k0 + kq];
        *(bfrag8*)&Bsa[sr * LDP + kq] = *(const bfrag8*)&Ba[(size_t)(bn + sr) * D + k0 + kq];
        *(bfrag8*)&Bsw[sr * LDP + kq] = *(const bfrag8*)&Bw[(size_t)(bn + sr) * D + k0 + kq];
        __syncthreads();
        bfrag8 af[2], ba[2], bw[2];
        #pragma unroll
        for (int mi = 0; mi < 2; mi++)
            af[mi] = *(const bfrag8*)&As[(wr + mi * 16 + l15) * LDP + quad * 8];
        #pragma unroll
        for (int ni = 0; ni < 2; ni++) {
            ba[ni] = *(const bfrag8*)&Bsa[(wc + ni * 16 + l15) * LDP + quad * 8];
            bw[ni] = *(const bfrag8*)&Bsw[(wc + ni * 16 + l15) * LDP + quad * 8];
        }
        #pragma unroll
        for (int mi = 0; mi < 2; mi++)
            #pragma unroll
            for (int ni = 0; ni < 2; ni++) {
                accA[mi][ni] = mfma16(af[mi], ba[ni], accA[mi][ni]);
                accW[mi][ni] = mfma16(af[mi], bw[ni], accW[mi][ni]);
            }
        __syncthreads();
    }
    float cs[2] = {0.f, 0.f};
    #pragma unroll
    for (int mi = 0; mi < 2; mi++) {
        #pragma unroll
        for (int ni = 0; ni < 2; ni++) {
            int col = bn + wc + ni * 16 + l15;
            float battb = b2f(conv[OFF_ATTB + col]);
            float bb1   = b2f(conv[OFF_B1 + col]);
            #pragma unroll
            for (int r = 0; r < 4; r++) {
                int row = bm + wr + mi * 16 + quad * 4 + r;
                cs[ni] += tanhf(accA[mi][ni][r] + battb);
                float v = accW[mi][ni][r] + bb1;
                v = v > 0.f ? v : expm1f(v);
                xbuf[(size_t)z * N * D + (size_t)row * D + col] = __float2bfloat16(v);
            }
        }
    }
    #pragma unroll
    for (int ni = 0; ni < 2; ni++) {
        float v = cs[ni];
        v += __shfl_xor(v, 16); v += __shfl_xor(v, 32);
        if (quad == 0) {
            int col = bn + wc + ni * 16 + l15;
            atomicAdd(&spacc[(size_t)z * D + col], v);
        }
    }
}

// ---------------------------------------------------------------------------
// 3c. proj2 GEMM with fused row-normalize: block = 16 rows × all 256 cols.
// ---------------------------------------------------------------------------
__global__ void gemm_w2_norm(const __hip_bfloat16* __restrict__ xbase,
                             const __hip_bfloat16* __restrict__ conv,
                             __hip_bfloat16* __restrict__ qbase) {
    int z = blockIdx.z;
    const __hip_bfloat16* A = xbase + (size_t)z * N * D;
    const __hip_bfloat16* B = conv + OFF_W2;
    __shared__ __align__(16) __hip_bfloat16 As[16 * LDP];
    __shared__ __align__(16) __hip_bfloat16 Bs[256 * LDP];
    __shared__ float sred[4][16];
    int bm = blockIdx.x * 16;
    int tid = threadIdx.x, wave = tid >> 6, lane = tid & 63;
    int quad = lane >> 4, l15 = lane & 15;
    int wc = wave * 64;
    facc4 acc[4] = {};
    for (int k0 = 0; k0 < D; k0 += 32) {
        if (tid < 64) {
            int r = tid >> 2, kq = (tid & 3) * 8;
            *(bfrag8*)&As[r * LDP + kq] = *(const bfrag8*)&A[(size_t)(bm + r) * D + k0 + kq];
        }
        #pragma unroll
        for (int i = 0; i < 4; i++) {
            int f = tid + 256 * i;          // 1024 fragments of B
            int r = f >> 2, kq = (f & 3) * 8;
            *(bfrag8*)&Bs[r * LDP + kq] = *(const bfrag8*)&B[(size_t)r * D + k0 + kq];
        }
        __syncthreads();
        bfrag8 af = *(const bfrag8*)&As[l15 * LDP + quad * 8];
        #pragma unroll
        for (int ni = 0; ni < 4; ni++) {
            bfrag8 bf = *(const bfrag8*)&Bs[(wc + ni * 16 + l15) * LDP + quad * 8];
            acc[ni] = mfma16(af, bf, acc[ni]);
        }
        __syncthreads();
    }
    float vv[4][4];   // [ni][r], bias applied
    #pragma unroll
    for (int ni = 0; ni < 4; ni++) {
        float bb = b2f(conv[OFF_B2 + wc + ni * 16 + l15]);
        #pragma unroll
        for (int r = 0; r < 4; r++) vv[ni][r] = acc[ni][r] + bb;
    }
    #pragma unroll
    for (int r = 0; r < 4; r++) {
        float ss = vv[0][r] * vv[0][r] + vv[1][r] * vv[1][r] +
                   vv[2][r] * vv[2][r] + vv[3][r] * vv[3][r];
        ss += __shfl_xor(ss, 1); ss += __shfl_xor(ss, 2);
        ss += __shfl_xor(ss, 4); ss += __shfl_xor(ss, 8);
        if (l15 == 0) sred[wave][quad * 4 + r] = ss;
    }
    __syncthreads();
    #pragma unroll
    for (int r = 0; r < 4; r++) {
        int rl = quad * 4 + r;
        float ssum = sred[0][rl] + sred[1][rl] + sred[2][rl] + sred[3][rl];
        float inv = rsqrtf(ssum + 1e-30f);
        int row = bm + rl;
        #pragma unroll
        for (int ni = 0; ni < 4; ni++)
            qbase[(size_t)z * N * D + (size_t)row * D + wc + ni * 16 + l15] =
                __float2bfloat16(vv[ni][r] * inv);
    }
}

// ---------------------------------------------------------------------------
// 4. spmm + prelu: wave per node, idx/val in lane registers, 2-way unroll.
// ---------------------------------------------------------------------------
__global__ void spmm_prelu(const __hip_bfloat16* __restrict__ Xbase,
                           const int* __restrict__ nbr_idx, const float* __restrict__ nbr_val,
                           const int* __restrict__ deg, const __hip_bfloat16* __restrict__ conv,
                           __hip_bfloat16* __restrict__ embBase) {
    int z = blockIdx.z;
    int wave = threadIdx.x >> 6, lane = threadIdx.x & 63;
    int n = blockIdx.x * 4 + wave;
    const __hip_bfloat16* X = Xbase + (size_t)z * N * D;
    int dg = deg[z * N + n];
    int idxv = 0; float valv = 0.f;
    if (lane < MAXDEG) {
        idxv = nbr_idx[((size_t)z * N + n) * MAXDEG + lane];
        valv = nbr_val[((size_t)z * N + n) * MAXDEG + lane];
    }
    float acc[4] = {0.f, 0.f, 0.f, 0.f};
    int k = 0;
    for (; k + 1 < dg; k += 2) {
        int j0 = __shfl(idxv, k), j1 = __shfl(idxv, k + 1);
        float v0 = __shfl(valv, k), v1 = __shfl(valv, k + 1);
        ushort4 x0 = *(const ushort4*)&X[(size_t)j0 * D + lane * 4];
        ushort4 x1 = *(const ushort4*)&X[(size_t)j1 * D + lane * 4];
        acc[0] += v0 * bfbits2f(x0.x) + v1 * bfbits2f(x1.x);
        acc[1] += v0 * bfbits2f(x0.y) + v1 * bfbits2f(x1.y);
        acc[2] += v0 * bfbits2f(x0.z) + v1 * bfbits2f(x1.z);
        acc[3] += v0 * bfbits2f(x0.w) + v1 * bfbits2f(x1.w);
    }
    if (k < dg) {
        int j0 = __shfl(idxv, k); float v0 = __shfl(valv, k);
        ushort4 x0 = *(const ushort4*)&X[(size_t)j0 * D + lane * 4];
        acc[0] += v0 * bfbits2f(x0.x); acc[1] += v0 * bfbits2f(x0.y);
        acc[2] += v0 * bfbits2f(x0.z); acc[3] += v0 * bfbits2f(x0.w);
    }
    ushort4 bb = *(const ushort4*)&conv[OFF_BG + z * D + lane * 4];
    float a = b2f(conv[OFF_PA + z]);
    ushort4 o;
    float v0 = acc[0] + bfbits2f(bb.x); o.x = f2bfbits(v0 > 0.f ? v0 : a * v0);
    float v1 = acc[1] + bfbits2f(bb.y); o.y = f2bfbits(v1 > 0.f ? v1 : a * v1);
    float v2 = acc[2] + bfbits2f(bb.z); o.z = f2bfbits(v2 > 0.f ? v2 : a * v2);
    float v3 = acc[3] + bfbits2f(bb.w); o.w = f2bfbits(v3 > 0.f ? v3 : a * v3);
    *(ushort4*)&embBase[(size_t)z * N * D + (size_t)n * D + lane * 4] = o;
}

// ---------------------------------------------------------------------------
// 6. sim MFMA: per pair z, S = exp(Qz @ Q2^T / TAU) → rowsum/colsum atomics.
//    128x128 tile, BK=64, global_load_lds(16B) + XOR chunk swizzle.
// ---------------------------------------------------------------------------
__global__ void sim_mfma(const __hip_bfloat16* __restrict__ q,
                         float* __restrict__ rowsum, float* __restrict__ colsum) {
    int pair = blockIdx.z;
    const __hip_bfloat16* Qa = q + (size_t)pair * N * D;
    const __hip_bfloat16* Qb = q + (size_t)2 * N * D;
    __shared__ __align__(16) __hip_bfloat16 As[128 * 64];
    __shared__ __align__(16) __hip_bfloat16 Bs[128 * 64];
    int bm = blockIdx.x * 128, bn = blockIdx.y * 128;
    int tid = threadIdx.x, wave = tid >> 6, lane = tid & 63;
    int quad = lane >> 4, l15 = lane & 15;
    int wr = (wave & 1) * 64, wc = (wave >> 1) * 64;
    facc4 acc[4][4] = {};
    int sr0 = tid >> 3;                 // 0..31
    int cc  = tid & 7;                  // lds chunk slot
    for (int k0 = 0; k0 < D; k0 += 64) {
        #pragma unroll
        for (int i = 0; i < 4; i++) {
            int r = sr0 + 32 * i;
            int cg = (cc ^ (r & 7)) * 8;          // swizzled global chunk
            gl_lds16(&Qa[(size_t)(bm + r) * D + k0 + cg], &As[r * 64 + cc * 8]);
            gl_lds16(&Qb[(size_t)(bn + r) * D + k0 + cg], &Bs[r * 64 + cc * 8]);
        }
        __syncthreads();
        #pragma unroll
        for (int kk = 0; kk < 64; kk += 32) {
            int kb = kk >> 3;
            bfrag8 af[4], bfr[4];
            #pragma unroll
            for (int mi = 0; mi < 4; mi++) {
                int R = wr + mi * 16 + l15;
                int pc = ((kb + quad) ^ (l15 & 7)) * 8;
                af[mi] = *(const bfrag8*)&As[R * 64 + pc];
            }
            #pragma unroll
            for (int ni = 0; ni < 4; ni++) {
                int R = wc + ni * 16 + l15;
                int pc = ((kb + quad) ^ (l15 & 7)) * 8;
                bfr[ni] = *(const bfrag8*)&Bs[R * 64 + pc];
            }
            #pragma unroll
            for (int mi = 0; mi < 4; mi++)
                #pragma unroll
                for (int ni = 0; ni < 4; ni++)
                    acc[mi][ni] = mfma16(af[mi], bfr[ni], acc[mi][ni]);
        }
        __syncthreads();
    }
    constexpr float invtau = 1.0f / TAU;
    float rs[4][4];
    float cs[4] = {0.f, 0.f, 0.f, 0.f};
    #pragma unroll
    for (int mi = 0; mi < 4; mi++)
        #pragma unroll
        for (int r = 0; r < 4; r++) rs[mi][r] = 0.f;
    #pragma unroll
    for (int mi = 0; mi < 4; mi++)
        #pragma unroll
        for (int ni = 0; ni < 4; ni++)
            #pragma unroll
            for (int r = 0; r < 4; r++) {
                float e = __expf(acc[mi][ni][r] * invtau);
                rs[mi][r] += e;
                cs[ni] += e;
            }
    #pragma unroll
    for (int mi = 0; mi < 4; mi++)
        #pragma unroll
        for (int r = 0; r < 4; r++) {
            float v = rs[mi][r];
            v += __shfl_xor(v, 1); v += __shfl_xor(v, 2);
            v += __shfl_xor(v, 4); v += __shfl_xor(v, 8);
            rs[mi][r] = v;
        }
    if (l15 == 0) {
        #pragma unroll
        for (int mi = 0; mi < 4; mi++)
            #pragma unroll
            for (int r = 0; r < 4; r++)
                atomicAdd(&rowsum[(size_t)pair * N + bm + wr + mi * 16 + quad * 4 + r], rs[mi][r]);
    }
    #pragma unroll
    for (int ni = 0; ni < 4; ni++) {
        float v = cs[ni];
        v += __shfl_xor(v, 16); v += __shfl_xor(v, 32);
        if (quad == 0)
            atomicAdd(&colsum[(size_t)pair * N + bn + wc + ni * 16 + l15], v);
    }
}

// ---------------------------------------------------------------------------
// 7. merged edge losses: z<P → node-loss; z>=P → posdot on pair z-P.
//    One wave per node, idx lists in lane registers, 2-way unroll.
// ---------------------------------------------------------------------------
__global__ void edge_losses(const __hip_bfloat16* __restrict__ embBase,
                            const __hip_bfloat16* __restrict__ q,
                            const int* __restrict__ nbr_idx, const float* __restrict__ nbr_val,
                            const int* __restrict__ neg_idx, const int* __restrict__ deg,
                            float* __restrict__ nlpart,
                            float* __restrict__ pdrow, float* __restrict__ pdcol) {
    int z = blockIdx.z;
    int wave = threadIdx.x >> 6, lane = threadIdx.x & 63;
    int n = blockIdx.x * 4 + wave;
    if (z < P) {
        const __hip_bfloat16* emb = embBase + (size_t)z * N * D;
        int dg = deg[z * N + n];
        int ipv = 0, igv = 0;
        if (lane < MAXDEG) {
            ipv = nbr_idx[((size_t)z * N + n) * MAXDEG + lane];
            igv = neg_idx[((size_t)z * N + n) * MAXDEG + lane];
        }
        ushort4 ar = *(const ushort4*)&emb[(size_t)n * D + lane * 4];
        float a[4] = {bfbits2f(ar.x), bfbits2f(ar.y), bfbits2f(ar.z), bfbits2f(ar.w)};
        float s = 0.f;
        for (int k = 0; k < dg; k++) {
            int jp = __shfl(ipv, k), jn = __shfl(igv, k);
            ushort4 pr = *(const ushort4*)&emb[(size_t)jp * D + lane * 4];
            ushort4 nr = *(const ushort4*)&emb[(size_t)jn * D + lane * 4];
            float x0 = a[0] - bfbits2f(pr.x) + EPS_PD, y0 = a[0] - bfbits2f(nr.x) + EPS_PD;
            float x1 = a[1] - bfbits2f(pr.y) + EPS_PD, y1 = a[1] - bfbits2f(nr.y) + EPS_PD;
            float x2 = a[2] - bfbits2f(pr.z) + EPS_PD, y2 = a[2] - bfbits2f(nr.z) + EPS_PD;
            float x3 = a[3] - bfbits2f(pr.w) + EPS_PD, y3 = a[3] - bfbits2f(nr.w) + EPS_PD;
            float dp = x0 * x0 + x1 * x1 + x2 * x2 + x3 * x3;
            float dn = y0 * y0 + y1 * y1 + y2 * y2 + y3 * y3;
            #pragma unroll
            for (int st = 1; st <= 32; st <<= 1) { dp += __shfl_xor(dp, st); dn += __shfl_xor(dn, st); }
            float v = dp - dn + MARGIN;
            s += v > 0.f ? v : 0.f;
        }
        if (lane == 0) nlpart[z * N + n] = s / (float)dg;
    } else {
        int pair = z - P;
        const __hip_bfloat16* Qa = q + (size_t)pair * N * D;
        const __hip_bfloat16* Qb = q + (size_t)2 * N * D;
        int dg = deg[pair * N + n];
        int idxv = 0; float valv = 0.f;
        if (lane < MAXDEG) {
            idxv = nbr_idx[((size_t)pair * N + n) * MAXDEG + lane];
            valv = nbr_val[((size_t)pair * N + n) * MAXDEG + lane];
        }
        const float invtau = 1.0f / TAU;
        ushort4 ar = *(const ushort4*)&Qa[(size_t)n * D + lane * 4];
        ushort4 br = *(const ushort4*)&Qb[(size_t)n * D + lane * 4];
        float a[4] = {bfbits2f(ar.x), bfbits2f(ar.y), bfbits2f(ar.z), bfbits2f(ar.w)};
        float b[4] = {bfbits2f(br.x), bfbits2f(br.y), bfbits2f(br.z), bfbits2f(br.w)};
        float sr = 0.f, sc = 0.f;
        for (int k = 0; k < dg; k++) {
            int j = __shfl(idxv, k);
            float vk = __shfl(valv, k);
            ushort4 pj = *(const ushort4*)&Qb[(size_t)j * D + lane * 4];
            ushort4 aj = *(const ushort4*)&Qa[(size_t)j * D + lane * 4];
            float dr = a[0] * bfbits2f(pj.x) + a[1] * bfbits2f(pj.y) +
                       a[2] * bfbits2f(pj.z) + a[3] * bfbits2f(pj.w);
            float dc = b[0] * bfbits2f(aj.x) + b[1] * bfbits2f(aj.y) +
                       b[2] * bfbits2f(aj.z) + b[3] * bfbits2f(aj.w);
            #pragma unroll
            for (int s2 = 1; s2 <= 32; s2 <<= 1) { dr += __shfl_xor(dr, s2); dc += __shfl_xor(dc, s2); }
            sr += __expf(dr * invtau) * vk;
            sc += __expf(dc * invtau) * vk;
        }
        if (lane == 0) { pdrow[pair * N + n] = sr; pdcol[pair * N + n] = sc; }
    }
}

// ---------------------------------------------------------------------------
// 9. final loss + beta: single block, no atomics.
// ---------------------------------------------------------------------------
__global__ void reduce_loss_beta(const float* __restrict__ nlpart,
                                 const float* __restrict__ rowsum, const float* __restrict__ colsum,
                                 const float* __restrict__ pdrow, const float* __restrict__ pdcol,
                                 const float* __restrict__ spacc,
                                 const __hip_bfloat16* __restrict__ conv,
                                 float* __restrict__ beta, float* __restrict__ loss) {
    int t = threadIdx.x;
    __shared__ float red[256];
    __shared__ float w[P];
    for (int p = 0; p < P; p++) {
        float v = (spacc[p * D + t] / (float)N) * b2f(conv[OFF_AV + t]);
        red[t] = v;
        __syncthreads();
        for (int s = 128; s > 0; s >>= 1) { if (t < s) red[t] += red[t + s]; __syncthreads(); }
        if (t == 0) w[p] = red[0];
        __syncthreads();
    }
    float s = 0.f;
    for (int i = t; i < P * N; i += 256) s += nlpart[i];
    for (int i = t; i < 2 * N; i += 256) {
        float l12 = -logf(pdrow[i] / (rowsum[i] + 1e-8f));
        float l21 = -logf(pdcol[i] / (colsum[i] + 1e-8f));
        s += (0.5f * l12 + 0.5f * l21) / (float)N;
    }
    red[t] = s;
    __syncthreads();
    for (int st = 128; st > 0; st >>= 1) { if (t < st) red[t] += red[t + st]; __syncthreads(); }
    if (t == 0) {
        loss[0] = red[0];
        float m = fmaxf(w[0], fmaxf(w[1], w[2]));
        float e0 = __expf(w[0] - m), e1 = __expf(w[1] - m), e2 = __expf(w[2] - m);
        float ssum = e0 + e1 + e2;
        beta[0] = e0 / ssum; beta[1] = e1 / ssum; beta[2] = e2 / ssum;
    }
}

// ---------------------------------------------------------------------------
// 10. z_mp output (vectorized) + loss scalar
// ---------------------------------------------------------------------------
__global__ void zmp_out(const __hip_bfloat16* __restrict__ embBase, const float* __restrict__ beta,
                        const float* __restrict__ loss, const int* __restrict__ counter,
                        void* __restrict__ out) {
    int bf = get_bf(counter);
    int i = (blockIdx.x * 256 + threadIdx.x) * 4;
    ushort4 e0 = *(const ushort4*)&embBase[i];
    ushort4 e1 = *(const ushort4*)&embBase[(size_t)N * D + i];
    ushort4 e2 = *(const ushort4*)&embBase[(size_t)2 * N * D + i];
    float b0 = beta[0], b1 = beta[1], b2 = beta[2];
    float v[4];
    v[0] = b0 * bfbits2f(e0.x) + b1 * bfbits2f(e1.x) + b2 * bfbits2f(e2.x);
    v[1] = b0 * bfbits2f(e0.y) + b1 * bfbits2f(e1.y) + b2 * bfbits2f(e2.y);
    v[2] = b0 * bfbits2f(e0.z) + b1 * bfbits2f(e1.z) + b2 * bfbits2f(e2.z);
    v[3] = b0 * bfbits2f(e0.w) + b1 * bfbits2f(e1.w) + b2 * bfbits2f(e2.w);
    if (bf) {
        __hip_bfloat16* o = (__hip_bfloat16*)out;
        ushort4 ov;
        ov.x = f2bfbits(v[0]); ov.y = f2bfbits(v[1]);
        ov.z = f2bfbits(v[2]); ov.w = f2bfbits(v[3]);
        *(ushort4*)&o[i] = ov;
        if (i == 0) o[(size_t)N * D] = __float2bfloat16(*loss);
    } else {
        float* o = (float*)out;
        o[i] = v[0]; o[i + 1] = v[1]; o[i + 2] = v[2]; o[i + 3] = v[3];
        if (i == 0) o[(size_t)N * D] = *loss;
    }
}

extern "C" void kernel_launch(void* const* d_in, const int* in_sizes, int n_in,
                              void* d_out, int out_size, void* d_ws, size_t ws_size,
                              hipStream_t stream) {
    const void* h        = d_in[0];
    const void* mps      = d_in[1];
    const void* W_gcn    = d_in[2];
    const void* b_gcn    = d_in[3];
    const void* prelu_a  = d_in[4];
    const void* att_fc_W = d_in[5];
    const void* att_fc_b = d_in[6];
    const void* att_vec  = d_in[7];
    const void* proj_W1  = d_in[8];
    const void* proj_b1  = d_in[9];
    const void* proj_W2  = d_in[10];
    const void* proj_b2  = d_in[11];

    char* ws = (char*)d_ws;
    size_t off = 0;
    auto alloc = [&](size_t bytes) -> char* {
        char* p = ws + off;
        off = (off + bytes + 255) & ~(size_t)255;
        return p;
    };
    __hip_bfloat16* conv = (__hip_bfloat16*)alloc((size_t)CONV_TOTAL * 2);
    __hip_bfloat16* xbuf = (__hip_bfloat16*)alloc((size_t)P * N * D * 2);
    __hip_bfloat16* emb  = (__hip_bfloat16*)alloc((size_t)P * N * D * 2);
    __hip_bfloat16* q    = (__hip_bfloat16*)alloc((size_t)P * N * D * 2);
    int*   nbr_idx = (int*)alloc((size_t)P * N * MAXDEG * 4);
    float* nbr_val = (float*)alloc((size_t)P * N * MAXDEG * 4);
    int*   neg_idx = (int*)alloc((size_t)P * N * MAXDEG * 4);
    int*   deg     = (int*)alloc((size_t)P * N * 4);
    float* nlpart  = (float*)alloc((size_t)P * N * 4);
    float* pdrow   = (float*)alloc((size_t)2 * N * 4);
    float* pdcol   = (float*)alloc((size_t)2 * N * 4);
    char* zero_begin = ws + off;
    float* rowsum = (float*)alloc((size_t)2 * N * 4);
    float* colsum = (float*)alloc((size_t)2 * N * 4);
    float* spacc  = (float*)alloc((size_t)P * D * 4);
    float* beta   = (float*)alloc(16);
    float* loss   = (float*)alloc(16);
    int*   counter = (int*)alloc(16);
    size_t zero_bytes = (size_t)((ws + off) - zero_begin);
    hipMemsetAsync(zero_begin, 0, zero_bytes, stream);

    // 0. dtype detection
    detect_dtype<<<1024, 256, 0, stream>>>((const unsigned int*)mps, 2 * 1024 * 1024, counter);

    // 1. convert dense inputs to bf16 staging
    convert_all<<<512, 256, 0, stream>>>(h, W_gcn, att_fc_W, proj_W1, proj_W2, b_gcn,
                                         att_fc_b, att_vec, prelu_a, proj_b1, proj_b2,
                                         counter, conv);

    // 2. sparse extraction (wave-parallel epilogue)
    extract_sparse<<<P * N, 256, 0, stream>>>(mps, counter, nbr_idx, nbr_val, neg_idx, deg);

    size_t nd = (size_t)N * D;
    // 3. GCN: X[z] = h @ Wg[z]^T — all three z in one pass over h
    gemm_triple<<<dim3(N / 64, D / 64), 256, 0, stream>>>(conv, xbuf);
    // 4. emb[z] = prelu(spmm + bias)
    spmm_prelu<<<dim3(N / 4, 1, P), 256, 0, stream>>>(xbuf, nbr_idx, nbr_val, deg, conv, emb);
    // 5+6a. fused: spacc = colsum(tanh(emb@attW^T+attb)); xbuf = elu(emb@W1^T+b1)
    gemm_dual<<<dim3(N / 64, D / 64, P), 256, 0, stream>>>(emb, conv, xbuf, spacc);
    // 6b+7. q[z] = rownorm(xbuf[z] @ W2^T + b2), fused
    gemm_w2_norm<<<dim3(N / 16, 1, P), 256, 0, stream>>>(xbuf, conv, q);
    // 8. sim (both pairs batched): rowsum/colsum (async-staged MFMA)
    sim_mfma<<<dim3(N / 128, N / 128, 2), 256, 0, stream>>>(q, rowsum, colsum);
    // 9. merged node-loss + posdot (grid.z = P+2)
    edge_losses<<<dim3(N / 4, 1, P + 2), 256, 0, stream>>>(emb, q, nbr_idx, nbr_val,
                                                           neg_idx, deg, nlpart, pdrow, pdcol);
    // 10. final loss + beta (no atomics)
    reduce_loss_beta<<<1, 256, 0, stream>>>(nlpart, rowsum, colsum, pdrow, pdcol,
                                            spacc, conv, beta, loss);
    // 11. output
    zmp_out<<<(N * D) / 1024, 256, 0, stream>>>(emb, beta, loss, counter, d_out);
}

// Round 10
// 469.405 us; speedup vs baseline: 1.7719x; 1.0145x over previous
//
#include <hip/hip_runtime.h>
#include <hip/hip_bf16.h>

// Problem constants (Mp_encoder): N nodes, D dims, P metapaths.
constexpr int N = 4096;
constexpr int D = 256;
constexpr int P = 3;
constexpr int MAXDEG = 17;       // K+1
constexpr float TAU = 0.8f;
constexpr float MARGIN = 0.1f;
constexpr float EPS_PD = 1e-6f;

constexpr int LDP = 40;          // LDS k-stride for 64-tiles (2-way max conflicts)

// bf16 conversion-area offsets (elements), all 256-aligned
constexpr int OFF_H    = 0;             // 1048576
constexpr int OFF_WG   = 1048576;       // 196608
constexpr int OFF_ATTW = 1245184;       // 65536
constexpr int OFF_W1   = 1310720;       // 65536
constexpr int OFF_W2   = 1376256;       // 65536
constexpr int OFF_BG   = 1441792;       // 768
constexpr int OFF_ATTB = 1442560;       // 256
constexpr int OFF_AV   = 1442816;       // 256
constexpr int OFF_PA   = 1443072;       // 3 (reserve 256)
constexpr int OFF_B1   = 1443328;       // 256
constexpr int OFF_B2   = 1443584;       // 256
constexpr int CONV_TOTAL = 1443840;

typedef __attribute__((ext_vector_type(8))) short bfrag8;
typedef __attribute__((ext_vector_type(4))) float facc4;

__device__ inline facc4 mfma16(bfrag8 a, bfrag8 b, facc4 c) {
    return __builtin_amdgcn_mfma_f32_16x16x32_bf16(a, b, c, 0, 0, 0);
}
__device__ inline float b2f(__hip_bfloat16 v) { return __bfloat162float(v); }
__device__ inline float bfbits2f(unsigned short u) {
    return __uint_as_float(((unsigned int)u) << 16);
}
__device__ inline unsigned short f2bfbits(float v) {
    __hip_bfloat16 t = __float2bfloat16(v);
    return *(unsigned short*)&t;
}
__device__ inline int get_bf(const int* __restrict__ counter) { return counter[0] > 100; }

__device__ inline float load_in(const void* p, size_t i, int bf) {
    return bf ? __bfloat162float(((const __hip_bfloat16*)p)[i])
              : ((const float*)p)[i];
}

// async global->LDS, 16 bytes per lane; dest = wave-uniform base + lane*16
__device__ __forceinline__ void gl_lds16(const __hip_bfloat16* g, __hip_bfloat16* l) {
    __builtin_amdgcn_global_load_lds(
        (const __attribute__((address_space(1))) unsigned int*)g,
        (__attribute__((address_space(3))) unsigned int*)l, 16, 0, 0);
}

// ---------------------------------------------------------------------------
// 0. dtype detection from mps bit patterns (bf16 ⇒ many nonzero low-halves)
// ---------------------------------------------------------------------------
__global__ void detect_dtype(const unsigned int* __restrict__ w, int nwords,
                             int* __restrict__ counter) {
    int stride = gridDim.x * blockDim.x;
    int c = 0;
    for (int i = blockIdx.x * blockDim.x + threadIdx.x; i < nwords; i += stride) {
        unsigned int x = w[i];
        if ((x & 0xFFFF0000u) == 0u && x != 0u) c++;
    }
    for (int s = 32; s > 0; s >>= 1) c += __shfl_down(c, s);
    if ((threadIdx.x & 63) == 0 && c > 0) atomicAdd(counter, c);
}

// ---------------------------------------------------------------------------
// 1. Convert all dense inputs to a contiguous bf16 staging area.
// ---------------------------------------------------------------------------
__global__ void convert_all(const void* h, const void* wg, const void* attw,
                            const void* w1, const void* w2, const void* bg,
                            const void* attb, const void* av, const void* pa,
                            const void* b1, const void* b2,
                            const int* __restrict__ counter,
                            __hip_bfloat16* __restrict__ dst) {
    int bf = get_bf(counter);
    const void* srcs[11] = {h, wg, attw, w1, w2, bg, attb, av, pa, b1, b2};
    const int offs[11] = {OFF_H, OFF_WG, OFF_ATTW, OFF_W1, OFF_W2, OFF_BG,
                          OFF_ATTB, OFF_AV, OFF_PA, OFF_B1, OFF_B2};
    const int lens[11] = {1048576, 196608, 65536, 65536, 65536, 768, 256, 256, 3, 256, 256};
    int stride = gridDim.x * blockDim.x;
    int t0 = blockIdx.x * blockDim.x + threadIdx.x;
    #pragma unroll
    for (int s = 0; s < 11; s++) {
        for (int i = t0; i < lens[s]; i += stride)
            dst[offs[s] + i] = __float2bfloat16(load_in(srcs[s], i, bf));
    }
}

// ---------------------------------------------------------------------------
// 2. Sparse extraction (per (p,n) row of mps), vectorized 16B loads.
//    Epilogue is wave-parallel (rank sort + ballot-ranked neg list).
// ---------------------------------------------------------------------------
__global__ void extract_sparse(const void* __restrict__ mps, const int* __restrict__ counter,
                               int* __restrict__ nbr_idx, float* __restrict__ nbr_val,
                               int* __restrict__ neg_idx, int* __restrict__ deg) {
    int bf = get_bf(counter);
    int row = blockIdx.x;              // 0 .. P*N-1
    int t = threadIdx.x;               // 256 threads, 16 elems each
    __shared__ int cnt;
    __shared__ int sidx[32];
    __shared__ float sval[32];
    if (t == 0) cnt = 0;
    __syncthreads();
    int e0 = t * 16;
    if (bf) {
        const uint4* base = (const uint4*)((const __hip_bfloat16*)mps + (size_t)row * N + e0);
        #pragma unroll
        for (int v = 0; v < 2; v++) {
            uint4 w = base[v];
            unsigned int ws[4] = {w.x, w.y, w.z, w.w};
            #pragma unroll
            for (int j = 0; j < 4; j++) {
                unsigned short lo = (unsigned short)(ws[j] & 0xFFFFu);
                unsigned short hi = (unsigned short)(ws[j] >> 16);
                if (lo) { int k = atomicAdd(&cnt, 1); if (k < 32) { sidx[k] = e0 + v * 8 + j * 2;     sval[k] = bfbits2f(lo); } }
                if (hi) { int k = atomicAdd(&cnt, 1); if (k < 32) { sidx[k] = e0 + v * 8 + j * 2 + 1; sval[k] = bfbits2f(hi); } }
            }
        }
    } else {
        const float4* base = (const float4*)((const float*)mps + (size_t)row * N + e0);
        #pragma unroll
        for (int v = 0; v < 4; v++) {
            float4 w = base[v];
            float ws[4] = {w.x, w.y, w.z, w.w};
            #pragma unroll
            for (int j = 0; j < 4; j++)
                if (ws[j] > 0.f) { int k = atomicAdd(&cnt, 1); if (k < 32) { sidx[k] = e0 + v * 4 + j; sval[k] = ws[j]; } }
        }
    }
    __syncthreads();
    if (t < 64) {
        int dg = cnt; if (dg > MAXDEG) dg = MAXDEG;
        // wave-parallel rank sort (indices unique)
        int myidx = 0; float myval = 0.f; int rank = 0;
        if (t < dg) {
            myidx = sidx[t]; myval = sval[t];
            for (int j = 0; j < dg; j++) rank += (sidx[j] < myidx) ? 1 : 0;
        }
        if (t < dg) { sidx[rank] = myidx; sval[rank] = myval; }
        if (t < MAXDEG) {
            nbr_idx[(size_t)row * MAXDEG + t] = (t < dg) ? sidx[t] : 0;
            nbr_val[(size_t)row * MAXDEG + t] = (t < dg) ? sval[t] : 0.f;
        }
        if (t == 0) deg[row] = dg;
        // neg list: first MAXDEG non-neighbors among candidates 0..dg+16 (<=33)
        int c = t;
        bool cand = (c < dg + MAXDEG);
        bool isnbr = false;
        if (cand) for (int j = 0; j < dg; j++) isnbr |= (sidx[j] == c);
        bool nonnbr = cand && !isnbr;
        unsigned long long m = __ballot(nonnbr);
        int nrank = __popcll(m & ((c < 64) ? ((1ull << c) - 1ull) : ~0ull));
        if (nonnbr && nrank < MAXDEG) neg_idx[(size_t)row * MAXDEG + nrank] = c;
    }
}

// ---------------------------------------------------------------------------
// 3. Triple-B GEMM for the X-stage: X[z] = h @ Wg[z]^T, shared A staging.
// ---------------------------------------------------------------------------
__global__ void gemm_triple(const __hip_bfloat16* __restrict__ conv,
                            __hip_bfloat16* __restrict__ xbuf) {
    const __hip_bfloat16* A = conv + OFF_H;
    __shared__ __align__(16) __hip_bfloat16 As[64 * LDP];
    __shared__ __align__(16) __hip_bfloat16 Bs[3][64 * LDP];
    int bm = blockIdx.x * 64, bn = blockIdx.y * 64;
    int tid = threadIdx.x, wave = tid >> 6, lane = tid & 63;
    int quad = lane >> 4, l15 = lane & 15;
    int wr = (wave & 1) * 32, wc = (wave >> 1) * 32;
    facc4 acc[3][2][2] = {};
    int sr = tid >> 2, kq = (tid & 3) * 8;
    for (int k0 = 0; k0 < D; k0 += 32) {
        *(bfrag8*)&As[sr * LDP + kq] = *(const bfrag8*)&A[(size_t)(bm + sr) * D + k0 + kq];
        #pragma unroll
        for (int z = 0; z < 3; z++)
            *(bfrag8*)&Bs[z][sr * LDP + kq] =
                *(const bfrag8*)&conv[OFF_WG + (size_t)z * D * D + (size_t)(bn + sr) * D + k0 + kq];
        __syncthreads();
        bfrag8 af[2];
        #pragma unroll
        for (int mi = 0; mi < 2; mi++)
            af[mi] = *(const bfrag8*)&As[(wr + mi * 16 + l15) * LDP + quad * 8];
        #pragma unroll
        for (int z = 0; z < 3; z++) {
            bfrag8 bfr[2];
            #pragma unroll
            for (int ni = 0; ni < 2; ni++)
                bfr[ni] = *(const bfrag8*)&Bs[z][(wc + ni * 16 + l15) * LDP + quad * 8];
            #pragma unroll
            for (int mi = 0; mi < 2; mi++)
                #pragma unroll
                for (int ni = 0; ni < 2; ni++)
                    acc[z][mi][ni] = mfma16(af[mi], bfr[ni], acc[z][mi][ni]);
        }
        __syncthreads();
    }
    #pragma unroll
    for (int z = 0; z < 3; z++)
        #pragma unroll
        for (int mi = 0; mi < 2; mi++)
            #pragma unroll
            for (int ni = 0; ni < 2; ni++) {
                int col = bn + wc + ni * 16 + l15;
                #pragma unroll
                for (int r = 0; r < 4; r++) {
                    int row = bm + wr + mi * 16 + quad * 4 + r;
                    xbuf[(size_t)z * N * D + (size_t)row * D + col] =
                        __float2bfloat16(acc[z][mi][ni][r]);
                }
            }
}

// ---------------------------------------------------------------------------
// 3b. Fused dual-B GEMM over emb: attention colsum path + elu(W1) path.
// ---------------------------------------------------------------------------
__global__ void gemm_dual(const __hip_bfloat16* __restrict__ embBase,
                          const __hip_bfloat16* __restrict__ conv,
                          __hip_bfloat16* __restrict__ xbuf,
                          float* __restrict__ spacc) {
    int z = blockIdx.z;
    const __hip_bfloat16* A = embBase + (size_t)z * N * D;
    const __hip_bfloat16* Ba = conv + OFF_ATTW;
    const __hip_bfloat16* Bw = conv + OFF_W1;
    __shared__ __align__(16) __hip_bfloat16 As[64 * LDP];
    __shared__ __align__(16) __hip_bfloat16 Bsa[64 * LDP];
    __shared__ __align__(16) __hip_bfloat16 Bsw[64 * LDP];
    int bm = blockIdx.x * 64, bn = blockIdx.y * 64;
    int tid = threadIdx.x, wave = tid >> 6, lane = tid & 63;
    int quad = lane >> 4, l15 = lane & 15;
    int wr = (wave & 1) * 32, wc = (wave >> 1) * 32;
    facc4 accA[2][2] = {};
    facc4 accW[2][2] = {};
    int sr = tid >> 2, kq = (tid & 3) * 8;
    for (int k0 = 0; k0 < D; k0 += 32) {
        *(bfrag8*)&As[sr * LDP + kq]  = *(const bfrag8*)&A[(size_t)(bm + sr) * D + k0 + kq];
        *(bfrag8*)&Bsa[sr * LDP + kq] = *(const bfrag8*)&Ba[(size_t)(bn + sr) * D + k0 + kq];
        *(bfrag8*)&Bsw[sr * LDP + kq] = *(const bfrag8*)&Bw[(size_t)(bn + sr) * D + k0 + kq];
        __syncthreads();
        bfrag8 af[2], ba[2], bw[2];
        #pragma unroll
        for (int mi = 0; mi < 2; mi++)
            af[mi] = *(const bfrag8*)&As[(wr + mi * 16 + l15) * LDP + quad * 8];
        #pragma unroll
        for (int ni = 0; ni < 2; ni++) {
            ba[ni] = *(const bfrag8*)&Bsa[(wc + ni * 16 + l15) * LDP + quad * 8];
            bw[ni] = *(const bfrag8*)&Bsw[(wc + ni * 16 + l15) * LDP + quad * 8];
        }
        #pragma unroll
        for (int mi = 0; mi < 2; mi++)
            #pragma unroll
            for (int ni = 0; ni < 2; ni++) {
                accA[mi][ni] = mfma16(af[mi], ba[ni], accA[mi][ni]);
                accW[mi][ni] = mfma16(af[mi], bw[ni], accW[mi][ni]);
            }
        __syncthreads();
    }
    float cs[2] = {0.f, 0.f};
    #pragma unroll
    for (int mi = 0; mi < 2; mi++) {
        #pragma unroll
        for (int ni = 0; ni < 2; ni++) {
            int col = bn + wc + ni * 16 + l15;
            float battb = b2f(conv[OFF_ATTB + col]);
            float bb1   = b2f(conv[OFF_B1 + col]);
            #pragma unroll
            for (int r = 0; r < 4; r++) {
                int row = bm + wr + mi * 16 + quad * 4 + r;
                cs[ni] += tanhf(accA[mi][ni][r] + battb);
                float v = accW[mi][ni][r] + bb1;
                v = v > 0.f ? v : expm1f(v);
                xbuf[(size_t)z * N * D + (size_t)row * D + col] = __float2bfloat16(v);
            }
        }
    }
    #pragma unroll
    for (int ni = 0; ni < 2; ni++) {
        float v = cs[ni];
        v += __shfl_xor(v, 16); v += __shfl_xor(v, 32);
        if (quad == 0) {
            int col = bn + wc + ni * 16 + l15;
            atomicAdd(&spacc[(size_t)z * D + col], v);
        }
    }
}

// ---------------------------------------------------------------------------
// 3c. proj2 GEMM with fused row-normalize: block = 16 rows × all 256 cols.
// ---------------------------------------------------------------------------
__global__ void gemm_w2_norm(const __hip_bfloat16* __restrict__ xbase,
                             const __hip_bfloat16* __restrict__ conv,
                             __hip_bfloat16* __restrict__ qbase) {
    int z = blockIdx.z;
    const __hip_bfloat16* A = xbase + (size_t)z * N * D;
    const __hip_bfloat16* B = conv + OFF_W2;
    __shared__ __align__(16) __hip_bfloat16 As[16 * LDP];
    __shared__ __align__(16) __hip_bfloat16 Bs[256 * LDP];
    __shared__ float sred[4][16];
    int bm = blockIdx.x * 16;
    int tid = threadIdx.x, wave = tid >> 6, lane = tid & 63;
    int quad = lane >> 4, l15 = lane & 15;
    int wc = wave * 64;
    facc4 acc[4] = {};
    for (int k0 = 0; k0 < D; k0 += 32) {
        if (tid < 64) {
            int r = tid >> 2, kq = (tid & 3) * 8;
            *(bfrag8*)&As[r * LDP + kq] = *(const bfrag8*)&A[(size_t)(bm + r) * D + k0 + kq];
        }
        #pragma unroll
        for (int i = 0; i < 4; i++) {
            int f = tid + 256 * i;          // 1024 fragments of B
            int r = f >> 2, kq = (f & 3) * 8;
            *(bfrag8*)&Bs[r * LDP + kq] = *(const bfrag8*)&B[(size_t)r * D + k0 + kq];
        }
        __syncthreads();
        bfrag8 af = *(const bfrag8*)&As[l15 * LDP + quad * 8];
        #pragma unroll
        for (int ni = 0; ni < 4; ni++) {
            bfrag8 bf = *(const bfrag8*)&Bs[(wc + ni * 16 + l15) * LDP + quad * 8];
            acc[ni] = mfma16(af, bf, acc[ni]);
        }
        __syncthreads();
    }
    float vv[4][4];   // [ni][r], bias applied
    #pragma unroll
    for (int ni = 0; ni < 4; ni++) {
        float bb = b2f(conv[OFF_B2 + wc + ni * 16 + l15]);
        #pragma unroll
        for (int r = 0; r < 4; r++) vv[ni][r] = acc[ni][r] + bb;
    }
    #pragma unroll
    for (int r = 0; r < 4; r++) {
        float ss = vv[0][r] * vv[0][r] + vv[1][r] * vv[1][r] +
                   vv[2][r] * vv[2][r] + vv[3][r] * vv[3][r];
        ss += __shfl_xor(ss, 1); ss += __shfl_xor(ss, 2);
        ss += __shfl_xor(ss, 4); ss += __shfl_xor(ss, 8);
        if (l15 == 0) sred[wave][quad * 4 + r] = ss;
    }
    __syncthreads();
    #pragma unroll
    for (int r = 0; r < 4; r++) {
        int rl = quad * 4 + r;
        float ssum = sred[0][rl] + sred[1][rl] + sred[2][rl] + sred[3][rl];
        float inv = rsqrtf(ssum + 1e-30f);
        int row = bm + rl;
        #pragma unroll
        for (int ni = 0; ni < 4; ni++)
            qbase[(size_t)z * N * D + (size_t)row * D + wc + ni * 16 + l15] =
                __float2bfloat16(vv[ni][r] * inv);
    }
}

// ---------------------------------------------------------------------------
// 4. spmm + prelu: wave per node, idx/val in lane registers, 4-way unroll.
// ---------------------------------------------------------------------------
__global__ void spmm_prelu(const __hip_bfloat16* __restrict__ Xbase,
                           const int* __restrict__ nbr_idx, const float* __restrict__ nbr_val,
                           const int* __restrict__ deg, const __hip_bfloat16* __restrict__ conv,
                           __hip_bfloat16* __restrict__ embBase) {
    int z = blockIdx.z;
    int wave = threadIdx.x >> 6, lane = threadIdx.x & 63;
    int n = blockIdx.x * 4 + wave;
    const __hip_bfloat16* X = Xbase + (size_t)z * N * D;
    int dg = deg[z * N + n];
    int idxv = 0; float valv = 0.f;
    if (lane < MAXDEG) {
        idxv = nbr_idx[((size_t)z * N + n) * MAXDEG + lane];
        valv = nbr_val[((size_t)z * N + n) * MAXDEG + lane];
    }
    float acc[4] = {0.f, 0.f, 0.f, 0.f};
    int k = 0;
    for (; k + 3 < dg; k += 4) {
        int j0 = __shfl(idxv, k), j1 = __shfl(idxv, k + 1);
        int j2 = __shfl(idxv, k + 2), j3 = __shfl(idxv, k + 3);
        float v0 = __shfl(valv, k), v1 = __shfl(valv, k + 1);
        float v2 = __shfl(valv, k + 2), v3 = __shfl(valv, k + 3);
        ushort4 x0 = *(const ushort4*)&X[(size_t)j0 * D + lane * 4];
        ushort4 x1 = *(const ushort4*)&X[(size_t)j1 * D + lane * 4];
        ushort4 x2 = *(const ushort4*)&X[(size_t)j2 * D + lane * 4];
        ushort4 x3 = *(const ushort4*)&X[(size_t)j3 * D + lane * 4];
        acc[0] += v0 * bfbits2f(x0.x) + v1 * bfbits2f(x1.x) + v2 * bfbits2f(x2.x) + v3 * bfbits2f(x3.x);
        acc[1] += v0 * bfbits2f(x0.y) + v1 * bfbits2f(x1.y) + v2 * bfbits2f(x2.y) + v3 * bfbits2f(x3.y);
        acc[2] += v0 * bfbits2f(x0.z) + v1 * bfbits2f(x1.z) + v2 * bfbits2f(x2.z) + v3 * bfbits2f(x3.z);
        acc[3] += v0 * bfbits2f(x0.w) + v1 * bfbits2f(x1.w) + v2 * bfbits2f(x2.w) + v3 * bfbits2f(x3.w);
    }
    for (; k < dg; k++) {
        int j0 = __shfl(idxv, k); float v0 = __shfl(valv, k);
        ushort4 x0 = *(const ushort4*)&X[(size_t)j0 * D + lane * 4];
        acc[0] += v0 * bfbits2f(x0.x); acc[1] += v0 * bfbits2f(x0.y);
        acc[2] += v0 * bfbits2f(x0.z); acc[3] += v0 * bfbits2f(x0.w);
    }
    ushort4 bb = *(const ushort4*)&conv[OFF_BG + z * D + lane * 4];
    float a = b2f(conv[OFF_PA + z]);
    ushort4 o;
    float v0 = acc[0] + bfbits2f(bb.x); o.x = f2bfbits(v0 > 0.f ? v0 : a * v0);
    float v1 = acc[1] + bfbits2f(bb.y); o.y = f2bfbits(v1 > 0.f ? v1 : a * v1);
    float v2 = acc[2] + bfbits2f(bb.z); o.z = f2bfbits(v2 > 0.f ? v2 : a * v2);
    float v3 = acc[3] + bfbits2f(bb.w); o.w = f2bfbits(v3 > 0.f ? v3 : a * v3);
    *(ushort4*)&embBase[(size_t)z * N * D + (size_t)n * D + lane * 4] = o;
}

// ---------------------------------------------------------------------------
// 6. sim MFMA: per pair z, S = exp(Qz @ Q2^T / TAU) → rowsum/colsum atomics.
//    128x128 tile, BK=64, global_load_lds(16B) + XOR chunk swizzle.
// ---------------------------------------------------------------------------
__global__ void sim_mfma(const __hip_bfloat16* __restrict__ q,
                         float* __restrict__ rowsum, float* __restrict__ colsum) {
    int pair = blockIdx.z;
    const __hip_bfloat16* Qa = q + (size_t)pair * N * D;
    const __hip_bfloat16* Qb = q + (size_t)2 * N * D;
    __shared__ __align__(16) __hip_bfloat16 As[128 * 64];
    __shared__ __align__(16) __hip_bfloat16 Bs[128 * 64];
    int bm = blockIdx.x * 128, bn = blockIdx.y * 128;
    int tid = threadIdx.x, wave = tid >> 6, lane = tid & 63;
    int quad = lane >> 4, l15 = lane & 15;
    int wr = (wave & 1) * 64, wc = (wave >> 1) * 64;
    facc4 acc[4][4] = {};
    int sr0 = tid >> 3;                 // 0..31
    int cc  = tid & 7;                  // lds chunk slot
    for (int k0 = 0; k0 < D; k0 += 64) {
        #pragma unroll
        for (int i = 0; i < 4; i++) {
            int r = sr0 + 32 * i;
            int cg = (cc ^ (r & 7)) * 8;          // swizzled global chunk
            gl_lds16(&Qa[(size_t)(bm + r) * D + k0 + cg], &As[r * 64 + cc * 8]);
            gl_lds16(&Qb[(size_t)(bn + r) * D + k0 + cg], &Bs[r * 64 + cc * 8]);
        }
        __syncthreads();
        #pragma unroll
        for (int kk = 0; kk < 64; kk += 32) {
            int kb = kk >> 3;
            bfrag8 af[4], bfr[4];
            #pragma unroll
            for (int mi = 0; mi < 4; mi++) {
                int R = wr + mi * 16 + l15;
                int pc = ((kb + quad) ^ (l15 & 7)) * 8;
                af[mi] = *(const bfrag8*)&As[R * 64 + pc];
            }
            #pragma unroll
            for (int ni = 0; ni < 4; ni++) {
                int R = wc + ni * 16 + l15;
                int pc = ((kb + quad) ^ (l15 & 7)) * 8;
                bfr[ni] = *(const bfrag8*)&Bs[R * 64 + pc];
            }
            #pragma unroll
            for (int mi = 0; mi < 4; mi++)
                #pragma unroll
                for (int ni = 0; ni < 4; ni++)
                    acc[mi][ni] = mfma16(af[mi], bfr[ni], acc[mi][ni]);
        }
        __syncthreads();
    }
    constexpr float invtau = 1.0f / TAU;
    float rs[4][4];
    float cs[4] = {0.f, 0.f, 0.f, 0.f};
    #pragma unroll
    for (int mi = 0; mi < 4; mi++)
        #pragma unroll
        for (int r = 0; r < 4; r++) rs[mi][r] = 0.f;
    #pragma unroll
    for (int mi = 0; mi < 4; mi++)
        #pragma unroll
        for (int ni = 0; ni < 4; ni++)
            #pragma unroll
            for (int r = 0; r < 4; r++) {
                float e = __expf(acc[mi][ni][r] * invtau);
                rs[mi][r] += e;
                cs[ni] += e;
            }
    #pragma unroll
    for (int mi = 0; mi < 4; mi++)
        #pragma unroll
        for (int r = 0; r < 4; r++) {
            float v = rs[mi][r];
            v += __shfl_xor(v, 1); v += __shfl_xor(v, 2);
            v += __shfl_xor(v, 4); v += __shfl_xor(v, 8);
            rs[mi][r] = v;
        }
    if (l15 == 0) {
        #pragma unroll
        for (int mi = 0; mi < 4; mi++)
            #pragma unroll
            for (int r = 0; r < 4; r++)
                atomicAdd(&rowsum[(size_t)pair * N + bm + wr + mi * 16 + quad * 4 + r], rs[mi][r]);
    }
    #pragma unroll
    for (int ni = 0; ni < 4; ni++) {
        float v = cs[ni];
        v += __shfl_xor(v, 16); v += __shfl_xor(v, 32);
        if (quad == 0)
            atomicAdd(&colsum[(size_t)pair * N + bn + wc + ni * 16 + l15], v);
    }
}

// ---------------------------------------------------------------------------
// 7. merged edge losses: z<P → node-loss; z>=P → posdot on pair z-P.
//    One wave per node, idx lists in lane registers, 2-way unroll.
// ---------------------------------------------------------------------------
__global__ void edge_losses(const __hip_bfloat16* __restrict__ embBase,
                            const __hip_bfloat16* __restrict__ q,
                            const int* __restrict__ nbr_idx, const float* __restrict__ nbr_val,
                            const int* __restrict__ neg_idx, const int* __restrict__ deg,
                            float* __restrict__ nlpart,
                            float* __restrict__ pdrow, float* __restrict__ pdcol) {
    int z = blockIdx.z;
    int wave = threadIdx.x >> 6, lane = threadIdx.x & 63;
    int n = blockIdx.x * 4 + wave;
    if (z < P) {
        const __hip_bfloat16* emb = embBase + (size_t)z * N * D;
        int dg = deg[z * N + n];
        int ipv = 0, igv = 0;
        if (lane < MAXDEG) {
            ipv = nbr_idx[((size_t)z * N + n) * MAXDEG + lane];
            igv = neg_idx[((size_t)z * N + n) * MAXDEG + lane];
        }
        ushort4 ar = *(const ushort4*)&emb[(size_t)n * D + lane * 4];
        float a[4] = {bfbits2f(ar.x), bfbits2f(ar.y), bfbits2f(ar.z), bfbits2f(ar.w)};
        float s = 0.f;
        int k = 0;
        for (; k + 1 < dg; k += 2) {
            int jp0 = __shfl(ipv, k), jn0 = __shfl(igv, k);
            int jp1 = __shfl(ipv, k + 1), jn1 = __shfl(igv, k + 1);
            ushort4 pr0 = *(const ushort4*)&emb[(size_t)jp0 * D + lane * 4];
            ushort4 nr0 = *(const ushort4*)&emb[(size_t)jn0 * D + lane * 4];
            ushort4 pr1 = *(const ushort4*)&emb[(size_t)jp1 * D + lane * 4];
            ushort4 nr1 = *(const ushort4*)&emb[(size_t)jn1 * D + lane * 4];
            float dp0, dn0, dp1, dn1;
            {
                float x0 = a[0] - bfbits2f(pr0.x) + EPS_PD, y0 = a[0] - bfbits2f(nr0.x) + EPS_PD;
                float x1 = a[1] - bfbits2f(pr0.y) + EPS_PD, y1 = a[1] - bfbits2f(nr0.y) + EPS_PD;
                float x2 = a[2] - bfbits2f(pr0.z) + EPS_PD, y2 = a[2] - bfbits2f(nr0.z) + EPS_PD;
                float x3 = a[3] - bfbits2f(pr0.w) + EPS_PD, y3 = a[3] - bfbits2f(nr0.w) + EPS_PD;
                dp0 = x0 * x0 + x1 * x1 + x2 * x2 + x3 * x3;
                dn0 = y0 * y0 + y1 * y1 + y2 * y2 + y3 * y3;
            }
            {
                float x0 = a[0] - bfbits2f(pr1.x) + EPS_PD, y0 = a[0] - bfbits2f(nr1.x) + EPS_PD;
                float x1 = a[1] - bfbits2f(pr1.y) + EPS_PD, y1 = a[1] - bfbits2f(nr1.y) + EPS_PD;
                float x2 = a[2] - bfbits2f(pr1.z) + EPS_PD, y2 = a[2] - bfbits2f(nr1.z) + EPS_PD;
                float x3 = a[3] - bfbits2f(pr1.w) + EPS_PD, y3 = a[3] - bfbits2f(nr1.w) + EPS_PD;
                dp1 = x0 * x0 + x1 * x1 + x2 * x2 + x3 * x3;
                dn1 = y0 * y0 + y1 * y1 + y2 * y2 + y3 * y3;
            }
            #pragma unroll
            for (int st = 1; st <= 32; st <<= 1) {
                dp0 += __shfl_xor(dp0, st); dn0 += __shfl_xor(dn0, st);
                dp1 += __shfl_xor(dp1, st); dn1 += __shfl_xor(dn1, st);
            }
            float v0 = dp0 - dn0 + MARGIN; s += v0 > 0.f ? v0 : 0.f;
            float v1 = dp1 - dn1 + MARGIN; s += v1 > 0.f ? v1 : 0.f;
        }
        if (k < dg) {
            int jp = __shfl(ipv, k), jn = __shfl(igv, k);
            ushort4 pr = *(const ushort4*)&emb[(size_t)jp * D + lane * 4];
            ushort4 nr = *(const ushort4*)&emb[(size_t)jn * D + lane * 4];
            float x0 = a[0] - bfbits2f(pr.x) + EPS_PD, y0 = a[0] - bfbits2f(nr.x) + EPS_PD;
            float x1 = a[1] - bfbits2f(pr.y) + EPS_PD, y1 = a[1] - bfbits2f(nr.y) + EPS_PD;
            float x2 = a[2] - bfbits2f(pr.z) + EPS_PD, y2 = a[2] - bfbits2f(nr.z) + EPS_PD;
            float x3 = a[3] - bfbits2f(pr.w) + EPS_PD, y3 = a[3] - bfbits2f(nr.w) + EPS_PD;
            float dp = x0 * x0 + x1 * x1 + x2 * x2 + x3 * x3;
            float dn = y0 * y0 + y1 * y1 + y2 * y2 + y3 * y3;
            #pragma unroll
            for (int st = 1; st <= 32; st <<= 1) { dp += __shfl_xor(dp, st); dn += __shfl_xor(dn, st); }
            float v = dp - dn + MARGIN;
            s += v > 0.f ? v : 0.f;
        }
        if (lane == 0) nlpart[z * N + n] = s / (float)dg;
    } else {
        int pair = z - P;
        const __hip_bfloat16* Qa = q + (size_t)pair * N * D;
        const __hip_bfloat16* Qb = q + (size_t)2 * N * D;
        int dg = deg[pair * N + n];
        int idxv = 0; float valv = 0.f;
        if (lane < MAXDEG) {
            idxv = nbr_idx[((size_t)pair * N + n) * MAXDEG + lane];
            valv = nbr_val[((size_t)pair * N + n) * MAXDEG + lane];
        }
        const float invtau = 1.0f / TAU;
        ushort4 ar = *(const ushort4*)&Qa[(size_t)n * D + lane * 4];
        ushort4 br = *(const ushort4*)&Qb[(size_t)n * D + lane * 4];
        float a[4] = {bfbits2f(ar.x), bfbits2f(ar.y), bfbits2f(ar.z), bfbits2f(ar.w)};
        float b[4] = {bfbits2f(br.x), bfbits2f(br.y), bfbits2f(br.z), bfbits2f(br.w)};
        float sr = 0.f, sc = 0.f;
        int k = 0;
        for (; k + 1 < dg; k += 2) {
            int j0 = __shfl(idxv, k), j1 = __shfl(idxv, k + 1);
            float vk0 = __shfl(valv, k), vk1 = __shfl(valv, k + 1);
            ushort4 pj0 = *(const ushort4*)&Qb[(size_t)j0 * D + lane * 4];
            ushort4 aj0 = *(const ushort4*)&Qa[(size_t)j0 * D + lane * 4];
            ushort4 pj1 = *(const ushort4*)&Qb[(size_t)j1 * D + lane * 4];
            ushort4 aj1 = *(const ushort4*)&Qa[(size_t)j1 * D + lane * 4];
            float dr0 = a[0] * bfbits2f(pj0.x) + a[1] * bfbits2f(pj0.y) +
                        a[2] * bfbits2f(pj0.z) + a[3] * bfbits2f(pj0.w);
            float dc0 = b[0] * bfbits2f(aj0.x) + b[1] * bfbits2f(aj0.y) +
                        b[2] * bfbits2f(aj0.z) + b[3] * bfbits2f(aj0.w);
            float dr1 = a[0] * bfbits2f(pj1.x) + a[1] * bfbits2f(pj1.y) +
                        a[2] * bfbits2f(pj1.z) + a[3] * bfbits2f(pj1.w);
            float dc1 = b[0] * bfbits2f(aj1.x) + b[1] * bfbits2f(aj1.y) +
                        b[2] * bfbits2f(aj1.z) + b[3] * bfbits2f(aj1.w);
            #pragma unroll
            for (int s2 = 1; s2 <= 32; s2 <<= 1) {
                dr0 += __shfl_xor(dr0, s2); dc0 += __shfl_xor(dc0, s2);
                dr1 += __shfl_xor(dr1, s2); dc1 += __shfl_xor(dc1, s2);
            }
            sr += __expf(dr0 * invtau) * vk0 + __expf(dr1 * invtau) * vk1;
            sc += __expf(dc0 * invtau) * vk0 + __expf(dc1 * invtau) * vk1;
        }
        if (k < dg) {
            int j = __shfl(idxv, k);
            float vk = __shfl(valv, k);
            ushort4 pj = *(const ushort4*)&Qb[(size_t)j * D + lane * 4];
            ushort4 aj = *(const ushort4*)&Qa[(size_t)j * D + lane * 4];
            float dr = a[0] * bfbits2f(pj.x) + a[1] * bfbits2f(pj.y) +
                       a[2] * bfbits2f(pj.z) + a[3] * bfbits2f(pj.w);
            float dc = b[0] * bfbits2f(aj.x) + b[1] * bfbits2f(aj.y) +
                       b[2] * bfbits2f(aj.z) + b[3] * bfbits2f(aj.w);
            #pragma unroll
            for (int s2 = 1; s2 <= 32; s2 <<= 1) { dr += __shfl_xor(dr, s2); dc += __shfl_xor(dc, s2); }
            sr += __expf(dr * invtau) * vk;
            sc += __expf(dc * invtau) * vk;
        }
        if (lane == 0) { pdrow[pair * N + n] = sr; pdcol[pair * N + n] = sc; }
    }
}

// ---------------------------------------------------------------------------
// 9. finalize: block 0 → loss reduce + write out[N*D];
//    blocks 1..64 → per-block beta (redundant 768-float reduce) + z_mp slice.
// ---------------------------------------------------------------------------
__global__ void finalize(const float* __restrict__ nlpart,
                         const float* __restrict__ rowsum, const float* __restrict__ colsum,
                         const float* __restrict__ pdrow, const float* __restrict__ pdcol,
                         const float* __restrict__ spacc,
                         const __hip_bfloat16* __restrict__ conv,
                         const __hip_bfloat16* __restrict__ embBase,
                         const int* __restrict__ counter,
                         void* __restrict__ out) {
    int bf = get_bf(counter);
    int t = threadIdx.x;
    __shared__ float red[256];
    if (blockIdx.x == 0) {
        float s = 0.f;
        for (int i = t; i < P * N; i += 256) s += nlpart[i];
        for (int i = t; i < 2 * N; i += 256) {
            float l12 = -logf(pdrow[i] / (rowsum[i] + 1e-8f));
            float l21 = -logf(pdcol[i] / (colsum[i] + 1e-8f));
            s += (0.5f * l12 + 0.5f * l21) / (float)N;
        }
        red[t] = s;
        __syncthreads();
        for (int st = 128; st > 0; st >>= 1) { if (t < st) red[t] += red[t + st]; __syncthreads(); }
        if (t == 0) {
            if (bf) ((__hip_bfloat16*)out)[(size_t)N * D] = __float2bfloat16(red[0]);
            else    ((float*)out)[(size_t)N * D] = red[0];
        }
        return;
    }
    // beta (redundant per block)
    __shared__ float w[P];
    for (int p = 0; p < P; p++) {
        float v = (spacc[p * D + t] / (float)N) * b2f(conv[OFF_AV + t]);
        red[t] = v;
        __syncthreads();
        for (int s = 128; s > 0; s >>= 1) { if (t < s) red[t] += red[t + s]; __syncthreads(); }
        if (t == 0) w[p] = red[0];
        __syncthreads();
    }
    float m = fmaxf(w[0], fmaxf(w[1], w[2]));
    float e0 = __expf(w[0] - m), e1 = __expf(w[1] - m), e2 = __expf(w[2] - m);
    float ssum = e0 + e1 + e2;
    float b0 = e0 / ssum, b1 = e1 / ssum, b2 = e2 / ssum;
    // z_mp slice: blocks 1..64, each handles N*D/64 elements, vec4 per thread
    int slice = blockIdx.x - 1;
    int base = slice * (N * D / 64);
    for (int e = t * 4; e < N * D / 64; e += 256 * 4) {
        int i = base + e;
        ushort4 x0 = *(const ushort4*)&embBase[i];
        ushort4 x1 = *(const ushort4*)&embBase[(size_t)N * D + i];
        ushort4 x2 = *(const ushort4*)&embBase[(size_t)2 * N * D + i];
        float v[4];
        v[0] = b0 * bfbits2f(x0.x) + b1 * bfbits2f(x1.x) + b2 * bfbits2f(x2.x);
        v[1] = b0 * bfbits2f(x0.y) + b1 * bfbits2f(x1.y) + b2 * bfbits2f(x2.y);
        v[2] = b0 * bfbits2f(x0.z) + b1 * bfbits2f(x1.z) + b2 * bfbits2f(x2.z);
        v[3] = b0 * bfbits2f(x0.w) + b1 * bfbits2f(x1.w) + b2 * bfbits2f(x2.w);
        if (bf) {
            ushort4 ov;
            ov.x = f2bfbits(v[0]); ov.y = f2bfbits(v[1]);
            ov.z = f2bfbits(v[2]); ov.w = f2bfbits(v[3]);
            *(ushort4*)&((__hip_bfloat16*)out)[i] = ov;
        } else {
            float* o = (float*)out;
            o[i] = v[0]; o[i + 1] = v[1]; o[i + 2] = v[2]; o[i + 3] = v[3];
        }
    }
}

extern "C" void kernel_launch(void* const* d_in, const int* in_sizes, int n_in,
                              void* d_out, int out_size, void* d_ws, size_t ws_size,
                              hipStream_t stream) {
    const void* h        = d_in[0];
    const void* mps      = d_in[1];
    const void* W_gcn    = d_in[2];
    const void* b_gcn    = d_in[3];
    const void* prelu_a  = d_in[4];
    const void* att_fc_W = d_in[5];
    const void* att_fc_b = d_in[6];
    const void* att_vec  = d_in[7];
    const void* proj_W1  = d_in[8];
    const void* proj_b1  = d_in[9];
    const void* proj_W2  = d_in[10];
    const void* proj_b2  = d_in[11];

    char* ws = (char*)d_ws;
    size_t off = 0;
    auto alloc = [&](size_t bytes) -> char* {
        char* p = ws + off;
        off = (off + bytes + 255) & ~(size_t)255;
        return p;
    };
    __hip_bfloat16* conv = (__hip_bfloat16*)alloc((size_t)CONV_TOTAL * 2);
    __hip_bfloat16* xbuf = (__hip_bfloat16*)alloc((size_t)P * N * D * 2);
    __hip_bfloat16* emb  = (__hip_bfloat16*)alloc((size_t)P * N * D * 2);
    __hip_bfloat16* q    = (__hip_bfloat16*)alloc((size_t)P * N * D * 2);
    int*   nbr_idx = (int*)alloc((size_t)P * N * MAXDEG * 4);
    float* nbr_val = (float*)alloc((size_t)P * N * MAXDEG * 4);
    int*   neg_idx = (int*)alloc((size_t)P * N * MAXDEG * 4);
    int*   deg     = (int*)alloc((size_t)P * N * 4);
    float* nlpart  = (float*)alloc((size_t)P * N * 4);
    float* pdrow   = (float*)alloc((size_t)2 * N * 4);
    float* pdcol   = (float*)alloc((size_t)2 * N * 4);
    char* zero_begin = ws + off;
    float* rowsum = (float*)alloc((size_t)2 * N * 4);
    float* colsum = (float*)alloc((size_t)2 * N * 4);
    float* spacc  = (float*)alloc((size_t)P * D * 4);
    int*   counter = (int*)alloc(16);
    size_t zero_bytes = (size_t)((ws + off) - zero_begin);
    hipMemsetAsync(zero_begin, 0, zero_bytes, stream);

    // 0. dtype detection
    detect_dtype<<<1024, 256, 0, stream>>>((const unsigned int*)mps, 2 * 1024 * 1024, counter);

    // 1. convert dense inputs to bf16 staging
    convert_all<<<512, 256, 0, stream>>>(h, W_gcn, att_fc_W, proj_W1, proj_W2, b_gcn,
                                         att_fc_b, att_vec, prelu_a, proj_b1, proj_b2,
                                         counter, conv);

    // 2. sparse extraction (wave-parallel epilogue)
    extract_sparse<<<P * N, 256, 0, stream>>>(mps, counter, nbr_idx, nbr_val, neg_idx, deg);

    // 3. GCN: X[z] = h @ Wg[z]^T — all three z in one pass over h
    gemm_triple<<<dim3(N / 64, D / 64), 256, 0, stream>>>(conv, xbuf);
    // 4. emb[z] = prelu(spmm + bias)
    spmm_prelu<<<dim3(N / 4, 1, P), 256, 0, stream>>>(xbuf, nbr_idx, nbr_val, deg, conv, emb);
    // 5+6a. fused: spacc = colsum(tanh(emb@attW^T+attb)); xbuf = elu(emb@W1^T+b1)
    gemm_dual<<<dim3(N / 64, D / 64, P), 256, 0, stream>>>(emb, conv, xbuf, spacc);
    // 6b+7. q[z] = rownorm(xbuf[z] @ W2^T + b2), fused
    gemm_w2_norm<<<dim3(N / 16, 1, P), 256, 0, stream>>>(xbuf, conv, q);
    // 8. sim (both pairs batched): rowsum/colsum (async-staged MFMA)
    sim_mfma<<<dim3(N / 128, N / 128, 2), 256, 0, stream>>>(q, rowsum, colsum);
    // 9. merged node-loss + posdot (grid.z = P+2)
    edge_losses<<<dim3(N / 4, 1, P + 2), 256, 0, stream>>>(emb, q, nbr_idx, nbr_val,
                                                           neg_idx, deg, nlpart, pdrow, pdcol);
    // 10. finalize: loss + beta + z_mp in one dispatch
    finalize<<<65, 256, 0, stream>>>(nlpart, rowsum, colsum, pdrow, pdcol,
                                     spacc, conv, emb, counter, d_out);
}

// Round 12
// 467.015 us; speedup vs baseline: 1.7810x; 1.0051x over previous
//
#include <hip/hip_runtime.h>
#include <hip/hip_bf16.h>

// Problem constants (Mp_encoder): N nodes, D dims, P metapaths.
constexpr int N = 4096;
constexpr int D = 256;
constexpr int P = 3;
constexpr int MAXDEG = 17;       // K+1
constexpr float TAU = 0.8f;
constexpr float MARGIN = 0.1f;
constexpr float EPS_PD = 1e-6f;

constexpr int LDP = 40;          // LDS k-stride for 64-tiles (2-way max conflicts)

// bf16 conversion-area offsets (elements), all 256-aligned
constexpr int OFF_H    = 0;             // 1048576
constexpr int OFF_WG   = 1048576;       // 196608
constexpr int OFF_ATTW = 1245184;       // 65536
constexpr int OFF_W1   = 1310720;       // 65536
constexpr int OFF_W2   = 1376256;       // 65536
constexpr int OFF_BG   = 1441792;       // 768
constexpr int OFF_ATTB = 1442560;       // 256
constexpr int OFF_AV   = 1442816;       // 256
constexpr int OFF_PA   = 1443072;       // 3 (reserve 256)
constexpr int OFF_B1   = 1443328;       // 256
constexpr int OFF_B2   = 1443584;       // 256
constexpr int CONV_TOTAL = 1443840;

typedef __attribute__((ext_vector_type(8))) short bfrag8;
typedef __attribute__((ext_vector_type(4))) float facc4;

__device__ inline facc4 mfma16(bfrag8 a, bfrag8 b, facc4 c) {
    return __builtin_amdgcn_mfma_f32_16x16x32_bf16(a, b, c, 0, 0, 0);
}
__device__ inline float b2f(__hip_bfloat16 v) { return __bfloat162float(v); }
__device__ inline float bfbits2f(unsigned short u) {
    return __uint_as_float(((unsigned int)u) << 16);
}
__device__ inline unsigned short f2bfbits(float v) {
    __hip_bfloat16 t = __float2bfloat16(v);
    return *(unsigned short*)&t;
}
__device__ inline int get_bf(const int* __restrict__ counter) { return counter[0] > 100; }

__device__ inline float load_in(const void* p, size_t i, int bf) {
    return bf ? __bfloat162float(((const __hip_bfloat16*)p)[i])
              : ((const float*)p)[i];
}

// async global->LDS, 16 bytes per lane; dest = wave-uniform base + lane*16
__device__ __forceinline__ void gl_lds16(const __hip_bfloat16* g, __hip_bfloat16* l) {
    __builtin_amdgcn_global_load_lds(
        (const __attribute__((address_space(1))) unsigned int*)g,
        (__attribute__((address_space(3))) unsigned int*)l, 16, 0, 0);
}

// ---------------------------------------------------------------------------
// 0. dtype detection (atomicMax sentinel — works from poisoned or zero init)
//    + zero the atomic-accumulator region (replaces hipMemsetAsync dispatch).
//    [validated round 11: output 0 passed through this path]
// ---------------------------------------------------------------------------
__global__ void detect_dtype(const unsigned int* __restrict__ w, int nwords,
                             int* __restrict__ counter,
                             float* __restrict__ zbuf, int nz) {
    int t0 = blockIdx.x * blockDim.x + threadIdx.x;
    if (t0 < nz) zbuf[t0] = 0.f;
    int stride = gridDim.x * blockDim.x;
    int c = 0;
    for (int i = t0; i < nwords; i += stride) {
        unsigned int x = w[i];
        if ((x & 0xFFFF0000u) == 0u && x != 0u) c++;
    }
    for (int s = 32; s > 0; s >>= 1) c += __shfl_down(c, s);
    if ((threadIdx.x & 63) == 0 && c > 0) atomicMax(counter, 1 << 20);
}

// ---------------------------------------------------------------------------
// 1. Convert all dense inputs to a contiguous bf16 staging area.
// ---------------------------------------------------------------------------
__global__ void convert_all(const void* h, const void* wg, const void* attw,
                            const void* w1, const void* w2, const void* bg,
                            const void* attb, const void* av, const void* pa,
                            const void* b1, const void* b2,
                            const int* __restrict__ counter,
                            __hip_bfloat16* __restrict__ dst) {
    int bf = get_bf(counter);
    const void* srcs[11] = {h, wg, attw, w1, w2, bg, attb, av, pa, b1, b2};
    const int offs[11] = {OFF_H, OFF_WG, OFF_ATTW, OFF_W1, OFF_W2, OFF_BG,
                          OFF_ATTB, OFF_AV, OFF_PA, OFF_B1, OFF_B2};
    const int lens[11] = {1048576, 196608, 65536, 65536, 65536, 768, 256, 256, 3, 256, 256};
    int stride = gridDim.x * blockDim.x;
    int t0 = blockIdx.x * blockDim.x + threadIdx.x;
    #pragma unroll
    for (int s = 0; s < 11; s++) {
        for (int i = t0; i < lens[s]; i += stride)
            dst[offs[s] + i] = __float2bfloat16(load_in(srcs[s], i, bf));
    }
}

// ---------------------------------------------------------------------------
// 2. Sparse extraction (per (p,n) row of mps), vectorized 16B loads.
//    Epilogue is wave-parallel (rank sort + ballot-ranked neg list).
// ---------------------------------------------------------------------------
__global__ void extract_sparse(const void* __restrict__ mps, const int* __restrict__ counter,
                               int* __restrict__ nbr_idx, float* __restrict__ nbr_val,
                               int* __restrict__ neg_idx, int* __restrict__ deg) {
    int bf = get_bf(counter);
    int row = blockIdx.x;              // 0 .. P*N-1
    int t = threadIdx.x;               // 256 threads, 16 elems each
    __shared__ int cnt;
    __shared__ int sidx[32];
    __shared__ float sval[32];
    if (t == 0) cnt = 0;
    __syncthreads();
    int e0 = t * 16;
    if (bf) {
        const uint4* base = (const uint4*)((const __hip_bfloat16*)mps + (size_t)row * N + e0);
        #pragma unroll
        for (int v = 0; v < 2; v++) {
            uint4 w = base[v];
            unsigned int ws[4] = {w.x, w.y, w.z, w.w};
            #pragma unroll
            for (int j = 0; j < 4; j++) {
                unsigned short lo = (unsigned short)(ws[j] & 0xFFFFu);
                unsigned short hi = (unsigned short)(ws[j] >> 16);
                if (lo) { int k = atomicAdd(&cnt, 1); if (k < 32) { sidx[k] = e0 + v * 8 + j * 2;     sval[k] = bfbits2f(lo); } }
                if (hi) { int k = atomicAdd(&cnt, 1); if (k < 32) { sidx[k] = e0 + v * 8 + j * 2 + 1; sval[k] = bfbits2f(hi); } }
            }
        }
    } else {
        const float4* base = (const float4*)((const float*)mps + (size_t)row * N + e0);
        #pragma unroll
        for (int v = 0; v < 4; v++) {
            float4 w = base[v];
            float ws[4] = {w.x, w.y, w.z, w.w};
            #pragma unroll
            for (int j = 0; j < 4; j++)
                if (ws[j] > 0.f) { int k = atomicAdd(&cnt, 1); if (k < 32) { sidx[k] = e0 + v * 4 + j; sval[k] = ws[j]; } }
        }
    }
    __syncthreads();
    if (t < 64) {
        int dg = cnt; if (dg > MAXDEG) dg = MAXDEG;
        int myidx = 0; float myval = 0.f; int rank = 0;
        if (t < dg) {
            myidx = sidx[t]; myval = sval[t];
            for (int j = 0; j < dg; j++) rank += (sidx[j] < myidx) ? 1 : 0;
        }
        if (t < dg) { sidx[rank] = myidx; sval[rank] = myval; }
        if (t < MAXDEG) {
            nbr_idx[(size_t)row * MAXDEG + t] = (t < dg) ? sidx[t] : 0;
            nbr_val[(size_t)row * MAXDEG + t] = (t < dg) ? sval[t] : 0.f;
        }
        if (t == 0) deg[row] = dg;
        int c = t;
        bool cand = (c < dg + MAXDEG);
        bool isnbr = false;
        if (cand) for (int j = 0; j < dg; j++) isnbr |= (sidx[j] == c);
        bool nonnbr = cand && !isnbr;
        unsigned long long m = __ballot(nonnbr);
        int nrank = __popcll(m & ((c < 64) ? ((1ull << c) - 1ull) : ~0ull));
        if (nonnbr && nrank < MAXDEG) neg_idx[(size_t)row * MAXDEG + nrank] = c;
    }
}

// ---------------------------------------------------------------------------
// 3. Triple-B GEMM for the X-stage: X[z] = h @ Wg[z]^T, shared A staging.
// ---------------------------------------------------------------------------
__global__ void gemm_triple(const __hip_bfloat16* __restrict__ conv,
                            __hip_bfloat16* __restrict__ xbuf) {
    const __hip_bfloat16* A = conv + OFF_H;
    __shared__ __align__(16) __hip_bfloat16 As[64 * LDP];
    __shared__ __align__(16) __hip_bfloat16 Bs[3][64 * LDP];
    int bm = blockIdx.x * 64, bn = blockIdx.y * 64;
    int tid = threadIdx.x, wave = tid >> 6, lane = tid & 63;
    int quad = lane >> 4, l15 = lane & 15;
    int wr = (wave & 1) * 32, wc = (wave >> 1) * 32;
    facc4 acc[3][2][2] = {};
    int sr = tid >> 2, kq = (tid & 3) * 8;
    for (int k0 = 0; k0 < D; k0 += 32) {
        *(bfrag8*)&As[sr * LDP + kq] = *(const bfrag8*)&A[(size_t)(bm + sr) * D + k0 + kq];
        #pragma unroll
        for (int z = 0; z < 3; z++)
            *(bfrag8*)&Bs[z][sr * LDP + kq] =
                *(const bfrag8*)&conv[OFF_WG + (size_t)z * D * D + (size_t)(bn + sr) * D + k0 + kq];
        __syncthreads();
        bfrag8 af[2];
        #pragma unroll
        for (int mi = 0; mi < 2; mi++)
            af[mi] = *(const bfrag8*)&As[(wr + mi * 16 + l15) * LDP + quad * 8];
        #pragma unroll
        for (int z = 0; z < 3; z++) {
            bfrag8 bfr[2];
            #pragma unroll
            for (int ni = 0; ni < 2; ni++)
                bfr[ni] = *(const bfrag8*)&Bs[z][(wc + ni * 16 + l15) * LDP + quad * 8];
            #pragma unroll
            for (int mi = 0; mi < 2; mi++)
                #pragma unroll
                for (int ni = 0; ni < 2; ni++)
                    acc[z][mi][ni] = mfma16(af[mi], bfr[ni], acc[z][mi][ni]);
        }
        __syncthreads();
    }
    #pragma unroll
    for (int z = 0; z < 3; z++)
        #pragma unroll
        for (int mi = 0; mi < 2; mi++)
            #pragma unroll
            for (int ni = 0; ni < 2; ni++) {
                int col = bn + wc + ni * 16 + l15;
                #pragma unroll
                for (int r = 0; r < 4; r++) {
                    int row = bm + wr + mi * 16 + quad * 4 + r;
                    xbuf[(size_t)z * N * D + (size_t)row * D + col] =
                        __float2bfloat16(acc[z][mi][ni][r]);
                }
            }
}

// ---------------------------------------------------------------------------
// 3b. Fused dual-B GEMM over emb: attention colsum path + elu(W1) path.
// ---------------------------------------------------------------------------
__global__ void gemm_dual(const __hip_bfloat16* __restrict__ embBase,
                          const __hip_bfloat16* __restrict__ conv,
                          __hip_bfloat16* __restrict__ xbuf,
                          float* __restrict__ spacc) {
    int z = blockIdx.z;
    const __hip_bfloat16* A = embBase + (size_t)z * N * D;
    const __hip_bfloat16* Ba = conv + OFF_ATTW;
    const __hip_bfloat16* Bw = conv + OFF_W1;
    __shared__ __align__(16) __hip_bfloat16 As[64 * LDP];
    __shared__ __align__(16) __hip_bfloat16 Bsa[64 * LDP];
    __shared__ __align__(16) __hip_bfloat16 Bsw[64 * LDP];
    int bm = blockIdx.x * 64, bn = blockIdx.y * 64;
    int tid = threadIdx.x, wave = tid >> 6, lane = tid & 63;
    int quad = lane >> 4, l15 = lane & 15;
    int wr = (wave & 1) * 32, wc = (wave >> 1) * 32;
    facc4 accA[2][2] = {};
    facc4 accW[2][2] = {};
    int sr = tid >> 2, kq = (tid & 3) * 8;
    for (int k0 = 0; k0 < D; k0 += 32) {
        *(bfrag8*)&As[sr * LDP + kq]  = *(const bfrag8*)&A[(size_t)(bm + sr) * D + k0 + kq];
        *(bfrag8*)&Bsa[sr * LDP + kq] = *(const bfrag8*)&Ba[(size_t)(bn + sr) * D + k0 + kq];
        *(bfrag8*)&Bsw[sr * LDP + kq] = *(const bfrag8*)&Bw[(size_t)(bn + sr) * D + k0 + kq];
        __syncthreads();
        bfrag8 af[2], ba[2], bw[2];
        #pragma unroll
        for (int mi = 0; mi < 2; mi++)
            af[mi] = *(const bfrag8*)&As[(wr + mi * 16 + l15) * LDP + quad * 8];
        #pragma unroll
        for (int ni = 0; ni < 2; ni++) {
            ba[ni] = *(const bfrag8*)&Bsa[(wc + ni * 16 + l15) * LDP + quad * 8];
            bw[ni] = *(const bfrag8*)&Bsw[(wc + ni * 16 + l15) * LDP + quad * 8];
        }
        #pragma unroll
        for (int mi = 0; mi < 2; mi++)
            #pragma unroll
            for (int ni = 0; ni < 2; ni++) {
                accA[mi][ni] = mfma16(af[mi], ba[ni], accA[mi][ni]);
                accW[mi][ni] = mfma16(af[mi], bw[ni], accW[mi][ni]);
            }
        __syncthreads();
    }
    float cs[2] = {0.f, 0.f};
    #pragma unroll
    for (int mi = 0; mi < 2; mi++) {
        #pragma unroll
        for (int ni = 0; ni < 2; ni++) {
            int col = bn + wc + ni * 16 + l15;
            float battb = b2f(conv[OFF_ATTB + col]);
            float bb1   = b2f(conv[OFF_B1 + col]);
            #pragma unroll
            for (int r = 0; r < 4; r++) {
                int row = bm + wr + mi * 16 + quad * 4 + r;
                cs[ni] += tanhf(accA[mi][ni][r] + battb);
                float v = accW[mi][ni][r] + bb1;
                v = v > 0.f ? v : expm1f(v);
                xbuf[(size_t)z * N * D + (size_t)row * D + col] = __float2bfloat16(v);
            }
        }
    }
    #pragma unroll
    for (int ni = 0; ni < 2; ni++) {
        float v = cs[ni];
        v += __shfl_xor(v, 16); v += __shfl_xor(v, 32);
        if (quad == 0) {
            int col = bn + wc + ni * 16 + l15;
            atomicAdd(&spacc[(size_t)z * D + col], v);
        }
    }
}

// ---------------------------------------------------------------------------
// 3c. proj2 GEMM with fused row-normalize: block = 16 rows × all 256 cols.
// ---------------------------------------------------------------------------
__global__ void gemm_w2_norm(const __hip_bfloat16* __restrict__ xbase,
                             const __hip_bfloat16* __restrict__ conv,
                             __hip_bfloat16* __restrict__ qbase) {
    int z = blockIdx.z;
    const __hip_bfloat16* A = xbase + (size_t)z * N * D;
    const __hip_bfloat16* B = conv + OFF_W2;
    __shared__ __align__(16) __hip_bfloat16 As[16 * LDP];
    __shared__ __align__(16) __hip_bfloat16 Bs[256 * LDP];
    __shared__ float sred[4][16];
    int bm = blockIdx.x * 16;
    int tid = threadIdx.x, wave = tid >> 6, lane = tid & 63;
    int quad = lane >> 4, l15 = lane & 15;
    int wc = wave * 64;
    facc4 acc[4] = {};
    for (int k0 = 0; k0 < D; k0 += 32) {
        if (tid < 64) {
            int r = tid >> 2, kq = (tid & 3) * 8;
            *(bfrag8*)&As[r * LDP + kq] = *(const bfrag8*)&A[(size_t)(bm + r) * D + k0 + kq];
        }
        #pragma unroll
        for (int i = 0; i < 4; i++) {
            int f = tid + 256 * i;          // 1024 fragments of B
            int r = f >> 2, kq = (f & 3) * 8;
            *(bfrag8*)&Bs[r * LDP + kq] = *(const bfrag8*)&B[(size_t)r * D + k0 + kq];
        }
        __syncthreads();
        bfrag8 af = *(const bfrag8*)&As[l15 * LDP + quad * 8];
        #pragma unroll
        for (int ni = 0; ni < 4; ni++) {
            bfrag8 bf = *(const bfrag8*)&Bs[(wc + ni * 16 + l15) * LDP + quad * 8];
            acc[ni] = mfma16(af, bf, acc[ni]);
        }
        __syncthreads();
    }
    float vv[4][4];   // [ni][r], bias applied
    #pragma unroll
    for (int ni = 0; ni < 4; ni++) {
        float bb = b2f(conv[OFF_B2 + wc + ni * 16 + l15]);
        #pragma unroll
        for (int r = 0; r < 4; r++) vv[ni][r] = acc[ni][r] + bb;
    }
    #pragma unroll
    for (int r = 0; r < 4; r++) {
        float ss = vv[0][r] * vv[0][r] + vv[1][r] * vv[1][r] +
                   vv[2][r] * vv[2][r] + vv[3][r] * vv[3][r];
        ss += __shfl_xor(ss, 1); ss += __shfl_xor(ss, 2);
        ss += __shfl_xor(ss, 4); ss += __shfl_xor(ss, 8);
        if (l15 == 0) sred[wave][quad * 4 + r] = ss;
    }
    __syncthreads();
    #pragma unroll
    for (int r = 0; r < 4; r++) {
        int rl = quad * 4 + r;
        float ssum = sred[0][rl] + sred[1][rl] + sred[2][rl] + sred[3][rl];
        float inv = rsqrtf(ssum + 1e-30f);
        int row = bm + rl;
        #pragma unroll
        for (int ni = 0; ni < 4; ni++)
            qbase[(size_t)z * N * D + (size_t)row * D + wc + ni * 16 + l15] =
                __float2bfloat16(vv[ni][r] * inv);
    }
}

// ---------------------------------------------------------------------------
// 4. spmm + prelu: wave per node, idx/val in lane registers, 4-way unroll.
// ---------------------------------------------------------------------------
__global__ void spmm_prelu(const __hip_bfloat16* __restrict__ Xbase,
                           const int* __restrict__ nbr_idx, const float* __restrict__ nbr_val,
                           const int* __restrict__ deg, const __hip_bfloat16* __restrict__ conv,
                           __hip_bfloat16* __restrict__ embBase) {
    int z = blockIdx.z;
    int wave = threadIdx.x >> 6, lane = threadIdx.x & 63;
    int n = blockIdx.x * 4 + wave;
    const __hip_bfloat16* X = Xbase + (size_t)z * N * D;
    int dg = deg[z * N + n];
    int idxv = 0; float valv = 0.f;
    if (lane < MAXDEG) {
        idxv = nbr_idx[((size_t)z * N + n) * MAXDEG + lane];
        valv = nbr_val[((size_t)z * N + n) * MAXDEG + lane];
    }
    float acc[4] = {0.f, 0.f, 0.f, 0.f};
    int k = 0;
    for (; k + 3 < dg; k += 4) {
        int j0 = __shfl(idxv, k), j1 = __shfl(idxv, k + 1);
        int j2 = __shfl(idxv, k + 2), j3 = __shfl(idxv, k + 3);
        float v0 = __shfl(valv, k), v1 = __shfl(valv, k + 1);
        float v2 = __shfl(valv, k + 2), v3 = __shfl(valv, k + 3);
        ushort4 x0 = *(const ushort4*)&X[(size_t)j0 * D + lane * 4];
        ushort4 x1 = *(const ushort4*)&X[(size_t)j1 * D + lane * 4];
        ushort4 x2 = *(const ushort4*)&X[(size_t)j2 * D + lane * 4];
        ushort4 x3 = *(const ushort4*)&X[(size_t)j3 * D + lane * 4];
        acc[0] += v0 * bfbits2f(x0.x) + v1 * bfbits2f(x1.x) + v2 * bfbits2f(x2.x) + v3 * bfbits2f(x3.x);
        acc[1] += v0 * bfbits2f(x0.y) + v1 * bfbits2f(x1.y) + v2 * bfbits2f(x2.y) + v3 * bfbits2f(x3.y);
        acc[2] += v0 * bfbits2f(x0.z) + v1 * bfbits2f(x1.z) + v2 * bfbits2f(x2.z) + v3 * bfbits2f(x3.z);
        acc[3] += v0 * bfbits2f(x0.w) + v1 * bfbits2f(x1.w) + v2 * bfbits2f(x2.w) + v3 * bfbits2f(x3.w);
    }
    for (; k < dg; k++) {
        int j0 = __shfl(idxv, k); float v0 = __shfl(valv, k);
        ushort4 x0 = *(const ushort4*)&X[(size_t)j0 * D + lane * 4];
        acc[0] += v0 * bfbits2f(x0.x); acc[1] += v0 * bfbits2f(x0.y);
        acc[2] += v0 * bfbits2f(x0.z); acc[3] += v0 * bfbits2f(x0.w);
    }
    ushort4 bb = *(const ushort4*)&conv[OFF_BG + z * D + lane * 4];
    float a = b2f(conv[OFF_PA + z]);
    ushort4 o;
    float v0 = acc[0] + bfbits2f(bb.x); o.x = f2bfbits(v0 > 0.f ? v0 : a * v0);
    float v1 = acc[1] + bfbits2f(bb.y); o.y = f2bfbits(v1 > 0.f ? v1 : a * v1);
    float v2 = acc[2] + bfbits2f(bb.z); o.z = f2bfbits(v2 > 0.f ? v2 : a * v2);
    float v3 = acc[3] + bfbits2f(bb.w); o.w = f2bfbits(v3 > 0.f ? v3 : a * v3);
    *(ushort4*)&embBase[(size_t)z * N * D + (size_t)n * D + lane * 4] = o;
}

// ---------------------------------------------------------------------------
// 6. sim MFMA: per pair z, S = exp(Qz @ Q2^T / TAU) → rowsum/colsum atomics.
//    128x128 tile, BK=64, global_load_lds(16B) + XOR chunk swizzle.
// ---------------------------------------------------------------------------
__global__ void sim_mfma(const __hip_bfloat16* __restrict__ q,
                         float* __restrict__ rowsum, float* __restrict__ colsum) {
    int pair = blockIdx.z;
    const __hip_bfloat16* Qa = q + (size_t)pair * N * D;
    const __hip_bfloat16* Qb = q + (size_t)2 * N * D;
    __shared__ __align__(16) __hip_bfloat16 As[128 * 64];
    __shared__ __align__(16) __hip_bfloat16 Bs[128 * 64];
    int bm = blockIdx.x * 128, bn = blockIdx.y * 128;
    int tid = threadIdx.x, wave = tid >> 6, lane = tid & 63;
    int quad = lane >> 4, l15 = lane & 15;
    int wr = (wave & 1) * 64, wc = (wave >> 1) * 64;
    facc4 acc[4][4] = {};
    int sr0 = tid >> 3;                 // 0..31
    int cc  = tid & 7;                  // lds chunk slot
    for (int k0 = 0; k0 < D; k0 += 64) {
        #pragma unroll
        for (int i = 0; i < 4; i++) {
            int r = sr0 + 32 * i;
            int cg = (cc ^ (r & 7)) * 8;          // swizzled global chunk
            gl_lds16(&Qa[(size_t)(bm + r) * D + k0 + cg], &As[r * 64 + cc * 8]);
            gl_lds16(&Qb[(size_t)(bn + r) * D + k0 + cg], &Bs[r * 64 + cc * 8]);
        }
        __syncthreads();
        #pragma unroll
        for (int kk = 0; kk < 64; kk += 32) {
            int kb = kk >> 3;
            bfrag8 af[4], bfr[4];
            #pragma unroll
            for (int mi = 0; mi < 4; mi++) {
                int R = wr + mi * 16 + l15;
                int pc = ((kb + quad) ^ (l15 & 7)) * 8;
                af[mi] = *(const bfrag8*)&As[R * 64 + pc];
            }
            #pragma unroll
            for (int ni = 0; ni < 4; ni++) {
                int R = wc + ni * 16 + l15;
                int pc = ((kb + quad) ^ (l15 & 7)) * 8;
                bfr[ni] = *(const bfrag8*)&Bs[R * 64 + pc];
            }
            #pragma unroll
            for (int mi = 0; mi < 4; mi++)
                #pragma unroll
                for (int ni = 0; ni < 4; ni++)
                    acc[mi][ni] = mfma16(af[mi], bfr[ni], acc[mi][ni]);
        }
        __syncthreads();
    }
    constexpr float invtau = 1.0f / TAU;
    float rs[4][4];
    float cs[4] = {0.f, 0.f, 0.f, 0.f};
    #pragma unroll
    for (int mi = 0; mi < 4; mi++)
        #pragma unroll
        for (int r = 0; r < 4; r++) rs[mi][r] = 0.f;
    #pragma unroll
    for (int mi = 0; mi < 4; mi++)
        #pragma unroll
        for (int ni = 0; ni < 4; ni++)
            #pragma unroll
            for (int r = 0; r < 4; r++) {
                float e = __expf(acc[mi][ni][r] * invtau);
                rs[mi][r] += e;
                cs[ni] += e;
            }
    #pragma unroll
    for (int mi = 0; mi < 4; mi++)
        #pragma unroll
        for (int r = 0; r < 4; r++) {
            float v = rs[mi][r];
            v += __shfl_xor(v, 1); v += __shfl_xor(v, 2);
            v += __shfl_xor(v, 4); v += __shfl_xor(v, 8);
            rs[mi][r] = v;
        }
    if (l15 == 0) {
        #pragma unroll
        for (int mi = 0; mi < 4; mi++)
            #pragma unroll
            for (int r = 0; r < 4; r++)
                atomicAdd(&rowsum[(size_t)pair * N + bm + wr + mi * 16 + quad * 4 + r], rs[mi][r]);
    }
    #pragma unroll
    for (int ni = 0; ni < 4; ni++) {
        float v = cs[ni];
        v += __shfl_xor(v, 16); v += __shfl_xor(v, 32);
        if (quad == 0)
            atomicAdd(&colsum[(size_t)pair * N + bn + wc + ni * 16 + l15], v);
    }
}

// ---------------------------------------------------------------------------
// 7. merged edge losses (round-10 proven version): z<P → node-loss on emb[z];
//    z>=P → posdot on pair z-P. One wave per node, idx lists in lane
//    registers, 2-way edge unroll.
// ---------------------------------------------------------------------------
__global__ void edge_losses(const __hip_bfloat16* __restrict__ embBase,
                            const __hip_bfloat16* __restrict__ q,
                            const int* __restrict__ nbr_idx, const float* __restrict__ nbr_val,
                            const int* __restrict__ neg_idx, const int* __restrict__ deg,
                            float* __restrict__ nlpart,
                            float* __restrict__ pdrow, float* __restrict__ pdcol) {
    int z = blockIdx.z;
    int wave = threadIdx.x >> 6, lane = threadIdx.x & 63;
    int n = blockIdx.x * 4 + wave;
    if (z < P) {
        const __hip_bfloat16* emb = embBase + (size_t)z * N * D;
        int dg = deg[z * N + n];
        int ipv = 0, igv = 0;
        if (lane < MAXDEG) {
            ipv = nbr_idx[((size_t)z * N + n) * MAXDEG + lane];
            igv = neg_idx[((size_t)z * N + n) * MAXDEG + lane];
        }
        ushort4 ar = *(const ushort4*)&emb[(size_t)n * D + lane * 4];
        float a[4] = {bfbits2f(ar.x), bfbits2f(ar.y), bfbits2f(ar.z), bfbits2f(ar.w)};
        float s = 0.f;
        int k = 0;
        for (; k + 1 < dg; k += 2) {
            int jp0 = __shfl(ipv, k), jn0 = __shfl(igv, k);
            int jp1 = __shfl(ipv, k + 1), jn1 = __shfl(igv, k + 1);
            ushort4 pr0 = *(const ushort4*)&emb[(size_t)jp0 * D + lane * 4];
            ushort4 nr0 = *(const ushort4*)&emb[(size_t)jn0 * D + lane * 4];
            ushort4 pr1 = *(const ushort4*)&emb[(size_t)jp1 * D + lane * 4];
            ushort4 nr1 = *(const ushort4*)&emb[(size_t)jn1 * D + lane * 4];
            float dp0, dn0, dp1, dn1;
            {
                float x0 = a[0] - bfbits2f(pr0.x) + EPS_PD, y0 = a[0] - bfbits2f(nr0.x) + EPS_PD;
                float x1 = a[1] - bfbits2f(pr0.y) + EPS_PD, y1 = a[1] - bfbits2f(nr0.y) + EPS_PD;
                float x2 = a[2] - bfbits2f(pr0.z) + EPS_PD, y2 = a[2] - bfbits2f(nr0.z) + EPS_PD;
                float x3 = a[3] - bfbits2f(pr0.w) + EPS_PD, y3 = a[3] - bfbits2f(nr0.w) + EPS_PD;
                dp0 = x0 * x0 + x1 * x1 + x2 * x2 + x3 * x3;
                dn0 = y0 * y0 + y1 * y1 + y2 * y2 + y3 * y3;
            }
            {
                float x0 = a[0] - bfbits2f(pr1.x) + EPS_PD, y0 = a[0] - bfbits2f(nr1.x) + EPS_PD;
                float x1 = a[1] - bfbits2f(pr1.y) + EPS_PD, y1 = a[1] - bfbits2f(nr1.y) + EPS_PD;
                float x2 = a[2] - bfbits2f(pr1.z) + EPS_PD, y2 = a[2] - bfbits2f(nr1.z) + EPS_PD;
                float x3 = a[3] - bfbits2f(pr1.w) + EPS_PD, y3 = a[3] - bfbits2f(nr1.w) + EPS_PD;
                dp1 = x0 * x0 + x1 * x1 + x2 * x2 + x3 * x3;
                dn1 = y0 * y0 + y1 * y1 + y2 * y2 + y3 * y3;
            }
            #pragma unroll
            for (int st = 1; st <= 32; st <<= 1) {
                dp0 += __shfl_xor(dp0, st); dn0 += __shfl_xor(dn0, st);
                dp1 += __shfl_xor(dp1, st); dn1 += __shfl_xor(dn1, st);
            }
            float v0 = dp0 - dn0 + MARGIN; s += v0 > 0.f ? v0 : 0.f;
            float v1 = dp1 - dn1 + MARGIN; s += v1 > 0.f ? v1 : 0.f;
        }
        if (k < dg) {
            int jp = __shfl(ipv, k), jn = __shfl(igv, k);
            ushort4 pr = *(const ushort4*)&emb[(size_t)jp * D + lane * 4];
            ushort4 nr = *(const ushort4*)&emb[(size_t)jn * D + lane * 4];
            float x0 = a[0] - bfbits2f(pr.x) + EPS_PD, y0 = a[0] - bfbits2f(nr.x) + EPS_PD;
            float x1 = a[1] - bfbits2f(pr.y) + EPS_PD, y1 = a[1] - bfbits2f(nr.y) + EPS_PD;
            float x2 = a[2] - bfbits2f(pr.z) + EPS_PD, y2 = a[2] - bfbits2f(nr.z) + EPS_PD;
            float x3 = a[3] - bfbits2f(pr.w) + EPS_PD, y3 = a[3] - bfbits2f(nr.w) + EPS_PD;
            float dp = x0 * x0 + x1 * x1 + x2 * x2 + x3 * x3;
            float dn = y0 * y0 + y1 * y1 + y2 * y2 + y3 * y3;
            #pragma unroll
            for (int st = 1; st <= 32; st <<= 1) { dp += __shfl_xor(dp, st); dn += __shfl_xor(dn, st); }
            float v = dp - dn + MARGIN;
            s += v > 0.f ? v : 0.f;
        }
        if (lane == 0) nlpart[z * N + n] = s / (float)dg;
    } else {
        int pair = z - P;
        const __hip_bfloat16* Qa = q + (size_t)pair * N * D;
        const __hip_bfloat16* Qb = q + (size_t)2 * N * D;
        int dg = deg[pair * N + n];
        int idxv = 0; float valv = 0.f;
        if (lane < MAXDEG) {
            idxv = nbr_idx[((size_t)pair * N + n) * MAXDEG + lane];
            valv = nbr_val[((size_t)pair * N + n) * MAXDEG + lane];
        }
        const float invtau = 1.0f / TAU;
        ushort4 ar = *(const ushort4*)&Qa[(size_t)n * D + lane * 4];
        ushort4 br = *(const ushort4*)&Qb[(size_t)n * D + lane * 4];
        float a[4] = {bfbits2f(ar.x), bfbits2f(ar.y), bfbits2f(ar.z), bfbits2f(ar.w)};
        float b[4] = {bfbits2f(br.x), bfbits2f(br.y), bfbits2f(br.z), bfbits2f(br.w)};
        float sr = 0.f, sc = 0.f;
        int k = 0;
        for (; k + 1 < dg; k += 2) {
            int j0 = __shfl(idxv, k), j1 = __shfl(idxv, k + 1);
            float vk0 = __shfl(valv, k), vk1 = __shfl(valv, k + 1);
            ushort4 pj0 = *(const ushort4*)&Qb[(size_t)j0 * D + lane * 4];
            ushort4 aj0 = *(const ushort4*)&Qa[(size_t)j0 * D + lane * 4];
            ushort4 pj1 = *(const ushort4*)&Qb[(size_t)j1 * D + lane * 4];
            ushort4 aj1 = *(const ushort4*)&Qa[(size_t)j1 * D + lane * 4];
            float dr0 = a[0] * bfbits2f(pj0.x) + a[1] * bfbits2f(pj0.y) +
                        a[2] * bfbits2f(pj0.z) + a[3] * bfbits2f(pj0.w);
            float dc0 = b[0] * bfbits2f(aj0.x) + b[1] * bfbits2f(aj0.y) +
                        b[2] * bfbits2f(aj0.z) + b[3] * bfbits2f(aj0.w);
            float dr1 = a[0] * bfbits2f(pj1.x) + a[1] * bfbits2f(pj1.y) +
                        a[2] * bfbits2f(pj1.z) + a[3] * bfbits2f(pj1.w);
            float dc1 = b[0] * bfbits2f(aj1.x) + b[1] * bfbits2f(aj1.y) +
                        b[2] * bfbits2f(aj1.z) + b[3] * bfbits2f(aj1.w);
            #pragma unroll
            for (int s2 = 1; s2 <= 32; s2 <<= 1) {
                dr0 += __shfl_xor(dr0, s2); dc0 += __shfl_xor(dc0, s2);
                dr1 += __shfl_xor(dr1, s2); dc1 += __shfl_xor(dc1, s2);
            }
            sr += __expf(dr0 * invtau) * vk0 + __expf(dr1 * invtau) * vk1;
            sc += __expf(dc0 * invtau) * vk0 + __expf(dc1 * invtau) * vk1;
        }
        if (k < dg) {
            int j = __shfl(idxv, k);
            float vk = __shfl(valv, k);
            ushort4 pj = *(const ushort4*)&Qb[(size_t)j * D + lane * 4];
            ushort4 aj = *(const ushort4*)&Qa[(size_t)j * D + lane * 4];
            float dr = a[0] * bfbits2f(pj.x) + a[1] * bfbits2f(pj.y) +
                       a[2] * bfbits2f(pj.z) + a[3] * bfbits2f(pj.w);
            float dc = b[0] * bfbits2f(aj.x) + b[1] * bfbits2f(aj.y) +
                       b[2] * bfbits2f(aj.z) + b[3] * bfbits2f(aj.w);
            #pragma unroll
            for (int s2 = 1; s2 <= 32; s2 <<= 1) { dr += __shfl_xor(dr, s2); dc += __shfl_xor(dc, s2); }
            sr += __expf(dr * invtau) * vk;
            sc += __expf(dc * invtau) * vk;
        }
        if (lane == 0) { pdrow[pair * N + n] = sr; pdcol[pair * N + n] = sc; }
    }
}

// ---------------------------------------------------------------------------
// 9. finalize: block 0 → loss reduce + write out[N*D];
//    blocks 1..64 → per-block beta (redundant reduce) + z_mp slice.
// ---------------------------------------------------------------------------
__global__ void finalize(const float* __restrict__ nlpart,
                         const float* __restrict__ rowsum, const float* __restrict__ colsum,
                         const float* __restrict__ pdrow, const float* __restrict__ pdcol,
                         const float* __restrict__ spacc,
                         const __hip_bfloat16* __restrict__ conv,
                         const __hip_bfloat16* __restrict__ embBase,
                         const int* __restrict__ counter,
                         void* __restrict__ out) {
    int bf = get_bf(counter);
    int t = threadIdx.x;
    __shared__ float red[256];
    if (blockIdx.x == 0) {
        float s = 0.f;
        for (int i = t; i < P * N; i += 256) s += nlpart[i];
        for (int i = t; i < 2 * N; i += 256) {
            float l12 = -logf(pdrow[i] / (rowsum[i] + 1e-8f));
            float l21 = -logf(pdcol[i] / (colsum[i] + 1e-8f));
            s += (0.5f * l12 + 0.5f * l21) / (float)N;
        }
        red[t] = s;
        __syncthreads();
        for (int st = 128; st > 0; st >>= 1) { if (t < st) red[t] += red[t + st]; __syncthreads(); }
        if (t == 0) {
            if (bf) ((__hip_bfloat16*)out)[(size_t)N * D] = __float2bfloat16(red[0]);
            else    ((float*)out)[(size_t)N * D] = red[0];
        }
        return;
    }
    __shared__ float w[P];
    for (int p = 0; p < P; p++) {
        float v = (spacc[p * D + t] / (float)N) * b2f(conv[OFF_AV + t]);
        red[t] = v;
        __syncthreads();
        for (int s = 128; s > 0; s >>= 1) { if (t < s) red[t] += red[t + s]; __syncthreads(); }
        if (t == 0) w[p] = red[0];
        __syncthreads();
    }
    float m = fmaxf(w[0], fmaxf(w[1], w[2]));
    float e0 = __expf(w[0] - m), e1 = __expf(w[1] - m), e2 = __expf(w[2] - m);
    float ssum = e0 + e1 + e2;
    float b0 = e0 / ssum, b1 = e1 / ssum, b2 = e2 / ssum;
    int slice = blockIdx.x - 1;
    int base = slice * (N * D / 64);
    for (int e = t * 4; e < N * D / 64; e += 256 * 4) {
        int i = base + e;
        ushort4 x0 = *(const ushort4*)&embBase[i];
        ushort4 x1 = *(const ushort4*)&embBase[(size_t)N * D + i];
        ushort4 x2 = *(const ushort4*)&embBase[(size_t)2 * N * D + i];
        float v[4];
        v[0] = b0 * bfbits2f(x0.x) + b1 * bfbits2f(x1.x) + b2 * bfbits2f(x2.x);
        v[1] = b0 * bfbits2f(x0.y) + b1 * bfbits2f(x1.y) + b2 * bfbits2f(x2.y);
        v[2] = b0 * bfbits2f(x0.z) + b1 * bfbits2f(x1.z) + b2 * bfbits2f(x2.z);
        v[3] = b0 * bfbits2f(x0.w) + b1 * bfbits2f(x1.w) + b2 * bfbits2f(x2.w);
        if (bf) {
            ushort4 ov;
            ov.x = f2bfbits(v[0]); ov.y = f2bfbits(v[1]);
            ov.z = f2bfbits(v[2]); ov.w = f2bfbits(v[3]);
            *(ushort4*)&((__hip_bfloat16*)out)[i] = ov;
        } else {
            float* o = (float*)out;
            o[i] = v[0]; o[i + 1] = v[1]; o[i + 2] = v[2]; o[i + 3] = v[3];
        }
    }
}

extern "C" void kernel_launch(void* const* d_in, const int* in_sizes, int n_in,
                              void* d_out, int out_size, void* d_ws, size_t ws_size,
                              hipStream_t stream) {
    const void* h        = d_in[0];
    const void* mps      = d_in[1];
    const void* W_gcn    = d_in[2];
    const void* b_gcn    = d_in[3];
    const void* prelu_a  = d_in[4];
    const void* att_fc_W = d_in[5];
    const void* att_fc_b = d_in[6];
    const void* att_vec  = d_in[7];
    const void* proj_W1  = d_in[8];
    const void* proj_b1  = d_in[9];
    const void* proj_W2  = d_in[10];
    const void* proj_b2  = d_in[11];

    char* ws = (char*)d_ws;
    size_t off = 0;
    auto alloc = [&](size_t bytes) -> char* {
        char* p = ws + off;
        off = (off + bytes + 255) & ~(size_t)255;
        return p;
    };
    __hip_bfloat16* conv = (__hip_bfloat16*)alloc((size_t)CONV_TOTAL * 2);
    __hip_bfloat16* xbuf = (__hip_bfloat16*)alloc((size_t)P * N * D * 2);
    __hip_bfloat16* emb  = (__hip_bfloat16*)alloc((size_t)P * N * D * 2);
    __hip_bfloat16* q    = (__hip_bfloat16*)alloc((size_t)P * N * D * 2);
    int*   nbr_idx = (int*)alloc((size_t)P * N * MAXDEG * 4);
    float* nbr_val = (float*)alloc((size_t)P * N * MAXDEG * 4);
    int*   neg_idx = (int*)alloc((size_t)P * N * MAXDEG * 4);
    int*   deg     = (int*)alloc((size_t)P * N * 4);
    float* nlpart  = (float*)alloc((size_t)P * N * 4);
    float* pdrow   = (float*)alloc((size_t)2 * N * 4);
    float* pdcol   = (float*)alloc((size_t)2 * N * 4);
    char* zero_begin = ws + off;
    float* rowsum = (float*)alloc((size_t)2 * N * 4);
    float* colsum = (float*)alloc((size_t)2 * N * 4);
    float* spacc  = (float*)alloc((size_t)P * D * 4);
    size_t zero_bytes = (size_t)((ws + off) - zero_begin);
    int*   counter = (int*)alloc(16);   // NOT zeroed: detect uses atomicMax sentinel

    // 0. dtype detection + zero the atomic-accumulator region (one dispatch)
    detect_dtype<<<1024, 256, 0, stream>>>((const unsigned int*)mps, 2 * 1024 * 1024,
                                           counter, (float*)zero_begin,
                                           (int)(zero_bytes / 4));

    // 1. convert dense inputs to bf16 staging
    convert_all<<<512, 256, 0, stream>>>(h, W_gcn, att_fc_W, proj_W1, proj_W2, b_gcn,
                                         att_fc_b, att_vec, prelu_a, proj_b1, proj_b2,
                                         counter, conv);

    // 2. sparse extraction (wave-parallel epilogue)
    extract_sparse<<<P * N, 256, 0, stream>>>(mps, counter, nbr_idx, nbr_val, neg_idx, deg);

    // 3. GCN: X[z] = h @ Wg[z]^T — all three z in one pass over h
    gemm_triple<<<dim3(N / 64, D / 64), 256, 0, stream>>>(conv, xbuf);
    // 4. emb[z] = prelu(spmm + bias)
    spmm_prelu<<<dim3(N / 4, 1, P), 256, 0, stream>>>(xbuf, nbr_idx, nbr_val, deg, conv, emb);
    // 5+6a. fused: spacc = colsum(tanh(emb@attW^T+attb)); xbuf = elu(emb@W1^T+b1)
    gemm_dual<<<dim3(N / 64, D / 64, P), 256, 0, stream>>>(emb, conv, xbuf, spacc);
    // 6b+7. q[z] = rownorm(xbuf[z] @ W2^T + b2), fused
    gemm_w2_norm<<<dim3(N / 16, 1, P), 256, 0, stream>>>(xbuf, conv, q);
    // 8. sim (both pairs batched): rowsum/colsum (async-staged MFMA)
    sim_mfma<<<dim3(N / 128, N / 128, 2), 256, 0, stream>>>(q, rowsum, colsum);
    // 9. merged node-loss + posdot (round-10 proven wave-per-edge version)
    edge_losses<<<dim3(N / 4, 1, P + 2), 256, 0, stream>>>(emb, q, nbr_idx, nbr_val,
                                                           neg_idx, deg, nlpart, pdrow, pdcol);
    // 10. finalize: loss + beta + z_mp in one dispatch
    finalize<<<65, 256, 0, stream>>>(nlpart, rowsum, colsum, pdrow, pdcol,
                                     spacc, conv, emb, counter, d_out);
}